// Round 1
// baseline (573.394 us; speedup 1.0000x reference)
//
#include <hip/hip_runtime.h>

#define NNODES 50000
#define NEDGES 800000
#define ETOT (NEDGES + NNODES)

// ---------------- degree (incoming edge count, excl. self loop) ----------------
__global__ __launch_bounds__(256) void deg_kernel(const int* __restrict__ ei,
                                                  int* __restrict__ deg) {
  int e = blockIdx.x * 256 + threadIdx.x;
  if (e < NEDGES) atomicAdd(&deg[ei[NEDGES + e]], 1);
}

// ---------------- t = x @ W, stored [N][OUT][H] (H=4) ----------------
// thread cIdx = o*4+h computes column h*OUT+o of x@W; write t[n*4OUT + cIdx] coalesced.
template<int FIN, int OUT>
__global__ __launch_bounds__(256) void gemm_t_kernel(const float* __restrict__ x,
                                                     const float* __restrict__ W,
                                                     float* __restrict__ t) {
  constexpr int COLS = 4 * OUT;
  constexpr int GROUPS = 256 / COLS;
  const int cIdx = threadIdx.x & (COLS - 1);
  const int g = threadIdx.x / COLS;
  const int o = cIdx >> 2, h = cIdx & 3;
  float wreg[FIN];
#pragma unroll
  for (int f = 0; f < FIN; ++f) wreg[f] = W[f * COLS + h * OUT + o];
  for (int n = blockIdx.x * GROUPS + g; n < NNODES; n += gridDim.x * GROUPS) {
    const float4* xr = (const float4*)(x + (size_t)n * FIN);
    float acc = 0.f;
#pragma unroll
    for (int f4 = 0; f4 < FIN / 4; ++f4) {
      float4 xv = xr[f4];
      acc += wreg[4 * f4 + 0] * xv.x + wreg[4 * f4 + 1] * xv.y +
             wreg[4 * f4 + 2] * xv.z + wreg[4 * f4 + 3] * xv.w;
    }
    t[(size_t)n * COLS + cIdx] = acc;
  }
}

// ---------------- s = x @ u  ([N,4]) ----------------
template<int FIN>
__global__ __launch_bounds__(256) void s_kernel(const float* __restrict__ x,
                                                const float* __restrict__ u,
                                                float* __restrict__ s) {
  int tid = blockIdx.x * 256 + threadIdx.x;
  int n = tid >> 2, h = tid & 3;
  if (n >= NNODES) return;
  const float4* xr = (const float4*)(x + (size_t)n * FIN);
  float acc = 0.f;
#pragma unroll
  for (int f4 = 0; f4 < FIN / 4; ++f4) {
    float4 xv = xr[f4];
    acc += xv.x * u[(4 * f4 + 0) * 4 + h] + xv.y * u[(4 * f4 + 1) * 4 + h] +
           xv.z * u[(4 * f4 + 2) * 4 + h] + xv.w * u[(4 * f4 + 3) * 4 + h];
  }
  s[tid] = acc;  // tid == n*4+h
}

// ---------------- per-edge: softmax(q) weighted message + atomic scatter ----------------
template<int OUT>
__global__ __launch_bounds__(256) void edge_kernel(const int* __restrict__ ei,
                                                   const float* __restrict__ s,
                                                   const float* __restrict__ t,
                                                   const float* __restrict__ cptr,
                                                   float* __restrict__ num) {
  constexpr int SH = (OUT == 16) ? 4 : (OUT == 32) ? 5 : 6;
  int gtid = blockIdx.x * 256 + threadIdx.x;
  int e = gtid >> SH;
  int o = gtid & (OUT - 1);
  if (e >= ETOT) return;
  int src, dst;
  if (e < NEDGES) {
    src = ei[e];
    dst = ei[NEDGES + e];
  } else {
    src = dst = e - NEDGES;
  }
  float4 c4 = *(const float4*)cptr;
  float4 ss = *(const float4*)(s + 4 * (size_t)src);
  float4 sd = *(const float4*)(s + 4 * (size_t)dst);
  float l0 = ss.x - sd.x + c4.x;
  float l1 = ss.y - sd.y + c4.y;
  float l2 = ss.z - sd.z + c4.z;
  float l3 = ss.w - sd.w + c4.w;
  float mx = fmaxf(fmaxf(l0, l1), fmaxf(l2, l3));
  float e0 = __expf(l0 - mx), e1 = __expf(l1 - mx), e2 = __expf(l2 - mx), e3 = __expf(l3 - mx);
  float inv = 1.f / (e0 + e1 + e2 + e3);
  float4 tv = *(const float4*)(t + ((size_t)src * OUT + o) * 4);
  float msg = (e0 * tv.x + e1 * tv.y + e2 * tv.z + e3 * tv.w) * inv;
  atomicAdd(&num[(size_t)dst * OUT + o], msg);
}

// ---------------- h = relu(num/deg + b); optional BN-stats reduction ----------------
template<int OUT, bool STATS>
__global__ __launch_bounds__(256) void finalize_kernel(const float* __restrict__ num,
                                                       const int* __restrict__ deg,
                                                       const float* __restrict__ bptr,
                                                       float* __restrict__ h,
                                                       float* __restrict__ sums) {
  constexpr int ROWS = 256 / OUT;
  const int o = threadIdx.x & (OUT - 1);
  const int r = threadIdx.x / OUT;
  const float b = bptr[o];
  float accS = 0.f, accQ = 0.f;
  for (int base = blockIdx.x * ROWS; base < NNODES; base += gridDim.x * ROWS) {
    int n = base + r;
    if (n < NNODES) {
      float d = (float)(deg[n] + 1);  // +1 self loop
      float v = fmaxf(num[(size_t)n * OUT + o] / d + b, 0.f);
      h[(size_t)n * OUT + o] = v;
      if (STATS) { accS += v; accQ += v * v; }
    }
  }
  if (STATS) {
    __shared__ float ls[256], lq[256];
    ls[threadIdx.x] = accS;
    lq[threadIdx.x] = accQ;
    __syncthreads();
    if (threadIdx.x < OUT) {
      float a = ls[threadIdx.x], q = lq[threadIdx.x];
#pragma unroll
      for (int rr = 1; rr < ROWS; ++rr) {
        a += ls[threadIdx.x + rr * OUT];
        q += lq[threadIdx.x + rr * OUT];
      }
      atomicAdd(&sums[threadIdx.x], a);
      atomicAdd(&sums[64 + threadIdx.x], q);
    }
  }
}

// ---------------- BN + MLP head + sigmoid, one thread per node ----------------
__global__ __launch_bounds__(256) void mlp_kernel(
    const float* __restrict__ h3, const float* __restrict__ sums,
    const float* __restrict__ gamma, const float* __restrict__ beta,
    const float* __restrict__ lw1, const float* __restrict__ lb1,
    const float* __restrict__ lw2, const float* __restrict__ lb2,
    const float* __restrict__ lw3, const float* __restrict__ lb3,
    const float* __restrict__ lw4, const float* __restrict__ lb4,
    const float* __restrict__ ow, const float* __restrict__ ob,
    float* __restrict__ out) {
  __shared__ float w1[64 * 32], w2[32 * 16], w3[16 * 8], w4[8 * 4];
  __shared__ float b1s[32], b2s[16], b3s[8], b4s[4], wos[4];
  __shared__ float scale[64], shift[64];
  int tid = threadIdx.x;
  for (int i = tid; i < 64 * 32; i += 256) w1[i] = lw1[i];
  for (int i = tid; i < 32 * 16; i += 256) w2[i] = lw2[i];
  if (tid < 128) w3[tid] = lw3[tid];
  if (tid < 32) { w4[tid] = lw4[tid]; b1s[tid] = lb1[tid]; }
  if (tid < 16) b2s[tid] = lb2[tid];
  if (tid < 8) b3s[tid] = lb3[tid];
  if (tid < 4) { b4s[tid] = lb4[tid]; wos[tid] = ow[tid]; }
  if (tid < 64) {
    float mu = sums[tid] * (1.f / NNODES);
    float var = sums[64 + tid] * (1.f / NNODES) - mu * mu;
    float sc = rsqrtf(var + 1e-5f) * gamma[tid];
    scale[tid] = sc;
    shift[tid] = beta[tid] - mu * sc;
  }
  __syncthreads();
  int n = blockIdx.x * 256 + tid;
  if (n >= NNODES) return;
  float obv = ob[0];
  const float4* hr = (const float4*)(h3 + (size_t)n * 64);
  float z1[32];
#pragma unroll
  for (int j = 0; j < 32; ++j) z1[j] = b1s[j];
  for (int i4 = 0; i4 < 16; ++i4) {
    float4 hv = hr[i4];
    float a0 = hv.x * scale[4 * i4 + 0] + shift[4 * i4 + 0];
    float a1 = hv.y * scale[4 * i4 + 1] + shift[4 * i4 + 1];
    float a2 = hv.z * scale[4 * i4 + 2] + shift[4 * i4 + 2];
    float a3 = hv.w * scale[4 * i4 + 3] + shift[4 * i4 + 3];
#pragma unroll
    for (int j = 0; j < 32; ++j) {
      z1[j] += a0 * w1[(4 * i4 + 0) * 32 + j] + a1 * w1[(4 * i4 + 1) * 32 + j] +
               a2 * w1[(4 * i4 + 2) * 32 + j] + a3 * w1[(4 * i4 + 3) * 32 + j];
    }
  }
  float z2[16];
#pragma unroll
  for (int j = 0; j < 16; ++j) z2[j] = b2s[j];
  for (int i = 0; i < 32; ++i) {
    float a = fmaxf(z1[i], 0.f);
#pragma unroll
    for (int j = 0; j < 16; ++j) z2[j] += a * w2[i * 16 + j];
  }
  float z3[8];
#pragma unroll
  for (int j = 0; j < 8; ++j) z3[j] = b3s[j];
  for (int i = 0; i < 16; ++i) {
    float a = fmaxf(z2[i], 0.f);
#pragma unroll
    for (int j = 0; j < 8; ++j) z3[j] += a * w3[i * 8 + j];
  }
  float z4[4];
#pragma unroll
  for (int j = 0; j < 4; ++j) z4[j] = b4s[j];
  for (int i = 0; i < 8; ++i) {
    float a = fmaxf(z3[i], 0.f);
#pragma unroll
    for (int j = 0; j < 4; ++j) z4[j] += a * w4[i * 4 + j];
  }
  float zo = obv;
#pragma unroll
  for (int i = 0; i < 4; ++i) zo += fmaxf(z4[i], 0.f) * wos[i];
  out[n] = 1.f / (1.f + __expf(-zo));
}

extern "C" void kernel_launch(void* const* d_in, const int* in_sizes, int n_in,
                              void* d_out, int out_size, void* d_ws, size_t ws_size,
                              hipStream_t stream) {
  const float* x  = (const float*)d_in[0];
  const int*   ei = (const int*)d_in[1];
  const float* W1 = (const float*)d_in[2];  const float* u1 = (const float*)d_in[3];
  const float* c1 = (const float*)d_in[4];  const float* b1 = (const float*)d_in[5];
  const float* W2 = (const float*)d_in[6];  const float* u2 = (const float*)d_in[7];
  const float* c2 = (const float*)d_in[8];  const float* b2 = (const float*)d_in[9];
  const float* W3 = (const float*)d_in[10]; const float* u3 = (const float*)d_in[11];
  const float* c3 = (const float*)d_in[12]; const float* b3 = (const float*)d_in[13];
  const float* gamma = (const float*)d_in[14]; const float* beta = (const float*)d_in[15];
  const float* lw1 = (const float*)d_in[16]; const float* lb1 = (const float*)d_in[17];
  const float* lw2 = (const float*)d_in[18]; const float* lb2 = (const float*)d_in[19];
  const float* lw3 = (const float*)d_in[20]; const float* lb3 = (const float*)d_in[21];
  const float* lw4 = (const float*)d_in[22]; const float* lb4 = (const float*)d_in[23];
  const float* ow  = (const float*)d_in[24]; const float* ob  = (const float*)d_in[25];
  float* out = (float*)d_out;

  float* t    = (float*)d_ws;                       // N*256
  float* num  = t + (size_t)NNODES * 256;           // N*64
  float* hA   = num + (size_t)NNODES * 64;          // N*64
  float* hB   = hA + (size_t)NNODES * 64;           // N*64
  float* s    = hB + (size_t)NNODES * 64;           // N*4
  float* sums = s + (size_t)NNODES * 4;             // 128
  int*   deg  = (int*)(sums + 128);                 // N

  hipMemsetAsync(deg, 0, NNODES * sizeof(int), stream);
  hipMemsetAsync(sums, 0, 128 * sizeof(float), stream);
  hipMemsetAsync(num, 0, (size_t)NNODES * 16 * sizeof(float), stream);

  deg_kernel<<<(NEDGES + 255) / 256, 256, 0, stream>>>(ei, deg);

  // ---- layer 1: 64 -> 16 ----
  gemm_t_kernel<64, 16><<<1024, 256, 0, stream>>>(x, W1, t);
  s_kernel<64><<<(NNODES * 4 + 255) / 256, 256, 0, stream>>>(x, u1, s);
  edge_kernel<16><<<((size_t)ETOT * 16 + 255) / 256, 256, 0, stream>>>(ei, s, t, c1, num);
  finalize_kernel<16, false><<<512, 256, 0, stream>>>(num, deg, b1, hA, nullptr);

  // ---- layer 2: 16 -> 32 ----
  hipMemsetAsync(num, 0, (size_t)NNODES * 32 * sizeof(float), stream);
  gemm_t_kernel<16, 32><<<1024, 256, 0, stream>>>(hA, W2, t);
  s_kernel<16><<<(NNODES * 4 + 255) / 256, 256, 0, stream>>>(hA, u2, s);
  edge_kernel<32><<<((size_t)ETOT * 32 + 255) / 256, 256, 0, stream>>>(ei, s, t, c2, num);
  finalize_kernel<32, false><<<512, 256, 0, stream>>>(num, deg, b2, hB, nullptr);

  // ---- layer 3: 32 -> 64 ----
  hipMemsetAsync(num, 0, (size_t)NNODES * 64 * sizeof(float), stream);
  gemm_t_kernel<32, 64><<<1024, 256, 0, stream>>>(hB, W3, t);
  s_kernel<32><<<(NNODES * 4 + 255) / 256, 256, 0, stream>>>(hB, u3, s);
  edge_kernel<64><<<((size_t)ETOT * 64 + 255) / 256, 256, 0, stream>>>(ei, s, t, c3, num);
  finalize_kernel<64, true><<<256, 256, 0, stream>>>(num, deg, b3, hA, sums);

  // ---- BN + MLP head ----
  mlp_kernel<<<(NNODES + 255) / 256, 256, 0, stream>>>(hA, sums, gamma, beta, lw1, lb1,
                                                       lw2, lb2, lw3, lb3, lw4, lb4,
                                                       ow, ob, out);
}

// Round 2
// 505.594 us; speedup vs baseline: 1.1341x; 1.1341x over previous
//
#include <hip/hip_runtime.h>

#define NNODES 50000
#define NEDGES 800000
#define SCAN_BLOCKS ((NNODES + 255) / 256)   // 196

// ---------------- CSR build: histogram over dst ----------------
__global__ __launch_bounds__(256) void hist_kernel(const int* __restrict__ ei,
                                                   int* __restrict__ counts) {
  int e = blockIdx.x * 256 + threadIdx.x;
  if (e < NEDGES) atomicAdd(&counts[ei[NEDGES + e]], 1);
}

// block-level exclusive scan of counts -> rowptr(partial), block sums out
__global__ __launch_bounds__(256) void scanA_kernel(const int* __restrict__ counts,
                                                    int* __restrict__ rowptr,
                                                    int* __restrict__ blockSum) {
  __shared__ int sm[256];
  int i = blockIdx.x * 256 + threadIdx.x;
  int v = (i < NNODES) ? counts[i] : 0;
  sm[threadIdx.x] = v;
  __syncthreads();
  for (int off = 1; off < 256; off <<= 1) {
    int x = (threadIdx.x >= off) ? sm[threadIdx.x - off] : 0;
    __syncthreads();
    sm[threadIdx.x] += x;
    __syncthreads();
  }
  if (i < NNODES) rowptr[i] = sm[threadIdx.x] - v;  // exclusive within block
  if (threadIdx.x == 255) blockSum[blockIdx.x] = sm[255];
}

__global__ __launch_bounds__(256) void scanB_kernel(int* __restrict__ blockSum,
                                                    int* __restrict__ blockOff) {
  __shared__ int sm[256];
  int v = (threadIdx.x < SCAN_BLOCKS) ? blockSum[threadIdx.x] : 0;
  sm[threadIdx.x] = v;
  __syncthreads();
  for (int off = 1; off < 256; off <<= 1) {
    int x = (threadIdx.x >= off) ? sm[threadIdx.x - off] : 0;
    __syncthreads();
    sm[threadIdx.x] += x;
    __syncthreads();
  }
  if (threadIdx.x < SCAN_BLOCKS) blockOff[threadIdx.x] = sm[threadIdx.x] - v;
}

__global__ __launch_bounds__(256) void scanC_kernel(int* __restrict__ rowptr,
                                                    const int* __restrict__ blockOff) {
  int i = blockIdx.x * 256 + threadIdx.x;
  if (i < NNODES) rowptr[i] += blockOff[blockIdx.x];
  if (i == 0) rowptr[NNODES] = NEDGES;
}

// scatter src ids into dst-sorted col array
__global__ __launch_bounds__(256) void scatter_kernel(const int* __restrict__ ei,
                                                      const int* __restrict__ rowptr,
                                                      int* __restrict__ fill,
                                                      int* __restrict__ col) {
  int e = blockIdx.x * 256 + threadIdx.x;
  if (e < NEDGES) {
    int dst = ei[NEDGES + e];
    int pos = rowptr[dst] + atomicAdd(&fill[dst], 1);
    col[pos] = ei[e];
  }
}

// ---------------- t = x @ W, stored [N][OUT][H] (H=4) ----------------
template<int FIN, int OUT>
__global__ __launch_bounds__(256) void gemm_t_kernel(const float* __restrict__ x,
                                                     const float* __restrict__ W,
                                                     float* __restrict__ t) {
  constexpr int COLS = 4 * OUT;
  constexpr int GROUPS = 256 / COLS;
  const int cIdx = threadIdx.x & (COLS - 1);
  const int g = threadIdx.x / COLS;
  const int o = cIdx >> 2, h = cIdx & 3;
  float wreg[FIN];
#pragma unroll
  for (int f = 0; f < FIN; ++f) wreg[f] = W[f * COLS + h * OUT + o];
  for (int n = blockIdx.x * GROUPS + g; n < NNODES; n += gridDim.x * GROUPS) {
    const float4* xr = (const float4*)(x + (size_t)n * FIN);
    float acc = 0.f;
#pragma unroll
    for (int f4 = 0; f4 < FIN / 4; ++f4) {
      float4 xv = xr[f4];
      acc += wreg[4 * f4 + 0] * xv.x + wreg[4 * f4 + 1] * xv.y +
             wreg[4 * f4 + 2] * xv.z + wreg[4 * f4 + 3] * xv.w;
    }
    t[(size_t)n * COLS + cIdx] = acc;
  }
}

// ---------------- s = x @ u  ([N,4]) ----------------
template<int FIN>
__global__ __launch_bounds__(256) void s_kernel(const float* __restrict__ x,
                                                const float* __restrict__ u,
                                                float* __restrict__ s) {
  int tid = blockIdx.x * 256 + threadIdx.x;
  int n = tid >> 2, h = tid & 3;
  if (n >= NNODES) return;
  const float4* xr = (const float4*)(x + (size_t)n * FIN);
  float acc = 0.f;
#pragma unroll
  for (int f4 = 0; f4 < FIN / 4; ++f4) {
    float4 xv = xr[f4];
    acc += xv.x * u[(4 * f4 + 0) * 4 + h] + xv.y * u[(4 * f4 + 1) * 4 + h] +
           xv.z * u[(4 * f4 + 2) * 4 + h] + xv.w * u[(4 * f4 + 3) * 4 + h];
  }
  s[tid] = acc;  // tid == n*4+h
}

// ---------------- gather: one OUT-lane subwave per dst node ----------------
// acc += softmax_h(s[src]-s[dst]+c) . t[src][o][:] over incoming edges + self loop,
// then h[n][o] = relu(acc/deg + b[o]).   No atomics, single write per output.
template<int OUT>
__global__ __launch_bounds__(256) void gather_kernel(const int* __restrict__ rowptr,
                                                     const int* __restrict__ col,
                                                     const float* __restrict__ s,
                                                     const float* __restrict__ t,
                                                     const float* __restrict__ cptr,
                                                     const float* __restrict__ bptr,
                                                     float* __restrict__ h) {
  constexpr int NSUB = 256 / OUT;  // dst nodes per block
  const int lane = threadIdx.x & (OUT - 1);
  const int sub = threadIdx.x / OUT;
  const int n = blockIdx.x * NSUB + sub;
  if (n >= NNODES) return;

  float4 c4 = *(const float4*)cptr;
  // self-loop attention = softmax(c) (s terms cancel)
  float mxc = fmaxf(fmaxf(c4.x, c4.y), fmaxf(c4.z, c4.w));
  float qs0 = __expf(c4.x - mxc), qs1 = __expf(c4.y - mxc);
  float qs2 = __expf(c4.z - mxc), qs3 = __expf(c4.w - mxc);
  float sinv = 1.f / (qs0 + qs1 + qs2 + qs3);
  qs0 *= sinv; qs1 *= sinv; qs2 *= sinv; qs3 *= sinv;

  float4 sd = *(const float4*)(s + 4 * (size_t)n);
  float4 tv = *((const float4*)(t + (size_t)n * (4 * OUT)) + lane);
  float acc = qs0 * tv.x + qs1 * tv.y + qs2 * tv.z + qs3 * tv.w;

  const int beg = rowptr[n], end = rowptr[n + 1];
  for (int idx = beg; idx < end; ++idx) {
    int src = col[idx];
    float4 ss = *(const float4*)(s + 4 * (size_t)src);
    float l0 = ss.x - sd.x + c4.x;
    float l1 = ss.y - sd.y + c4.y;
    float l2 = ss.z - sd.z + c4.z;
    float l3 = ss.w - sd.w + c4.w;
    float mx = fmaxf(fmaxf(l0, l1), fmaxf(l2, l3));
    float e0 = __expf(l0 - mx), e1 = __expf(l1 - mx);
    float e2 = __expf(l2 - mx), e3 = __expf(l3 - mx);
    float inv = 1.f / (e0 + e1 + e2 + e3);
    float4 tw = *((const float4*)(t + (size_t)src * (4 * OUT)) + lane);
    acc += (e0 * tw.x + e1 * tw.y + e2 * tw.z + e3 * tw.w) * inv;
  }
  float d = (float)(end - beg + 1);  // +1 self loop
  h[(size_t)n * OUT + lane] = fmaxf(acc / d + bptr[lane], 0.f);
}

// ---------------- BN batch-stats over h3 [N,64] ----------------
__global__ __launch_bounds__(256) void stats_kernel(const float* __restrict__ h3,
                                                    float* __restrict__ sums) {
  const int o = threadIdx.x & 63;
  const int r = threadIdx.x >> 6;
  float accS = 0.f, accQ = 0.f;
  for (int base = blockIdx.x * 4; base < NNODES; base += gridDim.x * 4) {
    int n = base + r;
    if (n < NNODES) {
      float v = h3[(size_t)n * 64 + o];
      accS += v;
      accQ += v * v;
    }
  }
  __shared__ float ls[256], lq[256];
  ls[threadIdx.x] = accS;
  lq[threadIdx.x] = accQ;
  __syncthreads();
  if (threadIdx.x < 64) {
    float a = ls[threadIdx.x] + ls[threadIdx.x + 64] + ls[threadIdx.x + 128] + ls[threadIdx.x + 192];
    float q = lq[threadIdx.x] + lq[threadIdx.x + 64] + lq[threadIdx.x + 128] + lq[threadIdx.x + 192];
    atomicAdd(&sums[threadIdx.x], a);
    atomicAdd(&sums[64 + threadIdx.x], q);
  }
}

// ---------------- BN + MLP head + sigmoid, one thread per node ----------------
__global__ __launch_bounds__(256) void mlp_kernel(
    const float* __restrict__ h3, const float* __restrict__ sums,
    const float* __restrict__ gamma, const float* __restrict__ beta,
    const float* __restrict__ lw1, const float* __restrict__ lb1,
    const float* __restrict__ lw2, const float* __restrict__ lb2,
    const float* __restrict__ lw3, const float* __restrict__ lb3,
    const float* __restrict__ lw4, const float* __restrict__ lb4,
    const float* __restrict__ ow, const float* __restrict__ ob,
    float* __restrict__ out) {
  __shared__ float w1[64 * 32], w2[32 * 16], w3[16 * 8], w4[8 * 4];
  __shared__ float b1s[32], b2s[16], b3s[8], b4s[4], wos[4];
  __shared__ float scale[64], shift[64];
  int tid = threadIdx.x;
  for (int i = tid; i < 64 * 32; i += 256) w1[i] = lw1[i];
  for (int i = tid; i < 32 * 16; i += 256) w2[i] = lw2[i];
  if (tid < 128) w3[tid] = lw3[tid];
  if (tid < 32) { w4[tid] = lw4[tid]; b1s[tid] = lb1[tid]; }
  if (tid < 16) b2s[tid] = lb2[tid];
  if (tid < 8) b3s[tid] = lb3[tid];
  if (tid < 4) { b4s[tid] = lb4[tid]; wos[tid] = ow[tid]; }
  if (tid < 64) {
    float mu = sums[tid] * (1.f / NNODES);
    float var = sums[64 + tid] * (1.f / NNODES) - mu * mu;
    float sc = rsqrtf(var + 1e-5f) * gamma[tid];
    scale[tid] = sc;
    shift[tid] = beta[tid] - mu * sc;
  }
  __syncthreads();
  int n = blockIdx.x * 256 + tid;
  if (n >= NNODES) return;
  float obv = ob[0];
  const float4* hr = (const float4*)(h3 + (size_t)n * 64);
  float z1[32];
#pragma unroll
  for (int j = 0; j < 32; ++j) z1[j] = b1s[j];
  for (int i4 = 0; i4 < 16; ++i4) {
    float4 hv = hr[i4];
    float a0 = hv.x * scale[4 * i4 + 0] + shift[4 * i4 + 0];
    float a1 = hv.y * scale[4 * i4 + 1] + shift[4 * i4 + 1];
    float a2 = hv.z * scale[4 * i4 + 2] + shift[4 * i4 + 2];
    float a3 = hv.w * scale[4 * i4 + 3] + shift[4 * i4 + 3];
#pragma unroll
    for (int j = 0; j < 32; ++j) {
      z1[j] += a0 * w1[(4 * i4 + 0) * 32 + j] + a1 * w1[(4 * i4 + 1) * 32 + j] +
               a2 * w1[(4 * i4 + 2) * 32 + j] + a3 * w1[(4 * i4 + 3) * 32 + j];
    }
  }
  float z2[16];
#pragma unroll
  for (int j = 0; j < 16; ++j) z2[j] = b2s[j];
  for (int i = 0; i < 32; ++i) {
    float a = fmaxf(z1[i], 0.f);
#pragma unroll
    for (int j = 0; j < 16; ++j) z2[j] += a * w2[i * 16 + j];
  }
  float z3[8];
#pragma unroll
  for (int j = 0; j < 8; ++j) z3[j] = b3s[j];
  for (int i = 0; i < 16; ++i) {
    float a = fmaxf(z2[i], 0.f);
#pragma unroll
    for (int j = 0; j < 8; ++j) z3[j] += a * w3[i * 8 + j];
  }
  float z4[4];
#pragma unroll
  for (int j = 0; j < 4; ++j) z4[j] = b4s[j];
  for (int i = 0; i < 8; ++i) {
    float a = fmaxf(z3[i], 0.f);
#pragma unroll
    for (int j = 0; j < 4; ++j) z4[j] += a * w4[i * 4 + j];
  }
  float zo = obv;
#pragma unroll
  for (int i = 0; i < 4; ++i) zo += fmaxf(z4[i], 0.f) * wos[i];
  out[n] = 1.f / (1.f + __expf(-zo));
}

extern "C" void kernel_launch(void* const* d_in, const int* in_sizes, int n_in,
                              void* d_out, int out_size, void* d_ws, size_t ws_size,
                              hipStream_t stream) {
  const float* x  = (const float*)d_in[0];
  const int*   ei = (const int*)d_in[1];
  const float* W1 = (const float*)d_in[2];  const float* u1 = (const float*)d_in[3];
  const float* c1 = (const float*)d_in[4];  const float* b1 = (const float*)d_in[5];
  const float* W2 = (const float*)d_in[6];  const float* u2 = (const float*)d_in[7];
  const float* c2 = (const float*)d_in[8];  const float* b2 = (const float*)d_in[9];
  const float* W3 = (const float*)d_in[10]; const float* u3 = (const float*)d_in[11];
  const float* c3 = (const float*)d_in[12]; const float* b3 = (const float*)d_in[13];
  const float* gamma = (const float*)d_in[14]; const float* beta = (const float*)d_in[15];
  const float* lw1 = (const float*)d_in[16]; const float* lb1 = (const float*)d_in[17];
  const float* lw2 = (const float*)d_in[18]; const float* lb2 = (const float*)d_in[19];
  const float* lw3 = (const float*)d_in[20]; const float* lb3 = (const float*)d_in[21];
  const float* lw4 = (const float*)d_in[22]; const float* lb4 = (const float*)d_in[23];
  const float* ow  = (const float*)d_in[24]; const float* ob  = (const float*)d_in[25];
  float* out = (float*)d_out;

  float* t    = (float*)d_ws;                         // N*256
  float* hA   = t + (size_t)NNODES * 256;             // N*64
  float* hB   = hA + (size_t)NNODES * 64;             // N*64
  float* s    = hB + (size_t)NNODES * 64;             // N*4
  float* sums = s + (size_t)NNODES * 4;               // 128
  int*   rowptr   = (int*)(sums + 128);               // N+1
  int*   counts   = rowptr + NNODES + 8;              // N
  int*   fill     = counts + NNODES;                  // N
  int*   blockSum = fill + NNODES;                    // SCAN_BLOCKS
  int*   blockOff = blockSum + 256;                   // SCAN_BLOCKS
  int*   col      = blockOff + 256;                   // E

  hipMemsetAsync(counts, 0, NNODES * sizeof(int), stream);
  hipMemsetAsync(fill, 0, NNODES * sizeof(int), stream);
  hipMemsetAsync(sums, 0, 128 * sizeof(float), stream);

  // ---- CSR by dst ----
  hist_kernel<<<(NEDGES + 255) / 256, 256, 0, stream>>>(ei, counts);
  scanA_kernel<<<SCAN_BLOCKS, 256, 0, stream>>>(counts, rowptr, blockSum);
  scanB_kernel<<<1, 256, 0, stream>>>(blockSum, blockOff);
  scanC_kernel<<<SCAN_BLOCKS, 256, 0, stream>>>(rowptr, blockOff);
  scatter_kernel<<<(NEDGES + 255) / 256, 256, 0, stream>>>(ei, rowptr, fill, col);

  // ---- layer 1: 64 -> 16 ----
  gemm_t_kernel<64, 16><<<1024, 256, 0, stream>>>(x, W1, t);
  s_kernel<64><<<(NNODES * 4 + 255) / 256, 256, 0, stream>>>(x, u1, s);
  gather_kernel<16><<<(NNODES + 15) / 16, 256, 0, stream>>>(rowptr, col, s, t, c1, b1, hA);

  // ---- layer 2: 16 -> 32 ----
  gemm_t_kernel<16, 32><<<1024, 256, 0, stream>>>(hA, W2, t);
  s_kernel<16><<<(NNODES * 4 + 255) / 256, 256, 0, stream>>>(hA, u2, s);
  gather_kernel<32><<<(NNODES + 7) / 8, 256, 0, stream>>>(rowptr, col, s, t, c2, b2, hB);

  // ---- layer 3: 32 -> 64 ----
  gemm_t_kernel<32, 64><<<1024, 256, 0, stream>>>(hB, W3, t);
  s_kernel<32><<<(NNODES * 4 + 255) / 256, 256, 0, stream>>>(hB, u3, s);
  gather_kernel<64><<<(NNODES + 3) / 4, 256, 0, stream>>>(rowptr, col, s, t, c3, b3, hA);

  // ---- BN stats + MLP head ----
  stats_kernel<<<256, 256, 0, stream>>>(hA, sums);
  mlp_kernel<<<(NNODES + 255) / 256, 256, 0, stream>>>(hA, sums, gamma, beta, lw1, lb1,
                                                       lw2, lb2, lw3, lb3, lw4, lb4,
                                                       ow, ob, out);
}

// Round 3
// 441.011 us; speedup vs baseline: 1.3002x; 1.1464x over previous
//
#include <hip/hip_runtime.h>

#define NNODES 50000
#define NEDGES 800000
#define SCAN_BLOCKS ((NNODES + 255) / 256)   // 196

// ---------------- CSR build: histogram over dst ----------------
__global__ __launch_bounds__(256) void hist_kernel(const int* __restrict__ ei,
                                                   int* __restrict__ counts) {
  int e = blockIdx.x * 256 + threadIdx.x;
  if (e < NEDGES) atomicAdd(&counts[ei[NEDGES + e]], 1);
}

__global__ __launch_bounds__(256) void scanA_kernel(const int* __restrict__ counts,
                                                    int* __restrict__ rowptr,
                                                    int* __restrict__ blockSum) {
  __shared__ int sm[256];
  int i = blockIdx.x * 256 + threadIdx.x;
  int v = (i < NNODES) ? counts[i] : 0;
  sm[threadIdx.x] = v;
  __syncthreads();
  for (int off = 1; off < 256; off <<= 1) {
    int x = (threadIdx.x >= off) ? sm[threadIdx.x - off] : 0;
    __syncthreads();
    sm[threadIdx.x] += x;
    __syncthreads();
  }
  if (i < NNODES) rowptr[i] = sm[threadIdx.x] - v;
  if (threadIdx.x == 255) blockSum[blockIdx.x] = sm[255];
}

__global__ __launch_bounds__(256) void scanB_kernel(int* __restrict__ blockSum,
                                                    int* __restrict__ blockOff) {
  __shared__ int sm[256];
  int v = (threadIdx.x < SCAN_BLOCKS) ? blockSum[threadIdx.x] : 0;
  sm[threadIdx.x] = v;
  __syncthreads();
  for (int off = 1; off < 256; off <<= 1) {
    int x = (threadIdx.x >= off) ? sm[threadIdx.x - off] : 0;
    __syncthreads();
    sm[threadIdx.x] += x;
    __syncthreads();
  }
  if (threadIdx.x < SCAN_BLOCKS) blockOff[threadIdx.x] = sm[threadIdx.x] - v;
}

__global__ __launch_bounds__(256) void scanC_kernel(int* __restrict__ rowptr,
                                                    const int* __restrict__ blockOff) {
  int i = blockIdx.x * 256 + threadIdx.x;
  if (i < NNODES) rowptr[i] += blockOff[blockIdx.x];
  if (i == 0) rowptr[NNODES] = NEDGES;
}

// scatter src ids (and dst per slot) into dst-sorted arrays
__global__ __launch_bounds__(256) void scatter_kernel(const int* __restrict__ ei,
                                                      const int* __restrict__ rowptr,
                                                      int* __restrict__ fill,
                                                      int* __restrict__ col,
                                                      int* __restrict__ dstArr) {
  int e = blockIdx.x * 256 + threadIdx.x;
  if (e < NEDGES) {
    int dst = ei[NEDGES + e];
    int pos = rowptr[dst] + atomicAdd(&fill[dst], 1);
    col[pos] = ei[e];
    dstArr[pos] = dst;
  }
}

// ---------------- t = x @ W1, stored [N][16][4] (layer 1 only) ----------------
template<int FIN, int OUT>
__global__ __launch_bounds__(256) void gemm_t_kernel(const float* __restrict__ x,
                                                     const float* __restrict__ W,
                                                     float* __restrict__ t) {
  constexpr int COLS = 4 * OUT;
  constexpr int GROUPS = 256 / COLS;
  const int cIdx = threadIdx.x & (COLS - 1);
  const int g = threadIdx.x / COLS;
  const int o = cIdx >> 2, h = cIdx & 3;
  float wreg[FIN];
#pragma unroll
  for (int f = 0; f < FIN; ++f) wreg[f] = W[f * COLS + h * OUT + o];
  for (int n = blockIdx.x * GROUPS + g; n < NNODES; n += gridDim.x * GROUPS) {
    const float4* xr = (const float4*)(x + (size_t)n * FIN);
    float acc = 0.f;
#pragma unroll
    for (int f4 = 0; f4 < FIN / 4; ++f4) {
      float4 xv = xr[f4];
      acc += wreg[4 * f4 + 0] * xv.x + wreg[4 * f4 + 1] * xv.y +
             wreg[4 * f4 + 2] * xv.z + wreg[4 * f4 + 3] * xv.w;
    }
    t[(size_t)n * COLS + cIdx] = acc;
  }
}

// ---------------- s = x @ u  ([N,4]) ----------------
template<int FIN>
__global__ __launch_bounds__(256) void s_kernel(const float* __restrict__ x,
                                                const float* __restrict__ u,
                                                float* __restrict__ s) {
  int tid = blockIdx.x * 256 + threadIdx.x;
  int n = tid >> 2, h = tid & 3;
  if (n >= NNODES) return;
  const float4* xr = (const float4*)(x + (size_t)n * FIN);
  float acc = 0.f;
#pragma unroll
  for (int f4 = 0; f4 < FIN / 4; ++f4) {
    float4 xv = xr[f4];
    acc += xv.x * u[(4 * f4 + 0) * 4 + h] + xv.y * u[(4 * f4 + 1) * 4 + h] +
           xv.z * u[(4 * f4 + 2) * 4 + h] + xv.w * u[(4 * f4 + 3) * 4 + h];
  }
  s[tid] = acc;  // tid == n*4+h
}

// ---------------- per-edge attention weights q[idx] = softmax(s[src]-s[dst]+c) ----------------
__global__ __launch_bounds__(256) void q_kernel(const int* __restrict__ col,
                                                const int* __restrict__ dstArr,
                                                const float* __restrict__ s,
                                                const float* __restrict__ cptr,
                                                float* __restrict__ q) {
  int idx = blockIdx.x * 256 + threadIdx.x;
  if (idx >= NEDGES) return;
  int src = col[idx], dst = dstArr[idx];
  float4 c4 = *(const float4*)cptr;
  float4 ss = *(const float4*)(s + 4 * (size_t)src);
  float4 sd = *(const float4*)(s + 4 * (size_t)dst);
  float l0 = ss.x - sd.x + c4.x;
  float l1 = ss.y - sd.y + c4.y;
  float l2 = ss.z - sd.z + c4.z;
  float l3 = ss.w - sd.w + c4.w;
  float mx = fmaxf(fmaxf(l0, l1), fmaxf(l2, l3));
  float e0 = __expf(l0 - mx), e1 = __expf(l1 - mx);
  float e2 = __expf(l2 - mx), e3 = __expf(l3 - mx);
  float inv = 1.f / (e0 + e1 + e2 + e3);
  *(float4*)(q + 4 * (size_t)idx) = make_float4(e0 * inv, e1 * inv, e2 * inv, e3 * inv);
}

// ---------------- layer-1 gather over t (16 lanes per dst node) ----------------
__global__ __launch_bounds__(256) void gather1_kernel(const int* __restrict__ rowptr,
                                                      const int* __restrict__ col,
                                                      const float* __restrict__ q,
                                                      const float* __restrict__ t,
                                                      const float* __restrict__ cptr,
                                                      const float* __restrict__ bptr,
                                                      float* __restrict__ h) {
  const int lane = threadIdx.x & 15;
  const int sub = threadIdx.x >> 4;
  const int n = blockIdx.x * 16 + sub;
  if (n >= NNODES) return;
  float4 c4 = *(const float4*)cptr;
  float mxc = fmaxf(fmaxf(c4.x, c4.y), fmaxf(c4.z, c4.w));
  float qs0 = __expf(c4.x - mxc), qs1 = __expf(c4.y - mxc);
  float qs2 = __expf(c4.z - mxc), qs3 = __expf(c4.w - mxc);
  float sinv = 1.f / (qs0 + qs1 + qs2 + qs3);
  float4 tv = *((const float4*)(t + (size_t)n * 64) + lane);
  float acc = (qs0 * tv.x + qs1 * tv.y + qs2 * tv.z + qs3 * tv.w) * sinv;
  const int beg = rowptr[n], end = rowptr[n + 1];
  for (int idx = beg; idx < end; ++idx) {
    int src = col[idx];
    float4 qv = *(const float4*)(q + 4 * (size_t)idx);
    float4 tw = *((const float4*)(t + (size_t)src * 64) + lane);
    acc += qv.x * tw.x + qv.y * tw.y + qv.z * tw.z + qv.w * tw.w;
  }
  float d = (float)(end - beg + 1);
  h[(size_t)n * 16 + lane] = fmaxf(acc / d + bptr[lane], 0.f);
}

// ---------------- g-gather: g[n][h][f] = sum_j q_jh * x_j[f]  (FIN lanes per node) ----------------
template<int FIN>
__global__ __launch_bounds__(256) void gatherG_kernel(const int* __restrict__ rowptr,
                                                      const int* __restrict__ col,
                                                      const float* __restrict__ q,
                                                      const float* __restrict__ x,
                                                      const float* __restrict__ cptr,
                                                      float* __restrict__ g) {
  constexpr int NSUB = 256 / FIN;
  const int f = threadIdx.x & (FIN - 1);
  const int sub = threadIdx.x / FIN;
  const int n = blockIdx.x * NSUB + sub;
  if (n >= NNODES) return;
  float4 c4 = *(const float4*)cptr;
  float mxc = fmaxf(fmaxf(c4.x, c4.y), fmaxf(c4.z, c4.w));
  float qs0 = __expf(c4.x - mxc), qs1 = __expf(c4.y - mxc);
  float qs2 = __expf(c4.z - mxc), qs3 = __expf(c4.w - mxc);
  float sinv = 1.f / (qs0 + qs1 + qs2 + qs3);
  float xn = x[(size_t)n * FIN + f];
  float g0 = qs0 * sinv * xn, g1 = qs1 * sinv * xn;
  float g2 = qs2 * sinv * xn, g3 = qs3 * sinv * xn;
  const int beg = rowptr[n], end = rowptr[n + 1];
  for (int idx = beg; idx < end; ++idx) {
    int src = col[idx];
    float4 qv = *(const float4*)(q + 4 * (size_t)idx);
    float xv = x[(size_t)src * FIN + f];
    g0 += qv.x * xv; g1 += qv.y * xv; g2 += qv.z * xv; g3 += qv.w * xv;
  }
  float* gr = g + (size_t)n * 4 * FIN;
  gr[0 * FIN + f] = g0;
  gr[1 * FIN + f] = g1;
  gr[2 * FIN + f] = g2;
  gr[3 * FIN + f] = g3;
}

// ---------------- per-node transform: h[n][o] = relu((sum_h W_h g_h)/deg + b) ----------------
template<int FIN, int OUT, bool STATS>
__global__ __launch_bounds__(256) void transform_kernel(const float* __restrict__ g,
                                                        const int* __restrict__ rowptr,
                                                        const float* __restrict__ W,
                                                        const float* __restrict__ bptr,
                                                        float* __restrict__ h,
                                                        float* __restrict__ sums) {
  constexpr int COLS = 4 * OUT;
  constexpr int NSUB = 256 / OUT;
  __shared__ float ws[FIN * COLS];
  for (int i = threadIdx.x; i < FIN * COLS; i += 256) ws[i] = W[i];
  __syncthreads();
  const int o = threadIdx.x & (OUT - 1);
  const int sub = threadIdx.x / OUT;
  const float b = bptr[o];
  float accS = 0.f, accQ = 0.f;
  for (int n0 = blockIdx.x * NSUB; n0 < NNODES; n0 += gridDim.x * NSUB) {
    int n = n0 + sub;
    if (n < NNODES) {
      const float* gr = g + (size_t)n * 4 * FIN;
      float acc = 0.f;
#pragma unroll
      for (int hh = 0; hh < 4; ++hh) {
#pragma unroll
        for (int f4 = 0; f4 < FIN / 4; ++f4) {
          float4 gv = *(const float4*)(gr + hh * FIN + 4 * f4);
          acc += gv.x * ws[(4 * f4 + 0) * COLS + hh * OUT + o] +
                 gv.y * ws[(4 * f4 + 1) * COLS + hh * OUT + o] +
                 gv.z * ws[(4 * f4 + 2) * COLS + hh * OUT + o] +
                 gv.w * ws[(4 * f4 + 3) * COLS + hh * OUT + o];
        }
      }
      float d = (float)(rowptr[n + 1] - rowptr[n] + 1);
      float v = fmaxf(acc / d + b, 0.f);
      h[(size_t)n * OUT + o] = v;
      if (STATS) { accS += v; accQ += v * v; }
    }
  }
  if (STATS) {
    __shared__ float ls[256], lq[256];
    ls[threadIdx.x] = accS;
    lq[threadIdx.x] = accQ;
    __syncthreads();
    if (threadIdx.x < OUT) {
      float a = ls[threadIdx.x], qq = lq[threadIdx.x];
#pragma unroll
      for (int rr = 1; rr < NSUB; ++rr) {
        a += ls[threadIdx.x + rr * OUT];
        qq += lq[threadIdx.x + rr * OUT];
      }
      atomicAdd(&sums[threadIdx.x], a);
      atomicAdd(&sums[64 + threadIdx.x], qq);
    }
  }
}

// ---------------- BN + MLP head + sigmoid, one thread per node ----------------
__global__ __launch_bounds__(256) void mlp_kernel(
    const float* __restrict__ h3, const float* __restrict__ sums,
    const float* __restrict__ gamma, const float* __restrict__ beta,
    const float* __restrict__ lw1, const float* __restrict__ lb1,
    const float* __restrict__ lw2, const float* __restrict__ lb2,
    const float* __restrict__ lw3, const float* __restrict__ lb3,
    const float* __restrict__ lw4, const float* __restrict__ lb4,
    const float* __restrict__ ow, const float* __restrict__ ob,
    float* __restrict__ out) {
  __shared__ float w1[64 * 32], w2[32 * 16], w3[16 * 8], w4[8 * 4];
  __shared__ float b1s[32], b2s[16], b3s[8], b4s[4], wos[4];
  __shared__ float scale[64], shift[64];
  int tid = threadIdx.x;
  for (int i = tid; i < 64 * 32; i += 256) w1[i] = lw1[i];
  for (int i = tid; i < 32 * 16; i += 256) w2[i] = lw2[i];
  if (tid < 128) w3[tid] = lw3[tid];
  if (tid < 32) { w4[tid] = lw4[tid]; b1s[tid] = lb1[tid]; }
  if (tid < 16) b2s[tid] = lb2[tid];
  if (tid < 8) b3s[tid] = lb3[tid];
  if (tid < 4) { b4s[tid] = lb4[tid]; wos[tid] = ow[tid]; }
  if (tid < 64) {
    float mu = sums[tid] * (1.f / NNODES);
    float var = sums[64 + tid] * (1.f / NNODES) - mu * mu;
    float sc = rsqrtf(var + 1e-5f) * gamma[tid];
    scale[tid] = sc;
    shift[tid] = beta[tid] - mu * sc;
  }
  __syncthreads();
  int n = blockIdx.x * 256 + tid;
  if (n >= NNODES) return;
  float obv = ob[0];
  const float4* hr = (const float4*)(h3 + (size_t)n * 64);
  float z1[32];
#pragma unroll
  for (int j = 0; j < 32; ++j) z1[j] = b1s[j];
  for (int i4 = 0; i4 < 16; ++i4) {
    float4 hv = hr[i4];
    float a0 = hv.x * scale[4 * i4 + 0] + shift[4 * i4 + 0];
    float a1 = hv.y * scale[4 * i4 + 1] + shift[4 * i4 + 1];
    float a2 = hv.z * scale[4 * i4 + 2] + shift[4 * i4 + 2];
    float a3 = hv.w * scale[4 * i4 + 3] + shift[4 * i4 + 3];
#pragma unroll
    for (int j = 0; j < 32; ++j) {
      z1[j] += a0 * w1[(4 * i4 + 0) * 32 + j] + a1 * w1[(4 * i4 + 1) * 32 + j] +
               a2 * w1[(4 * i4 + 2) * 32 + j] + a3 * w1[(4 * i4 + 3) * 32 + j];
    }
  }
  float z2[16];
#pragma unroll
  for (int j = 0; j < 16; ++j) z2[j] = b2s[j];
  for (int i = 0; i < 32; ++i) {
    float a = fmaxf(z1[i], 0.f);
#pragma unroll
    for (int j = 0; j < 16; ++j) z2[j] += a * w2[i * 16 + j];
  }
  float z3[8];
#pragma unroll
  for (int j = 0; j < 8; ++j) z3[j] = b3s[j];
  for (int i = 0; i < 16; ++i) {
    float a = fmaxf(z2[i], 0.f);
#pragma unroll
    for (int j = 0; j < 8; ++j) z3[j] += a * w3[i * 8 + j];
  }
  float z4[4];
#pragma unroll
  for (int j = 0; j < 4; ++j) z4[j] = b4s[j];
  for (int i = 0; i < 8; ++i) {
    float a = fmaxf(z3[i], 0.f);
#pragma unroll
    for (int j = 0; j < 4; ++j) z4[j] += a * w4[i * 4 + j];
  }
  float zo = obv;
#pragma unroll
  for (int i = 0; i < 4; ++i) zo += fmaxf(z4[i], 0.f) * wos[i];
  out[n] = 1.f / (1.f + __expf(-zo));
}

extern "C" void kernel_launch(void* const* d_in, const int* in_sizes, int n_in,
                              void* d_out, int out_size, void* d_ws, size_t ws_size,
                              hipStream_t stream) {
  const float* x  = (const float*)d_in[0];
  const int*   ei = (const int*)d_in[1];
  const float* W1 = (const float*)d_in[2];  const float* u1 = (const float*)d_in[3];
  const float* c1 = (const float*)d_in[4];  const float* b1 = (const float*)d_in[5];
  const float* W2 = (const float*)d_in[6];  const float* u2 = (const float*)d_in[7];
  const float* c2 = (const float*)d_in[8];  const float* b2 = (const float*)d_in[9];
  const float* W3 = (const float*)d_in[10]; const float* u3 = (const float*)d_in[11];
  const float* c3 = (const float*)d_in[12]; const float* b3 = (const float*)d_in[13];
  const float* gamma = (const float*)d_in[14]; const float* beta = (const float*)d_in[15];
  const float* lw1 = (const float*)d_in[16]; const float* lb1 = (const float*)d_in[17];
  const float* lw2 = (const float*)d_in[18]; const float* lb2 = (const float*)d_in[19];
  const float* lw3 = (const float*)d_in[20]; const float* lb3 = (const float*)d_in[21];
  const float* lw4 = (const float*)d_in[22]; const float* lb4 = (const float*)d_in[23];
  const float* ow  = (const float*)d_in[24]; const float* ob  = (const float*)d_in[25];
  float* out = (float*)d_out;

  float* t    = (float*)d_ws;                         // N*64   (layer-1 t)
  float* g    = t + (size_t)NNODES * 64;              // N*128  (g buffer, max 4*32)
  float* hA   = g + (size_t)NNODES * 128;             // N*64
  float* hB   = hA + (size_t)NNODES * 64;             // N*64
  float* s    = hB + (size_t)NNODES * 64;             // N*4
  float* q    = s + (size_t)NNODES * 4;               // E*4
  float* sums = q + (size_t)NEDGES * 4;               // 128
  int*   rowptr   = (int*)(sums + 128);               // N+1 (pad 8)
  int*   counts   = rowptr + NNODES + 8;              // N
  int*   fill     = counts + NNODES;                  // N
  int*   blockSum = fill + NNODES;                    // 256
  int*   blockOff = blockSum + 256;                   // 256
  int*   col      = blockOff + 256;                   // E
  int*   dstArr   = col + NEDGES;                     // E

  hipMemsetAsync(counts, 0, NNODES * sizeof(int), stream);
  hipMemsetAsync(fill, 0, NNODES * sizeof(int), stream);
  hipMemsetAsync(sums, 0, 128 * sizeof(float), stream);

  // ---- CSR by dst ----
  hist_kernel<<<(NEDGES + 255) / 256, 256, 0, stream>>>(ei, counts);
  scanA_kernel<<<SCAN_BLOCKS, 256, 0, stream>>>(counts, rowptr, blockSum);
  scanB_kernel<<<1, 256, 0, stream>>>(blockSum, blockOff);
  scanC_kernel<<<SCAN_BLOCKS, 256, 0, stream>>>(rowptr, blockOff);
  scatter_kernel<<<(NEDGES + 255) / 256, 256, 0, stream>>>(ei, rowptr, fill, col, dstArr);

  // ---- layer 1: 64 -> 16 (t-gather) ----
  gemm_t_kernel<64, 16><<<1024, 256, 0, stream>>>(x, W1, t);
  s_kernel<64><<<(NNODES * 4 + 255) / 256, 256, 0, stream>>>(x, u1, s);
  q_kernel<<<(NEDGES + 255) / 256, 256, 0, stream>>>(col, dstArr, s, c1, q);
  gather1_kernel<<<(NNODES + 15) / 16, 256, 0, stream>>>(rowptr, col, q, t, c1, b1, hA);

  // ---- layer 2: 16 -> 32 (g-gather) ----
  s_kernel<16><<<(NNODES * 4 + 255) / 256, 256, 0, stream>>>(hA, u2, s);
  q_kernel<<<(NEDGES + 255) / 256, 256, 0, stream>>>(col, dstArr, s, c2, q);
  gatherG_kernel<16><<<(NNODES + 15) / 16, 256, 0, stream>>>(rowptr, col, q, hA, c2, g);
  transform_kernel<16, 32, false><<<(NNODES + 7) / 8, 256, 0, stream>>>(g, rowptr, W2, b2, hB, nullptr);

  // ---- layer 3: 32 -> 64 (g-gather) ----
  s_kernel<32><<<(NNODES * 4 + 255) / 256, 256, 0, stream>>>(hB, u3, s);
  q_kernel<<<(NEDGES + 255) / 256, 256, 0, stream>>>(col, dstArr, s, c3, q);
  gatherG_kernel<32><<<(NNODES + 7) / 8, 256, 0, stream>>>(rowptr, col, q, hB, c3, g);
  transform_kernel<32, 64, true><<<256, 256, 0, stream>>>(g, rowptr, W3, b3, hA, sums);

  // ---- BN (stats fused above) + MLP head ----
  mlp_kernel<<<(NNODES + 255) / 256, 256, 0, stream>>>(hA, sums, gamma, beta, lw1, lb1,
                                                       lw2, lb2, lw3, lb3, lw4, lb4,
                                                       ow, ob, out);
}

// Round 4
// 405.707 us; speedup vs baseline: 1.4133x; 1.0870x over previous
//
#include <hip/hip_runtime.h>

#define NNODES 50000
#define NEDGES 800000
#define SCAN_BLOCKS ((NNODES + 255) / 256)   // 196

// ---------------- CSR build: histogram over dst ----------------
__global__ __launch_bounds__(256) void hist_kernel(const int* __restrict__ ei,
                                                   int* __restrict__ counts) {
  int e = blockIdx.x * 256 + threadIdx.x;
  if (e < NEDGES) atomicAdd(&counts[ei[NEDGES + e]], 1);
}

__global__ __launch_bounds__(256) void scanA_kernel(const int* __restrict__ counts,
                                                    int* __restrict__ rowptr,
                                                    int* __restrict__ blockSum) {
  __shared__ int sm[256];
  int i = blockIdx.x * 256 + threadIdx.x;
  int v = (i < NNODES) ? counts[i] : 0;
  sm[threadIdx.x] = v;
  __syncthreads();
  for (int off = 1; off < 256; off <<= 1) {
    int x = (threadIdx.x >= off) ? sm[threadIdx.x - off] : 0;
    __syncthreads();
    sm[threadIdx.x] += x;
    __syncthreads();
  }
  if (i < NNODES) rowptr[i] = sm[threadIdx.x] - v;
  if (threadIdx.x == 255) blockSum[blockIdx.x] = sm[255];
}

__global__ __launch_bounds__(256) void scanB_kernel(int* __restrict__ blockSum,
                                                    int* __restrict__ blockOff) {
  __shared__ int sm[256];
  int v = (threadIdx.x < SCAN_BLOCKS) ? blockSum[threadIdx.x] : 0;
  sm[threadIdx.x] = v;
  __syncthreads();
  for (int off = 1; off < 256; off <<= 1) {
    int x = (threadIdx.x >= off) ? sm[threadIdx.x - off] : 0;
    __syncthreads();
    sm[threadIdx.x] += x;
    __syncthreads();
  }
  if (threadIdx.x < SCAN_BLOCKS) blockOff[threadIdx.x] = sm[threadIdx.x] - v;
}

__global__ __launch_bounds__(256) void scanC_kernel(int* __restrict__ rowptr,
                                                    const int* __restrict__ blockOff) {
  int i = blockIdx.x * 256 + threadIdx.x;
  if (i < NNODES) rowptr[i] += blockOff[blockIdx.x];
  if (i == 0) rowptr[NNODES] = NEDGES;
}

__global__ __launch_bounds__(256) void scatter_kernel(const int* __restrict__ ei,
                                                      const int* __restrict__ rowptr,
                                                      int* __restrict__ fill,
                                                      int* __restrict__ col,
                                                      int* __restrict__ dstArr) {
  int e = blockIdx.x * 256 + threadIdx.x;
  if (e < NEDGES) {
    int dst = ei[NEDGES + e];
    int pos = rowptr[dst] + atomicAdd(&fill[dst], 1);
    col[pos] = ei[e];
    dstArr[pos] = dst;
  }
}

// ---------------- t = x @ W1, stored [N][16][4] (layer 1 only) ----------------
template<int FIN, int OUT>
__global__ __launch_bounds__(256) void gemm_t_kernel(const float* __restrict__ x,
                                                     const float* __restrict__ W,
                                                     float* __restrict__ t) {
  constexpr int COLS = 4 * OUT;
  constexpr int GROUPS = 256 / COLS;
  const int cIdx = threadIdx.x & (COLS - 1);
  const int g = threadIdx.x / COLS;
  const int o = cIdx >> 2, h = cIdx & 3;
  float wreg[FIN];
#pragma unroll
  for (int f = 0; f < FIN; ++f) wreg[f] = W[f * COLS + h * OUT + o];
  for (int n = blockIdx.x * GROUPS + g; n < NNODES; n += gridDim.x * GROUPS) {
    const float4* xr = (const float4*)(x + (size_t)n * FIN);
    float acc = 0.f;
#pragma unroll
    for (int f4 = 0; f4 < FIN / 4; ++f4) {
      float4 xv = xr[f4];
      acc += wreg[4 * f4 + 0] * xv.x + wreg[4 * f4 + 1] * xv.y +
             wreg[4 * f4 + 2] * xv.z + wreg[4 * f4 + 3] * xv.w;
    }
    t[(size_t)n * COLS + cIdx] = acc;
  }
}

// ---------------- s = x @ u  ([N,4]) ----------------
template<int FIN>
__global__ __launch_bounds__(256) void s_kernel(const float* __restrict__ x,
                                                const float* __restrict__ u,
                                                float* __restrict__ s) {
  int tid = blockIdx.x * 256 + threadIdx.x;
  int n = tid >> 2, h = tid & 3;
  if (n >= NNODES) return;
  const float4* xr = (const float4*)(x + (size_t)n * FIN);
  float acc = 0.f;
#pragma unroll
  for (int f4 = 0; f4 < FIN / 4; ++f4) {
    float4 xv = xr[f4];
    acc += xv.x * u[(4 * f4 + 0) * 4 + h] + xv.y * u[(4 * f4 + 1) * 4 + h] +
           xv.z * u[(4 * f4 + 2) * 4 + h] + xv.w * u[(4 * f4 + 3) * 4 + h];
  }
  s[tid] = acc;  // tid == n*4+h
}

// ---------------- per-edge attention weights q[idx] = softmax(s[src]-s[dst]+c) ----------------
__global__ __launch_bounds__(256) void q_kernel(const int* __restrict__ col,
                                                const int* __restrict__ dstArr,
                                                const float* __restrict__ s,
                                                const float* __restrict__ cptr,
                                                float* __restrict__ q) {
  int idx = blockIdx.x * 256 + threadIdx.x;
  if (idx >= NEDGES) return;
  int src = col[idx], dst = dstArr[idx];
  float4 c4 = *(const float4*)cptr;
  float4 ss = *(const float4*)(s + 4 * (size_t)src);
  float4 sd = *(const float4*)(s + 4 * (size_t)dst);
  float l0 = ss.x - sd.x + c4.x;
  float l1 = ss.y - sd.y + c4.y;
  float l2 = ss.z - sd.z + c4.z;
  float l3 = ss.w - sd.w + c4.w;
  float mx = fmaxf(fmaxf(l0, l1), fmaxf(l2, l3));
  float e0 = __expf(l0 - mx), e1 = __expf(l1 - mx);
  float e2 = __expf(l2 - mx), e3 = __expf(l3 - mx);
  float inv = 1.f / (e0 + e1 + e2 + e3);
  *(float4*)(q + 4 * (size_t)idx) = make_float4(e0 * inv, e1 * inv, e2 * inv, e3 * inv);
}

// ---------------- layer-1 gather over t (16 lanes per dst node) ----------------
__global__ __launch_bounds__(256) void gather1_kernel(const int* __restrict__ rowptr,
                                                      const int* __restrict__ col,
                                                      const float* __restrict__ q,
                                                      const float* __restrict__ t,
                                                      const float* __restrict__ cptr,
                                                      const float* __restrict__ bptr,
                                                      float* __restrict__ h) {
  const int lane = threadIdx.x & 15;
  const int sub = threadIdx.x >> 4;
  const int n = blockIdx.x * 16 + sub;
  if (n >= NNODES) return;
  float4 c4 = *(const float4*)cptr;
  float mxc = fmaxf(fmaxf(c4.x, c4.y), fmaxf(c4.z, c4.w));
  float qs0 = __expf(c4.x - mxc), qs1 = __expf(c4.y - mxc);
  float qs2 = __expf(c4.z - mxc), qs3 = __expf(c4.w - mxc);
  float sinv = 1.f / (qs0 + qs1 + qs2 + qs3);
  float4 tv = *((const float4*)(t + (size_t)n * 64) + lane);
  float acc = (qs0 * tv.x + qs1 * tv.y + qs2 * tv.z + qs3 * tv.w) * sinv;
  const int beg = rowptr[n], end = rowptr[n + 1];
  for (int idx = beg; idx < end; ++idx) {
    int src = col[idx];
    float4 qv = *(const float4*)(q + 4 * (size_t)idx);
    float4 tw = *((const float4*)(t + (size_t)src * 64) + lane);
    acc += qv.x * tw.x + qv.y * tw.y + qv.z * tw.z + qv.w * tw.w;
  }
  float d = (float)(end - beg + 1);
  h[(size_t)n * 16 + lane] = fmaxf(acc / d + bptr[lane], 0.f);
}

// ---------------- g-gather: g[n][h][f] = sum_j q_jh * x_j[f]  (FIN lanes per node) ----------------
template<int FIN>
__global__ __launch_bounds__(256) void gatherG_kernel(const int* __restrict__ rowptr,
                                                      const int* __restrict__ col,
                                                      const float* __restrict__ q,
                                                      const float* __restrict__ x,
                                                      const float* __restrict__ cptr,
                                                      float* __restrict__ g) {
  constexpr int NSUB = 256 / FIN;
  const int f = threadIdx.x & (FIN - 1);
  const int sub = threadIdx.x / FIN;
  const int n = blockIdx.x * NSUB + sub;
  if (n >= NNODES) return;
  float4 c4 = *(const float4*)cptr;
  float mxc = fmaxf(fmaxf(c4.x, c4.y), fmaxf(c4.z, c4.w));
  float qs0 = __expf(c4.x - mxc), qs1 = __expf(c4.y - mxc);
  float qs2 = __expf(c4.z - mxc), qs3 = __expf(c4.w - mxc);
  float sinv = 1.f / (qs0 + qs1 + qs2 + qs3);
  float xn = x[(size_t)n * FIN + f];
  float g0 = qs0 * sinv * xn, g1 = qs1 * sinv * xn;
  float g2 = qs2 * sinv * xn, g3 = qs3 * sinv * xn;
  const int beg = rowptr[n], end = rowptr[n + 1];
  for (int idx = beg; idx < end; ++idx) {
    int src = col[idx];
    float4 qv = *(const float4*)(q + 4 * (size_t)idx);
    float xv = x[(size_t)src * FIN + f];
    g0 += qv.x * xv; g1 += qv.y * xv; g2 += qv.z * xv; g3 += qv.w * xv;
  }
  float* gr = g + (size_t)n * 4 * FIN;
  gr[0 * FIN + f] = g0;
  gr[1 * FIN + f] = g1;
  gr[2 * FIN + f] = g2;
  gr[3 * FIN + f] = g3;
}

// ---------------- per-node transform: h[n][o] = relu((sum_h W_h g_h)/deg + b) ----------------
// Register-tiled: each thread computes output o for NPT=4 nodes, reusing each
// LDS W read across 4 FMAs. Direct grid (no grid-stride) for occupancy.
template<int FIN, int OUT>
__global__ __launch_bounds__(256) void transform_kernel(const float* __restrict__ g,
                                                        const int* __restrict__ rowptr,
                                                        const float* __restrict__ W,
                                                        const float* __restrict__ bptr,
                                                        float* __restrict__ h) {
  constexpr int COLS = 4 * OUT;
  constexpr int NSUB = 256 / OUT;
  constexpr int NPT = 4;
  __shared__ float ws[FIN * COLS];
  for (int i = threadIdx.x; i < FIN * COLS; i += 256) ws[i] = W[i];
  __syncthreads();
  const int o = threadIdx.x & (OUT - 1);
  const int sub = threadIdx.x / OUT;
  const int nb = blockIdx.x * (NSUB * NPT) + sub * NPT;
  if (nb >= NNODES) return;
  const float* gp[NPT];
#pragma unroll
  for (int p = 0; p < NPT; ++p) {
    int n = nb + p;
    gp[p] = g + (size_t)(n < NNODES ? n : NNODES - 1) * 4 * FIN;
  }
  float acc[NPT] = {0.f, 0.f, 0.f, 0.f};
#pragma unroll 1
  for (int hh = 0; hh < 4; ++hh) {
#pragma unroll
    for (int f4 = 0; f4 < FIN / 4; ++f4) {
      const float w0 = ws[(4 * f4 + 0) * COLS + hh * OUT + o];
      const float w1 = ws[(4 * f4 + 1) * COLS + hh * OUT + o];
      const float w2 = ws[(4 * f4 + 2) * COLS + hh * OUT + o];
      const float w3 = ws[(4 * f4 + 3) * COLS + hh * OUT + o];
#pragma unroll
      for (int p = 0; p < NPT; ++p) {
        float4 gv = *(const float4*)(gp[p] + hh * FIN + 4 * f4);
        acc[p] += w0 * gv.x + w1 * gv.y + w2 * gv.z + w3 * gv.w;
      }
    }
  }
  const float b = bptr[o];
#pragma unroll
  for (int p = 0; p < NPT; ++p) {
    int n = nb + p;
    if (n < NNODES) {
      float d = (float)(rowptr[n + 1] - rowptr[n] + 1);
      h[(size_t)n * OUT + o] = fmaxf(acc[p] / d + b, 0.f);
    }
  }
}

// ---------------- BN batch-stats over h3 [N,64] ----------------
__global__ __launch_bounds__(256) void stats_kernel(const float* __restrict__ h3,
                                                    float* __restrict__ sums) {
  const int o = threadIdx.x & 63;
  const int r = threadIdx.x >> 6;
  float accS = 0.f, accQ = 0.f;
  for (int base = blockIdx.x * 4; base < NNODES; base += gridDim.x * 4) {
    int n = base + r;
    if (n < NNODES) {
      float v = h3[(size_t)n * 64 + o];
      accS += v;
      accQ += v * v;
    }
  }
  __shared__ float ls[256], lq[256];
  ls[threadIdx.x] = accS;
  lq[threadIdx.x] = accQ;
  __syncthreads();
  if (threadIdx.x < 64) {
    float a = ls[threadIdx.x] + ls[threadIdx.x + 64] + ls[threadIdx.x + 128] + ls[threadIdx.x + 192];
    float qq = lq[threadIdx.x] + lq[threadIdx.x + 64] + lq[threadIdx.x + 128] + lq[threadIdx.x + 192];
    atomicAdd(&sums[threadIdx.x], a);
    atomicAdd(&sums[64 + threadIdx.x], qq);
  }
}

// ---------------- BN + MLP head + sigmoid, one thread per node ----------------
__global__ __launch_bounds__(256) void mlp_kernel(
    const float* __restrict__ h3, const float* __restrict__ sums,
    const float* __restrict__ gamma, const float* __restrict__ beta,
    const float* __restrict__ lw1, const float* __restrict__ lb1,
    const float* __restrict__ lw2, const float* __restrict__ lb2,
    const float* __restrict__ lw3, const float* __restrict__ lb3,
    const float* __restrict__ lw4, const float* __restrict__ lb4,
    const float* __restrict__ ow, const float* __restrict__ ob,
    float* __restrict__ out) {
  __shared__ float w1[64 * 32], w2[32 * 16], w3[16 * 8], w4[8 * 4];
  __shared__ float b1s[32], b2s[16], b3s[8], b4s[4], wos[4];
  __shared__ float scale[64], shift[64];
  int tid = threadIdx.x;
  for (int i = tid; i < 64 * 32; i += 256) w1[i] = lw1[i];
  for (int i = tid; i < 32 * 16; i += 256) w2[i] = lw2[i];
  if (tid < 128) w3[tid] = lw3[tid];
  if (tid < 32) { w4[tid] = lw4[tid]; b1s[tid] = lb1[tid]; }
  if (tid < 16) b2s[tid] = lb2[tid];
  if (tid < 8) b3s[tid] = lb3[tid];
  if (tid < 4) { b4s[tid] = lb4[tid]; wos[tid] = ow[tid]; }
  if (tid < 64) {
    float mu = sums[tid] * (1.f / NNODES);
    float var = sums[64 + tid] * (1.f / NNODES) - mu * mu;
    float sc = rsqrtf(var + 1e-5f) * gamma[tid];
    scale[tid] = sc;
    shift[tid] = beta[tid] - mu * sc;
  }
  __syncthreads();
  int n = blockIdx.x * 256 + tid;
  if (n >= NNODES) return;
  float obv = ob[0];
  const float4* hr = (const float4*)(h3 + (size_t)n * 64);
  float z1[32];
#pragma unroll
  for (int j = 0; j < 32; ++j) z1[j] = b1s[j];
  for (int i4 = 0; i4 < 16; ++i4) {
    float4 hv = hr[i4];
    float a0 = hv.x * scale[4 * i4 + 0] + shift[4 * i4 + 0];
    float a1 = hv.y * scale[4 * i4 + 1] + shift[4 * i4 + 1];
    float a2 = hv.z * scale[4 * i4 + 2] + shift[4 * i4 + 2];
    float a3 = hv.w * scale[4 * i4 + 3] + shift[4 * i4 + 3];
#pragma unroll
    for (int j = 0; j < 32; ++j) {
      z1[j] += a0 * w1[(4 * i4 + 0) * 32 + j] + a1 * w1[(4 * i4 + 1) * 32 + j] +
               a2 * w1[(4 * i4 + 2) * 32 + j] + a3 * w1[(4 * i4 + 3) * 32 + j];
    }
  }
  float z2[16];
#pragma unroll
  for (int j = 0; j < 16; ++j) z2[j] = b2s[j];
  for (int i = 0; i < 32; ++i) {
    float a = fmaxf(z1[i], 0.f);
#pragma unroll
    for (int j = 0; j < 16; ++j) z2[j] += a * w2[i * 16 + j];
  }
  float z3[8];
#pragma unroll
  for (int j = 0; j < 8; ++j) z3[j] = b3s[j];
  for (int i = 0; i < 16; ++i) {
    float a = fmaxf(z2[i], 0.f);
#pragma unroll
    for (int j = 0; j < 8; ++j) z3[j] += a * w3[i * 8 + j];
  }
  float z4[4];
#pragma unroll
  for (int j = 0; j < 4; ++j) z4[j] = b4s[j];
  for (int i = 0; i < 8; ++i) {
    float a = fmaxf(z3[i], 0.f);
#pragma unroll
    for (int j = 0; j < 4; ++j) z4[j] += a * w4[i * 4 + j];
  }
  float zo = obv;
#pragma unroll
  for (int i = 0; i < 4; ++i) zo += fmaxf(z4[i], 0.f) * wos[i];
  out[n] = 1.f / (1.f + __expf(-zo));
}

extern "C" void kernel_launch(void* const* d_in, const int* in_sizes, int n_in,
                              void* d_out, int out_size, void* d_ws, size_t ws_size,
                              hipStream_t stream) {
  const float* x  = (const float*)d_in[0];
  const int*   ei = (const int*)d_in[1];
  const float* W1 = (const float*)d_in[2];  const float* u1 = (const float*)d_in[3];
  const float* c1 = (const float*)d_in[4];  const float* b1 = (const float*)d_in[5];
  const float* W2 = (const float*)d_in[6];  const float* u2 = (const float*)d_in[7];
  const float* c2 = (const float*)d_in[8];  const float* b2 = (const float*)d_in[9];
  const float* W3 = (const float*)d_in[10]; const float* u3 = (const float*)d_in[11];
  const float* c3 = (const float*)d_in[12]; const float* b3 = (const float*)d_in[13];
  const float* gamma = (const float*)d_in[14]; const float* beta = (const float*)d_in[15];
  const float* lw1 = (const float*)d_in[16]; const float* lb1 = (const float*)d_in[17];
  const float* lw2 = (const float*)d_in[18]; const float* lb2 = (const float*)d_in[19];
  const float* lw3 = (const float*)d_in[20]; const float* lb3 = (const float*)d_in[21];
  const float* lw4 = (const float*)d_in[22]; const float* lb4 = (const float*)d_in[23];
  const float* ow  = (const float*)d_in[24]; const float* ob  = (const float*)d_in[25];
  float* out = (float*)d_out;

  float* t    = (float*)d_ws;                         // N*64   (layer-1 t)
  float* g    = t + (size_t)NNODES * 64;              // N*128  (g buffer, max 4*32)
  float* hA   = g + (size_t)NNODES * 128;             // N*64
  float* hB   = hA + (size_t)NNODES * 64;             // N*64
  float* s    = hB + (size_t)NNODES * 64;             // N*4
  float* q    = s + (size_t)NNODES * 4;               // E*4
  float* sums = q + (size_t)NEDGES * 4;               // 128
  int*   rowptr   = (int*)(sums + 128);               // N+1 (pad 8)
  int*   counts   = rowptr + NNODES + 8;              // N
  int*   fill     = counts + NNODES;                  // N
  int*   blockSum = fill + NNODES;                    // 256
  int*   blockOff = blockSum + 256;                   // 256
  int*   col      = blockOff + 256;                   // E
  int*   dstArr   = col + NEDGES;                     // E

  hipMemsetAsync(counts, 0, NNODES * sizeof(int), stream);
  hipMemsetAsync(fill, 0, NNODES * sizeof(int), stream);
  hipMemsetAsync(sums, 0, 128 * sizeof(float), stream);

  // ---- CSR by dst ----
  hist_kernel<<<(NEDGES + 255) / 256, 256, 0, stream>>>(ei, counts);
  scanA_kernel<<<SCAN_BLOCKS, 256, 0, stream>>>(counts, rowptr, blockSum);
  scanB_kernel<<<1, 256, 0, stream>>>(blockSum, blockOff);
  scanC_kernel<<<SCAN_BLOCKS, 256, 0, stream>>>(rowptr, blockOff);
  scatter_kernel<<<(NEDGES + 255) / 256, 256, 0, stream>>>(ei, rowptr, fill, col, dstArr);

  // ---- layer 1: 64 -> 16 (t-gather) ----
  gemm_t_kernel<64, 16><<<1024, 256, 0, stream>>>(x, W1, t);
  s_kernel<64><<<(NNODES * 4 + 255) / 256, 256, 0, stream>>>(x, u1, s);
  q_kernel<<<(NEDGES + 255) / 256, 256, 0, stream>>>(col, dstArr, s, c1, q);
  gather1_kernel<<<(NNODES + 15) / 16, 256, 0, stream>>>(rowptr, col, q, t, c1, b1, hA);

  // ---- layer 2: 16 -> 32 (g-gather) ----
  s_kernel<16><<<(NNODES * 4 + 255) / 256, 256, 0, stream>>>(hA, u2, s);
  q_kernel<<<(NEDGES + 255) / 256, 256, 0, stream>>>(col, dstArr, s, c2, q);
  gatherG_kernel<16><<<(NNODES + 15) / 16, 256, 0, stream>>>(rowptr, col, q, hA, c2, g);
  transform_kernel<16, 32><<<(NNODES + 31) / 32, 256, 0, stream>>>(g, rowptr, W2, b2, hB);

  // ---- layer 3: 32 -> 64 (g-gather) ----
  s_kernel<32><<<(NNODES * 4 + 255) / 256, 256, 0, stream>>>(hB, u3, s);
  q_kernel<<<(NEDGES + 255) / 256, 256, 0, stream>>>(col, dstArr, s, c3, q);
  gatherG_kernel<32><<<(NNODES + 7) / 8, 256, 0, stream>>>(rowptr, col, q, hB, c3, g);
  transform_kernel<32, 64><<<(NNODES + 15) / 16, 256, 0, stream>>>(g, rowptr, W3, b3, hA);

  // ---- BN stats + MLP head ----
  stats_kernel<<<256, 256, 0, stream>>>(hA, sums);
  mlp_kernel<<<(NNODES + 255) / 256, 256, 0, stream>>>(hA, sums, gamma, beta, lw1, lb1,
                                                       lw2, lb2, lw3, lb3, lw4, lb4,
                                                       ow, ob, out);
}

// Round 5
// 370.188 us; speedup vs baseline: 1.5489x; 1.0960x over previous
//
#include <hip/hip_runtime.h>

#define NNODES 50000
#define NEDGES 800000
#define SCAN_BLOCKS ((NNODES + 255) / 256)   // 196

// ---------------- CSR build: histogram over dst ----------------
__global__ __launch_bounds__(256) void hist_kernel(const int* __restrict__ ei,
                                                   int* __restrict__ counts) {
  int e = blockIdx.x * 256 + threadIdx.x;
  if (e < NEDGES) atomicAdd(&counts[ei[NEDGES + e]], 1);
}

__global__ __launch_bounds__(256) void scanA_kernel(const int* __restrict__ counts,
                                                    int* __restrict__ rowptr,
                                                    int* __restrict__ blockSum) {
  __shared__ int sm[256];
  int i = blockIdx.x * 256 + threadIdx.x;
  int v = (i < NNODES) ? counts[i] : 0;
  sm[threadIdx.x] = v;
  __syncthreads();
  for (int off = 1; off < 256; off <<= 1) {
    int x = (threadIdx.x >= off) ? sm[threadIdx.x - off] : 0;
    __syncthreads();
    sm[threadIdx.x] += x;
    __syncthreads();
  }
  if (i < NNODES) rowptr[i] = sm[threadIdx.x] - v;
  if (threadIdx.x == 255) blockSum[blockIdx.x] = sm[255];
}

__global__ __launch_bounds__(256) void scanB_kernel(int* __restrict__ blockSum,
                                                    int* __restrict__ blockOff) {
  __shared__ int sm[256];
  int v = (threadIdx.x < SCAN_BLOCKS) ? blockSum[threadIdx.x] : 0;
  sm[threadIdx.x] = v;
  __syncthreads();
  for (int off = 1; off < 256; off <<= 1) {
    int x = (threadIdx.x >= off) ? sm[threadIdx.x - off] : 0;
    __syncthreads();
    sm[threadIdx.x] += x;
    __syncthreads();
  }
  if (threadIdx.x < SCAN_BLOCKS) blockOff[threadIdx.x] = sm[threadIdx.x] - v;
}

__global__ __launch_bounds__(256) void scanC_kernel(int* __restrict__ rowptr,
                                                    const int* __restrict__ blockOff) {
  int i = blockIdx.x * 256 + threadIdx.x;
  if (i < NNODES) rowptr[i] += blockOff[blockIdx.x];
  if (i == 0) rowptr[NNODES] = NEDGES;
}

__global__ __launch_bounds__(256) void scatter_kernel(const int* __restrict__ ei,
                                                      const int* __restrict__ rowptr,
                                                      int* __restrict__ fill,
                                                      int* __restrict__ col,
                                                      int* __restrict__ dstArr) {
  int e = blockIdx.x * 256 + threadIdx.x;
  if (e < NEDGES) {
    int dst = ei[NEDGES + e];
    int pos = rowptr[dst] + atomicAdd(&fill[dst], 1);
    col[pos] = ei[e];
    dstArr[pos] = dst;
  }
}

// ---------------- t = x @ W1, stored [N][16][4] (layer 1 only) ----------------
template<int FIN, int OUT>
__global__ __launch_bounds__(256) void gemm_t_kernel(const float* __restrict__ x,
                                                     const float* __restrict__ W,
                                                     float* __restrict__ t) {
  constexpr int COLS = 4 * OUT;
  constexpr int GROUPS = 256 / COLS;
  const int cIdx = threadIdx.x & (COLS - 1);
  const int g = threadIdx.x / COLS;
  const int o = cIdx >> 2, h = cIdx & 3;
  float wreg[FIN];
#pragma unroll
  for (int f = 0; f < FIN; ++f) wreg[f] = W[f * COLS + h * OUT + o];
  for (int n = blockIdx.x * GROUPS + g; n < NNODES; n += gridDim.x * GROUPS) {
    const float4* xr = (const float4*)(x + (size_t)n * FIN);
    float acc = 0.f;
#pragma unroll
    for (int f4 = 0; f4 < FIN / 4; ++f4) {
      float4 xv = xr[f4];
      acc += wreg[4 * f4 + 0] * xv.x + wreg[4 * f4 + 1] * xv.y +
             wreg[4 * f4 + 2] * xv.z + wreg[4 * f4 + 3] * xv.w;
    }
    t[(size_t)n * COLS + cIdx] = acc;
  }
}

// ---------------- s = x @ u  ([N,4]) ----------------
template<int FIN>
__global__ __launch_bounds__(256) void s_kernel(const float* __restrict__ x,
                                                const float* __restrict__ u,
                                                float* __restrict__ s) {
  int tid = blockIdx.x * 256 + threadIdx.x;
  int n = tid >> 2, h = tid & 3;
  if (n >= NNODES) return;
  const float4* xr = (const float4*)(x + (size_t)n * FIN);
  float acc = 0.f;
#pragma unroll
  for (int f4 = 0; f4 < FIN / 4; ++f4) {
    float4 xv = xr[f4];
    acc += xv.x * u[(4 * f4 + 0) * 4 + h] + xv.y * u[(4 * f4 + 1) * 4 + h] +
           xv.z * u[(4 * f4 + 2) * 4 + h] + xv.w * u[(4 * f4 + 3) * 4 + h];
  }
  s[tid] = acc;  // tid == n*4+h
}

// ---------------- per-edge attention weights q[idx] = softmax(s[src]-s[dst]+c) ----------------
__global__ __launch_bounds__(256) void q_kernel(const int* __restrict__ col,
                                                const int* __restrict__ dstArr,
                                                const float* __restrict__ s,
                                                const float* __restrict__ cptr,
                                                float* __restrict__ q) {
  int idx = blockIdx.x * 256 + threadIdx.x;
  if (idx >= NEDGES) return;
  int src = col[idx], dst = dstArr[idx];
  float4 c4 = *(const float4*)cptr;
  float4 ss = *(const float4*)(s + 4 * (size_t)src);
  float4 sd = *(const float4*)(s + 4 * (size_t)dst);
  float l0 = ss.x - sd.x + c4.x;
  float l1 = ss.y - sd.y + c4.y;
  float l2 = ss.z - sd.z + c4.z;
  float l3 = ss.w - sd.w + c4.w;
  float mx = fmaxf(fmaxf(l0, l1), fmaxf(l2, l3));
  float e0 = __expf(l0 - mx), e1 = __expf(l1 - mx);
  float e2 = __expf(l2 - mx), e3 = __expf(l3 - mx);
  float inv = 1.f / (e0 + e1 + e2 + e3);
  *(float4*)(q + 4 * (size_t)idx) = make_float4(e0 * inv, e1 * inv, e2 * inv, e3 * inv);
}

// ---------------- layer-1 gather over t (16 lanes per dst node) ----------------
__global__ __launch_bounds__(256) void gather1_kernel(const int* __restrict__ rowptr,
                                                      const int* __restrict__ col,
                                                      const float* __restrict__ q,
                                                      const float* __restrict__ t,
                                                      const float* __restrict__ cptr,
                                                      const float* __restrict__ bptr,
                                                      float* __restrict__ h) {
  const int lane = threadIdx.x & 15;
  const int sub = threadIdx.x >> 4;
  const int n = blockIdx.x * 16 + sub;
  if (n >= NNODES) return;
  float4 c4 = *(const float4*)cptr;
  float mxc = fmaxf(fmaxf(c4.x, c4.y), fmaxf(c4.z, c4.w));
  float qs0 = __expf(c4.x - mxc), qs1 = __expf(c4.y - mxc);
  float qs2 = __expf(c4.z - mxc), qs3 = __expf(c4.w - mxc);
  float sinv = 1.f / (qs0 + qs1 + qs2 + qs3);
  float4 tv = *((const float4*)(t + (size_t)n * 64) + lane);
  float acc = (qs0 * tv.x + qs1 * tv.y + qs2 * tv.z + qs3 * tv.w) * sinv;
  const int beg = rowptr[n], end = rowptr[n + 1];
  for (int idx = beg; idx < end; ++idx) {
    int src = col[idx];
    float4 qv = *(const float4*)(q + 4 * (size_t)idx);
    float4 tw = *((const float4*)(t + (size_t)src * 64) + lane);
    acc += qv.x * tw.x + qv.y * tw.y + qv.z * tw.z + qv.w * tw.w;
  }
  float d = (float)(end - beg + 1);
  h[(size_t)n * 16 + lane] = fmaxf(acc / d + bptr[lane], 0.f);
}

// ---------------- g-gather: g[n][h][f] = sum_j q_jh * x_j[f]  (FIN lanes per node) ----------------
template<int FIN>
__global__ __launch_bounds__(256) void gatherG_kernel(const int* __restrict__ rowptr,
                                                      const int* __restrict__ col,
                                                      const float* __restrict__ q,
                                                      const float* __restrict__ x,
                                                      const float* __restrict__ cptr,
                                                      float* __restrict__ g) {
  constexpr int NSUB = 256 / FIN;
  const int f = threadIdx.x & (FIN - 1);
  const int sub = threadIdx.x / FIN;
  const int n = blockIdx.x * NSUB + sub;
  if (n >= NNODES) return;
  float4 c4 = *(const float4*)cptr;
  float mxc = fmaxf(fmaxf(c4.x, c4.y), fmaxf(c4.z, c4.w));
  float qs0 = __expf(c4.x - mxc), qs1 = __expf(c4.y - mxc);
  float qs2 = __expf(c4.z - mxc), qs3 = __expf(c4.w - mxc);
  float sinv = 1.f / (qs0 + qs1 + qs2 + qs3);
  float xn = x[(size_t)n * FIN + f];
  float g0 = qs0 * sinv * xn, g1 = qs1 * sinv * xn;
  float g2 = qs2 * sinv * xn, g3 = qs3 * sinv * xn;
  const int beg = rowptr[n], end = rowptr[n + 1];
  for (int idx = beg; idx < end; ++idx) {
    int src = col[idx];
    float4 qv = *(const float4*)(q + 4 * (size_t)idx);
    float xv = x[(size_t)src * FIN + f];
    g0 += qv.x * xv; g1 += qv.y * xv; g2 += qv.z * xv; g3 += qv.w * xv;
  }
  float* gr = g + (size_t)n * 4 * FIN;
  gr[0 * FIN + f] = g0;
  gr[1 * FIN + f] = g1;
  gr[2 * FIN + f] = g2;
  gr[3 * FIN + f] = g3;
}

// ---------------- per-node transform: h[n][o] = relu((sum_h W_h g_h)/deg + b) ----------------
// 2-D register-tiled GEMM: each thread computes MO outputs x NP nodes,
// k-vectorized by float4. W^T staged in LDS with per-16B-granule XOR swizzle
// (pg = kg ^ (o/MO)) -- unswizzled [OUT][K] would be an OG-way bank conflict
// (row stride K*4B is a multiple of 128B). A (g rows) read direct from L2;
// redundancy = OG (8 for layer3) instead of OUT (64).
template<int FIN, int OUT, int MO, int NP>
__global__ __launch_bounds__(256) void transform_kernel(const float* __restrict__ g,
                                                        const int* __restrict__ rowptr,
                                                        const float* __restrict__ W,
                                                        const float* __restrict__ bptr,
                                                        float* __restrict__ h) {
  constexpr int K = 4 * FIN;          // g row length
  constexpr int OG = OUT / MO;        // o-groups per node
  constexpr int NG = 256 / OG;        // node-groups per block
  constexpr int NPB = NG * NP;        // nodes per block
  __shared__ float wsT[OUT * K];
  for (int i = threadIdx.x; i < OUT * K; i += 256) {
    int o = i / K, k = i - o * K;
    int hh = k / FIN, f = k - hh * FIN;
    int kg = k >> 2;
    int pg = kg ^ (o / MO);           // granule swizzle
    wsT[o * K + (pg << 2) + (k & 3)] = W[f * (4 * OUT) + hh * OUT + o];
  }
  __syncthreads();
  const int og = threadIdx.x & (OG - 1);
  const int ng = threadIdx.x / OG;
  const int o0 = og * MO;
  const int nb = blockIdx.x * NPB + ng * NP;
  float acc[NP][MO];
#pragma unroll
  for (int p = 0; p < NP; ++p)
#pragma unroll
    for (int m = 0; m < MO; ++m) acc[p][m] = 0.f;
  const float* gptr[NP];
#pragma unroll
  for (int p = 0; p < NP; ++p) {
    int n = nb + p;
    gptr[p] = g + (size_t)(n < NNODES ? n : NNODES - 1) * K;
  }
#pragma unroll 2
  for (int kg = 0; kg < K / 4; ++kg) {
    float4 av[NP];
#pragma unroll
    for (int p = 0; p < NP; ++p) av[p] = *(const float4*)(gptr[p] + (kg << 2));
#pragma unroll
    for (int m = 0; m < MO; ++m) {
      const float4 wv = *(const float4*)(&wsT[(o0 + m) * K + ((kg ^ og) << 2)]);
#pragma unroll
      for (int p = 0; p < NP; ++p)
        acc[p][m] += av[p].x * wv.x + av[p].y * wv.y + av[p].z * wv.z + av[p].w * wv.w;
    }
  }
#pragma unroll
  for (int p = 0; p < NP; ++p) {
    int n = nb + p;
    if (n < NNODES) {
      float inv = 1.f / (float)(rowptr[n + 1] - rowptr[n] + 1);
#pragma unroll
      for (int m = 0; m < MO; ++m)
        h[(size_t)n * OUT + o0 + m] = fmaxf(acc[p][m] * inv + bptr[o0 + m], 0.f);
    }
  }
}

// ---------------- BN batch-stats over h3 [N,64] ----------------
__global__ __launch_bounds__(256) void stats_kernel(const float* __restrict__ h3,
                                                    float* __restrict__ sums) {
  const int o = threadIdx.x & 63;
  const int r = threadIdx.x >> 6;
  float accS = 0.f, accQ = 0.f;
  for (int base = blockIdx.x * 4; base < NNODES; base += gridDim.x * 4) {
    int n = base + r;
    if (n < NNODES) {
      float v = h3[(size_t)n * 64 + o];
      accS += v;
      accQ += v * v;
    }
  }
  __shared__ float ls[256], lq[256];
  ls[threadIdx.x] = accS;
  lq[threadIdx.x] = accQ;
  __syncthreads();
  if (threadIdx.x < 64) {
    float a = ls[threadIdx.x] + ls[threadIdx.x + 64] + ls[threadIdx.x + 128] + ls[threadIdx.x + 192];
    float qq = lq[threadIdx.x] + lq[threadIdx.x + 64] + lq[threadIdx.x + 128] + lq[threadIdx.x + 192];
    atomicAdd(&sums[threadIdx.x], a);
    atomicAdd(&sums[64 + threadIdx.x], qq);
  }
}

// ---------------- BN + MLP head + sigmoid, one thread per node ----------------
__global__ __launch_bounds__(256) void mlp_kernel(
    const float* __restrict__ h3, const float* __restrict__ sums,
    const float* __restrict__ gamma, const float* __restrict__ beta,
    const float* __restrict__ lw1, const float* __restrict__ lb1,
    const float* __restrict__ lw2, const float* __restrict__ lb2,
    const float* __restrict__ lw3, const float* __restrict__ lb3,
    const float* __restrict__ lw4, const float* __restrict__ lb4,
    const float* __restrict__ ow, const float* __restrict__ ob,
    float* __restrict__ out) {
  __shared__ float w1[64 * 32], w2[32 * 16], w3[16 * 8], w4[8 * 4];
  __shared__ float b1s[32], b2s[16], b3s[8], b4s[4], wos[4];
  __shared__ float scale[64], shift[64];
  int tid = threadIdx.x;
  for (int i = tid; i < 64 * 32; i += 256) w1[i] = lw1[i];
  for (int i = tid; i < 32 * 16; i += 256) w2[i] = lw2[i];
  if (tid < 128) w3[tid] = lw3[tid];
  if (tid < 32) { w4[tid] = lw4[tid]; b1s[tid] = lb1[tid]; }
  if (tid < 16) b2s[tid] = lb2[tid];
  if (tid < 8) b3s[tid] = lb3[tid];
  if (tid < 4) { b4s[tid] = lb4[tid]; wos[tid] = ow[tid]; }
  if (tid < 64) {
    float mu = sums[tid] * (1.f / NNODES);
    float var = sums[64 + tid] * (1.f / NNODES) - mu * mu;
    float sc = rsqrtf(var + 1e-5f) * gamma[tid];
    scale[tid] = sc;
    shift[tid] = beta[tid] - mu * sc;
  }
  __syncthreads();
  int n = blockIdx.x * 256 + tid;
  if (n >= NNODES) return;
  float obv = ob[0];
  const float4* hr = (const float4*)(h3 + (size_t)n * 64);
  float z1[32];
#pragma unroll
  for (int j = 0; j < 32; ++j) z1[j] = b1s[j];
  for (int i4 = 0; i4 < 16; ++i4) {
    float4 hv = hr[i4];
    float a0 = hv.x * scale[4 * i4 + 0] + shift[4 * i4 + 0];
    float a1 = hv.y * scale[4 * i4 + 1] + shift[4 * i4 + 1];
    float a2 = hv.z * scale[4 * i4 + 2] + shift[4 * i4 + 2];
    float a3 = hv.w * scale[4 * i4 + 3] + shift[4 * i4 + 3];
#pragma unroll
    for (int j = 0; j < 32; ++j) {
      z1[j] += a0 * w1[(4 * i4 + 0) * 32 + j] + a1 * w1[(4 * i4 + 1) * 32 + j] +
               a2 * w1[(4 * i4 + 2) * 32 + j] + a3 * w1[(4 * i4 + 3) * 32 + j];
    }
  }
  float z2[16];
#pragma unroll
  for (int j = 0; j < 16; ++j) z2[j] = b2s[j];
  for (int i = 0; i < 32; ++i) {
    float a = fmaxf(z1[i], 0.f);
#pragma unroll
    for (int j = 0; j < 16; ++j) z2[j] += a * w2[i * 16 + j];
  }
  float z3[8];
#pragma unroll
  for (int j = 0; j < 8; ++j) z3[j] = b3s[j];
  for (int i = 0; i < 16; ++i) {
    float a = fmaxf(z2[i], 0.f);
#pragma unroll
    for (int j = 0; j < 8; ++j) z3[j] += a * w3[i * 8 + j];
  }
  float z4[4];
#pragma unroll
  for (int j = 0; j < 4; ++j) z4[j] = b4s[j];
  for (int i = 0; i < 8; ++i) {
    float a = fmaxf(z3[i], 0.f);
#pragma unroll
    for (int j = 0; j < 4; ++j) z4[j] += a * w4[i * 4 + j];
  }
  float zo = obv;
#pragma unroll
  for (int i = 0; i < 4; ++i) zo += fmaxf(z4[i], 0.f) * wos[i];
  out[n] = 1.f / (1.f + __expf(-zo));
}

extern "C" void kernel_launch(void* const* d_in, const int* in_sizes, int n_in,
                              void* d_out, int out_size, void* d_ws, size_t ws_size,
                              hipStream_t stream) {
  const float* x  = (const float*)d_in[0];
  const int*   ei = (const int*)d_in[1];
  const float* W1 = (const float*)d_in[2];  const float* u1 = (const float*)d_in[3];
  const float* c1 = (const float*)d_in[4];  const float* b1 = (const float*)d_in[5];
  const float* W2 = (const float*)d_in[6];  const float* u2 = (const float*)d_in[7];
  const float* c2 = (const float*)d_in[8];  const float* b2 = (const float*)d_in[9];
  const float* W3 = (const float*)d_in[10]; const float* u3 = (const float*)d_in[11];
  const float* c3 = (const float*)d_in[12]; const float* b3 = (const float*)d_in[13];
  const float* gamma = (const float*)d_in[14]; const float* beta = (const float*)d_in[15];
  const float* lw1 = (const float*)d_in[16]; const float* lb1 = (const float*)d_in[17];
  const float* lw2 = (const float*)d_in[18]; const float* lb2 = (const float*)d_in[19];
  const float* lw3 = (const float*)d_in[20]; const float* lb3 = (const float*)d_in[21];
  const float* lw4 = (const float*)d_in[22]; const float* lb4 = (const float*)d_in[23];
  const float* ow  = (const float*)d_in[24]; const float* ob  = (const float*)d_in[25];
  float* out = (float*)d_out;

  float* t    = (float*)d_ws;                         // N*64   (layer-1 t)
  float* g    = t + (size_t)NNODES * 64;              // N*128  (g buffer, max 4*32)
  float* hA   = g + (size_t)NNODES * 128;             // N*64
  float* hB   = hA + (size_t)NNODES * 64;             // N*64
  float* s    = hB + (size_t)NNODES * 64;             // N*4
  float* q    = s + (size_t)NNODES * 4;               // E*4
  float* sums = q + (size_t)NEDGES * 4;               // 128
  int*   rowptr   = (int*)(sums + 128);               // N+1 (pad 8)
  int*   counts   = rowptr + NNODES + 8;              // N
  int*   fill     = counts + NNODES;                  // N
  int*   blockSum = fill + NNODES;                    // 256
  int*   blockOff = blockSum + 256;                   // 256
  int*   col      = blockOff + 256;                   // E
  int*   dstArr   = col + NEDGES;                     // E

  hipMemsetAsync(counts, 0, NNODES * sizeof(int), stream);
  hipMemsetAsync(fill, 0, NNODES * sizeof(int), stream);
  hipMemsetAsync(sums, 0, 128 * sizeof(float), stream);

  // ---- CSR by dst ----
  hist_kernel<<<(NEDGES + 255) / 256, 256, 0, stream>>>(ei, counts);
  scanA_kernel<<<SCAN_BLOCKS, 256, 0, stream>>>(counts, rowptr, blockSum);
  scanB_kernel<<<1, 256, 0, stream>>>(blockSum, blockOff);
  scanC_kernel<<<SCAN_BLOCKS, 256, 0, stream>>>(rowptr, blockOff);
  scatter_kernel<<<(NEDGES + 255) / 256, 256, 0, stream>>>(ei, rowptr, fill, col, dstArr);

  // ---- layer 1: 64 -> 16 (t-gather) ----
  gemm_t_kernel<64, 16><<<1024, 256, 0, stream>>>(x, W1, t);
  s_kernel<64><<<(NNODES * 4 + 255) / 256, 256, 0, stream>>>(x, u1, s);
  q_kernel<<<(NEDGES + 255) / 256, 256, 0, stream>>>(col, dstArr, s, c1, q);
  gather1_kernel<<<(NNODES + 15) / 16, 256, 0, stream>>>(rowptr, col, q, t, c1, b1, hA);

  // ---- layer 2: 16 -> 32 (g-gather) ----
  s_kernel<16><<<(NNODES * 4 + 255) / 256, 256, 0, stream>>>(hA, u2, s);
  q_kernel<<<(NEDGES + 255) / 256, 256, 0, stream>>>(col, dstArr, s, c2, q);
  gatherG_kernel<16><<<(NNODES + 15) / 16, 256, 0, stream>>>(rowptr, col, q, hA, c2, g);
  transform_kernel<16, 32, 8, 2><<<(NNODES + 127) / 128, 256, 0, stream>>>(g, rowptr, W2, b2, hB);

  // ---- layer 3: 32 -> 64 (g-gather) ----
  s_kernel<32><<<(NNODES * 4 + 255) / 256, 256, 0, stream>>>(hB, u3, s);
  q_kernel<<<(NEDGES + 255) / 256, 256, 0, stream>>>(col, dstArr, s, c3, q);
  gatherG_kernel<32><<<(NNODES + 7) / 8, 256, 0, stream>>>(rowptr, col, q, hB, c3, g);
  transform_kernel<32, 64, 8, 4><<<(NNODES + 127) / 128, 256, 0, stream>>>(g, rowptr, W3, b3, hA);

  // ---- BN stats + MLP head ----
  stats_kernel<<<256, 256, 0, stream>>>(hA, sums);
  mlp_kernel<<<(NNODES + 255) / 256, 256, 0, stream>>>(hA, sums, gamma, beta, lw1, lb1,
                                                       lw2, lb2, lw3, lb3, lw4, lb4,
                                                       ow, ob, out);
}

// Round 6
// 366.898 us; speedup vs baseline: 1.5628x; 1.0090x over previous
//
#include <hip/hip_runtime.h>

#define NNODES 50000
#define NEDGES 800000
#define SCAN_BLOCKS ((NNODES + 255) / 256)   // 196
#define NPART (NNODES / 8)                   // 6250 nodes per XCD partition
#define EPS 8192                             // edges per slice
#define NSLICE ((NEDGES + EPS - 1) / EPS)    // 98

// ---------------- CSR build: histogram over dst ----------------
__global__ __launch_bounds__(256) void hist_kernel(const int* __restrict__ ei,
                                                   int* __restrict__ counts) {
  int e = blockIdx.x * 256 + threadIdx.x;
  if (e < NEDGES) atomicAdd(&counts[ei[NEDGES + e]], 1);
}

__global__ __launch_bounds__(256) void scanA_kernel(const int* __restrict__ counts,
                                                    int* __restrict__ rowptr,
                                                    int* __restrict__ blockSum) {
  __shared__ int sm[256];
  int i = blockIdx.x * 256 + threadIdx.x;
  int v = (i < NNODES) ? counts[i] : 0;
  sm[threadIdx.x] = v;
  __syncthreads();
  for (int off = 1; off < 256; off <<= 1) {
    int x = (threadIdx.x >= off) ? sm[threadIdx.x - off] : 0;
    __syncthreads();
    sm[threadIdx.x] += x;
    __syncthreads();
  }
  if (i < NNODES) rowptr[i] = sm[threadIdx.x] - v;
  if (threadIdx.x == 255) blockSum[blockIdx.x] = sm[255];
}

__global__ __launch_bounds__(256) void scanB_kernel(int* __restrict__ blockSum,
                                                    int* __restrict__ blockOff) {
  __shared__ int sm[256];
  int v = (threadIdx.x < SCAN_BLOCKS) ? blockSum[threadIdx.x] : 0;
  sm[threadIdx.x] = v;
  __syncthreads();
  for (int off = 1; off < 256; off <<= 1) {
    int x = (threadIdx.x >= off) ? sm[threadIdx.x - off] : 0;
    __syncthreads();
    sm[threadIdx.x] += x;
    __syncthreads();
  }
  if (threadIdx.x < SCAN_BLOCKS) blockOff[threadIdx.x] = sm[threadIdx.x] - v;
}

__global__ __launch_bounds__(256) void scanC_kernel(int* __restrict__ rowptr,
                                                    const int* __restrict__ blockOff) {
  int i = blockIdx.x * 256 + threadIdx.x;
  if (i < NNODES) rowptr[i] += blockOff[blockIdx.x];
  if (i == 0) rowptr[NNODES] = NEDGES;
}

// XCD-partitioned scatter: WG (slice, p) streams slice, writes only dst in
// partition p -> each contiguous col region written by one XCD's L2 only
// (blockIdx%8 -> XCD round-robin; perf heuristic, never correctness).
__global__ __launch_bounds__(256) void scatter_kernel(const int* __restrict__ ei,
                                                      const int* __restrict__ rowptr,
                                                      int* __restrict__ fill,
                                                      int* __restrict__ col) {
  const int p = blockIdx.x & 7;
  const int sl = blockIdx.x >> 3;
  const int P0 = p * NPART;
  const int e1 = min((sl + 1) * EPS, NEDGES);
  for (int e = sl * EPS + threadIdx.x; e < e1; e += 256) {
    int dst = ei[NEDGES + e];
    if ((unsigned)(dst - P0) < (unsigned)NPART) {
      int pos = rowptr[dst] + atomicAdd(&fill[dst], 1);
      col[pos] = ei[e];
    }
  }
}

// ---------------- t = x @ W1, stored [N][16][4] (layer 1 only) ----------------
template<int FIN, int OUT>
__global__ __launch_bounds__(256) void gemm_t_kernel(const float* __restrict__ x,
                                                     const float* __restrict__ W,
                                                     float* __restrict__ t) {
  constexpr int COLS = 4 * OUT;
  constexpr int GROUPS = 256 / COLS;
  const int cIdx = threadIdx.x & (COLS - 1);
  const int g = threadIdx.x / COLS;
  const int o = cIdx >> 2, h = cIdx & 3;
  float wreg[FIN];
#pragma unroll
  for (int f = 0; f < FIN; ++f) wreg[f] = W[f * COLS + h * OUT + o];
  for (int n = blockIdx.x * GROUPS + g; n < NNODES; n += gridDim.x * GROUPS) {
    const float4* xr = (const float4*)(x + (size_t)n * FIN);
    float acc = 0.f;
#pragma unroll
    for (int f4 = 0; f4 < FIN / 4; ++f4) {
      float4 xv = xr[f4];
      acc += wreg[4 * f4 + 0] * xv.x + wreg[4 * f4 + 1] * xv.y +
             wreg[4 * f4 + 2] * xv.z + wreg[4 * f4 + 3] * xv.w;
    }
    t[(size_t)n * COLS + cIdx] = acc;
  }
}

// ---------------- s = x @ u  ([N,4]) ----------------
template<int FIN>
__global__ __launch_bounds__(256) void s_kernel(const float* __restrict__ x,
                                                const float* __restrict__ u,
                                                float* __restrict__ s) {
  int tid = blockIdx.x * 256 + threadIdx.x;
  int n = tid >> 2, h = tid & 3;
  if (n >= NNODES) return;
  const float4* xr = (const float4*)(x + (size_t)n * FIN);
  float acc = 0.f;
#pragma unroll
  for (int f4 = 0; f4 < FIN / 4; ++f4) {
    float4 xv = xr[f4];
    acc += xv.x * u[(4 * f4 + 0) * 4 + h] + xv.y * u[(4 * f4 + 1) * 4 + h] +
           xv.z * u[(4 * f4 + 2) * 4 + h] + xv.w * u[(4 * f4 + 3) * 4 + h];
  }
  s[tid] = acc;  // tid == n*4+h
}

// ---------------- per-edge q = softmax(s[src]-s[dst]+c), 16 lanes per node ----------------
// dst implicit from CSR row; writes coalesced (16 lanes x float4 = 256B).
__global__ __launch_bounds__(256) void q_kernel(const int* __restrict__ rowptr,
                                                const int* __restrict__ col,
                                                const float* __restrict__ s,
                                                const float* __restrict__ cptr,
                                                float* __restrict__ q) {
  const int lane = threadIdx.x & 15;
  const int sub = threadIdx.x >> 4;
  const int n = blockIdx.x * 16 + sub;
  if (n >= NNODES) return;
  float4 c4 = *(const float4*)cptr;
  float4 sd = *(const float4*)(s + 4 * (size_t)n);
  const int beg = rowptr[n], end = rowptr[n + 1];
  for (int idx = beg + lane; idx < end; idx += 16) {
    int src = col[idx];
    float4 ss = *(const float4*)(s + 4 * (size_t)src);
    float l0 = ss.x - sd.x + c4.x;
    float l1 = ss.y - sd.y + c4.y;
    float l2 = ss.z - sd.z + c4.z;
    float l3 = ss.w - sd.w + c4.w;
    float mx = fmaxf(fmaxf(l0, l1), fmaxf(l2, l3));
    float e0 = __expf(l0 - mx), e1 = __expf(l1 - mx);
    float e2 = __expf(l2 - mx), e3 = __expf(l3 - mx);
    float inv = 1.f / (e0 + e1 + e2 + e3);
    *(float4*)(q + 4 * (size_t)idx) = make_float4(e0 * inv, e1 * inv, e2 * inv, e3 * inv);
  }
}

// ---------------- layer-1 gather over t (16 lanes per dst node) ----------------
__global__ __launch_bounds__(256) void gather1_kernel(const int* __restrict__ rowptr,
                                                      const int* __restrict__ col,
                                                      const float* __restrict__ q,
                                                      const float* __restrict__ t,
                                                      const float* __restrict__ cptr,
                                                      const float* __restrict__ bptr,
                                                      float* __restrict__ h) {
  const int lane = threadIdx.x & 15;
  const int sub = threadIdx.x >> 4;
  const int n = blockIdx.x * 16 + sub;
  if (n >= NNODES) return;
  float4 c4 = *(const float4*)cptr;
  float mxc = fmaxf(fmaxf(c4.x, c4.y), fmaxf(c4.z, c4.w));
  float qs0 = __expf(c4.x - mxc), qs1 = __expf(c4.y - mxc);
  float qs2 = __expf(c4.z - mxc), qs3 = __expf(c4.w - mxc);
  float sinv = 1.f / (qs0 + qs1 + qs2 + qs3);
  float4 tv = *((const float4*)(t + (size_t)n * 64) + lane);
  float acc = (qs0 * tv.x + qs1 * tv.y + qs2 * tv.z + qs3 * tv.w) * sinv;
  const int beg = rowptr[n], end = rowptr[n + 1];
  for (int idx = beg; idx < end; ++idx) {
    int src = col[idx];
    float4 qv = *(const float4*)(q + 4 * (size_t)idx);
    float4 tw = *((const float4*)(t + (size_t)src * 64) + lane);
    acc += qv.x * tw.x + qv.y * tw.y + qv.z * tw.z + qv.w * tw.w;
  }
  float d = (float)(end - beg + 1);
  h[(size_t)n * 16 + lane] = fmaxf(acc / d + bptr[lane], 0.f);
}

// ---------------- g-gather: g[n][h][f] = sum_j q_jh * x_j[f]  (FIN lanes per node) ----------------
template<int FIN>
__global__ __launch_bounds__(256) void gatherG_kernel(const int* __restrict__ rowptr,
                                                      const int* __restrict__ col,
                                                      const float* __restrict__ q,
                                                      const float* __restrict__ x,
                                                      const float* __restrict__ cptr,
                                                      float* __restrict__ g) {
  constexpr int NSUB = 256 / FIN;
  const int f = threadIdx.x & (FIN - 1);
  const int sub = threadIdx.x / FIN;
  const int n = blockIdx.x * NSUB + sub;
  if (n >= NNODES) return;
  float4 c4 = *(const float4*)cptr;
  float mxc = fmaxf(fmaxf(c4.x, c4.y), fmaxf(c4.z, c4.w));
  float qs0 = __expf(c4.x - mxc), qs1 = __expf(c4.y - mxc);
  float qs2 = __expf(c4.z - mxc), qs3 = __expf(c4.w - mxc);
  float sinv = 1.f / (qs0 + qs1 + qs2 + qs3);
  float xn = x[(size_t)n * FIN + f];
  float g0 = qs0 * sinv * xn, g1 = qs1 * sinv * xn;
  float g2 = qs2 * sinv * xn, g3 = qs3 * sinv * xn;
  const int beg = rowptr[n], end = rowptr[n + 1];
  for (int idx = beg; idx < end; ++idx) {
    int src = col[idx];
    float4 qv = *(const float4*)(q + 4 * (size_t)idx);
    float xv = x[(size_t)src * FIN + f];
    g0 += qv.x * xv; g1 += qv.y * xv; g2 += qv.z * xv; g3 += qv.w * xv;
  }
  float* gr = g + (size_t)n * 4 * FIN;
  gr[0 * FIN + f] = g0;
  gr[1 * FIN + f] = g1;
  gr[2 * FIN + f] = g2;
  gr[3 * FIN + f] = g3;
}

// ---------------- per-node transform: h[n][o] = relu((sum_h W_h g_h)/deg + b) ----------------
template<int FIN, int OUT, int MO, int NP>
__global__ __launch_bounds__(256) void transform_kernel(const float* __restrict__ g,
                                                        const int* __restrict__ rowptr,
                                                        const float* __restrict__ W,
                                                        const float* __restrict__ bptr,
                                                        float* __restrict__ h) {
  constexpr int K = 4 * FIN;          // g row length
  constexpr int OG = OUT / MO;        // o-groups per node
  constexpr int NG = 256 / OG;        // node-groups per block
  constexpr int NPB = NG * NP;        // nodes per block
  __shared__ float wsT[OUT * K];
  for (int i = threadIdx.x; i < OUT * K; i += 256) {
    int o = i / K, k = i - o * K;
    int hh = k / FIN, f = k - hh * FIN;
    int kg = k >> 2;
    int pg = kg ^ (o / MO);           // granule swizzle
    wsT[o * K + (pg << 2) + (k & 3)] = W[f * (4 * OUT) + hh * OUT + o];
  }
  __syncthreads();
  const int og = threadIdx.x & (OG - 1);
  const int ng = threadIdx.x / OG;
  const int o0 = og * MO;
  const int nb = blockIdx.x * NPB + ng * NP;
  float acc[NP][MO];
#pragma unroll
  for (int p = 0; p < NP; ++p)
#pragma unroll
    for (int m = 0; m < MO; ++m) acc[p][m] = 0.f;
  const float* gptr[NP];
#pragma unroll
  for (int p = 0; p < NP; ++p) {
    int n = nb + p;
    gptr[p] = g + (size_t)(n < NNODES ? n : NNODES - 1) * K;
  }
#pragma unroll 2
  for (int kg = 0; kg < K / 4; ++kg) {
    float4 av[NP];
#pragma unroll
    for (int p = 0; p < NP; ++p) av[p] = *(const float4*)(gptr[p] + (kg << 2));
#pragma unroll
    for (int m = 0; m < MO; ++m) {
      const float4 wv = *(const float4*)(&wsT[(o0 + m) * K + ((kg ^ og) << 2)]);
#pragma unroll
      for (int p = 0; p < NP; ++p)
        acc[p][m] += av[p].x * wv.x + av[p].y * wv.y + av[p].z * wv.z + av[p].w * wv.w;
    }
  }
#pragma unroll
  for (int p = 0; p < NP; ++p) {
    int n = nb + p;
    if (n < NNODES) {
      float inv = 1.f / (float)(rowptr[n + 1] - rowptr[n] + 1);
#pragma unroll
      for (int m = 0; m < MO; ++m)
        h[(size_t)n * OUT + o0 + m] = fmaxf(acc[p][m] * inv + bptr[o0 + m], 0.f);
    }
  }
}

// ---------------- BN batch-stats over h3 [N,64] ----------------
__global__ __launch_bounds__(256) void stats_kernel(const float* __restrict__ h3,
                                                    float* __restrict__ sums) {
  const int o = threadIdx.x & 63;
  const int r = threadIdx.x >> 6;
  float accS = 0.f, accQ = 0.f;
  for (int base = blockIdx.x * 4; base < NNODES; base += gridDim.x * 4) {
    int n = base + r;
    if (n < NNODES) {
      float v = h3[(size_t)n * 64 + o];
      accS += v;
      accQ += v * v;
    }
  }
  __shared__ float ls[256], lq[256];
  ls[threadIdx.x] = accS;
  lq[threadIdx.x] = accQ;
  __syncthreads();
  if (threadIdx.x < 64) {
    float a = ls[threadIdx.x] + ls[threadIdx.x + 64] + ls[threadIdx.x + 128] + ls[threadIdx.x + 192];
    float qq = lq[threadIdx.x] + lq[threadIdx.x + 64] + lq[threadIdx.x + 128] + lq[threadIdx.x + 192];
    atomicAdd(&sums[threadIdx.x], a);
    atomicAdd(&sums[64 + threadIdx.x], qq);
  }
}

// ---------------- BN + MLP head + sigmoid, one thread per node ----------------
__global__ __launch_bounds__(256) void mlp_kernel(
    const float* __restrict__ h3, const float* __restrict__ sums,
    const float* __restrict__ gamma, const float* __restrict__ beta,
    const float* __restrict__ lw1, const float* __restrict__ lb1,
    const float* __restrict__ lw2, const float* __restrict__ lb2,
    const float* __restrict__ lw3, const float* __restrict__ lb3,
    const float* __restrict__ lw4, const float* __restrict__ lb4,
    const float* __restrict__ ow, const float* __restrict__ ob,
    float* __restrict__ out) {
  __shared__ float w1[64 * 32], w2[32 * 16], w3[16 * 8], w4[8 * 4];
  __shared__ float b1s[32], b2s[16], b3s[8], b4s[4], wos[4];
  __shared__ float scale[64], shift[64];
  int tid = threadIdx.x;
  for (int i = tid; i < 64 * 32; i += 256) w1[i] = lw1[i];
  for (int i = tid; i < 32 * 16; i += 256) w2[i] = lw2[i];
  if (tid < 128) w3[tid] = lw3[tid];
  if (tid < 32) { w4[tid] = lw4[tid]; b1s[tid] = lb1[tid]; }
  if (tid < 16) b2s[tid] = lb2[tid];
  if (tid < 8) b3s[tid] = lb3[tid];
  if (tid < 4) { b4s[tid] = lb4[tid]; wos[tid] = ow[tid]; }
  if (tid < 64) {
    float mu = sums[tid] * (1.f / NNODES);
    float var = sums[64 + tid] * (1.f / NNODES) - mu * mu;
    float sc = rsqrtf(var + 1e-5f) * gamma[tid];
    scale[tid] = sc;
    shift[tid] = beta[tid] - mu * sc;
  }
  __syncthreads();
  int n = blockIdx.x * 256 + tid;
  if (n >= NNODES) return;
  float obv = ob[0];
  const float4* hr = (const float4*)(h3 + (size_t)n * 64);
  float z1[32];
#pragma unroll
  for (int j = 0; j < 32; ++j) z1[j] = b1s[j];
  for (int i4 = 0; i4 < 16; ++i4) {
    float4 hv = hr[i4];
    float a0 = hv.x * scale[4 * i4 + 0] + shift[4 * i4 + 0];
    float a1 = hv.y * scale[4 * i4 + 1] + shift[4 * i4 + 1];
    float a2 = hv.z * scale[4 * i4 + 2] + shift[4 * i4 + 2];
    float a3 = hv.w * scale[4 * i4 + 3] + shift[4 * i4 + 3];
#pragma unroll
    for (int j = 0; j < 32; ++j) {
      z1[j] += a0 * w1[(4 * i4 + 0) * 32 + j] + a1 * w1[(4 * i4 + 1) * 32 + j] +
               a2 * w1[(4 * i4 + 2) * 32 + j] + a3 * w1[(4 * i4 + 3) * 32 + j];
    }
  }
  float z2[16];
#pragma unroll
  for (int j = 0; j < 16; ++j) z2[j] = b2s[j];
  for (int i = 0; i < 32; ++i) {
    float a = fmaxf(z1[i], 0.f);
#pragma unroll
    for (int j = 0; j < 16; ++j) z2[j] += a * w2[i * 16 + j];
  }
  float z3[8];
#pragma unroll
  for (int j = 0; j < 8; ++j) z3[j] = b3s[j];
  for (int i = 0; i < 16; ++i) {
    float a = fmaxf(z2[i], 0.f);
#pragma unroll
    for (int j = 0; j < 8; ++j) z3[j] += a * w3[i * 8 + j];
  }
  float z4[4];
#pragma unroll
  for (int j = 0; j < 4; ++j) z4[j] = b4s[j];
  for (int i = 0; i < 8; ++i) {
    float a = fmaxf(z3[i], 0.f);
#pragma unroll
    for (int j = 0; j < 4; ++j) z4[j] += a * w4[i * 4 + j];
  }
  float zo = obv;
#pragma unroll
  for (int i = 0; i < 4; ++i) zo += fmaxf(z4[i], 0.f) * wos[i];
  out[n] = 1.f / (1.f + __expf(-zo));
}

extern "C" void kernel_launch(void* const* d_in, const int* in_sizes, int n_in,
                              void* d_out, int out_size, void* d_ws, size_t ws_size,
                              hipStream_t stream) {
  const float* x  = (const float*)d_in[0];
  const int*   ei = (const int*)d_in[1];
  const float* W1 = (const float*)d_in[2];  const float* u1 = (const float*)d_in[3];
  const float* c1 = (const float*)d_in[4];  const float* b1 = (const float*)d_in[5];
  const float* W2 = (const float*)d_in[6];  const float* u2 = (const float*)d_in[7];
  const float* c2 = (const float*)d_in[8];  const float* b2 = (const float*)d_in[9];
  const float* W3 = (const float*)d_in[10]; const float* u3 = (const float*)d_in[11];
  const float* c3 = (const float*)d_in[12]; const float* b3 = (const float*)d_in[13];
  const float* gamma = (const float*)d_in[14]; const float* beta = (const float*)d_in[15];
  const float* lw1 = (const float*)d_in[16]; const float* lb1 = (const float*)d_in[17];
  const float* lw2 = (const float*)d_in[18]; const float* lb2 = (const float*)d_in[19];
  const float* lw3 = (const float*)d_in[20]; const float* lb3 = (const float*)d_in[21];
  const float* lw4 = (const float*)d_in[22]; const float* lb4 = (const float*)d_in[23];
  const float* ow  = (const float*)d_in[24]; const float* ob  = (const float*)d_in[25];
  float* out = (float*)d_out;

  float* t    = (float*)d_ws;                         // N*64   (layer-1 t)
  float* g    = t + (size_t)NNODES * 64;              // N*128  (g buffer, max 4*32)
  float* hA   = g + (size_t)NNODES * 128;             // N*64
  float* hB   = hA + (size_t)NNODES * 64;             // N*64
  float* s    = hB + (size_t)NNODES * 64;             // N*4
  float* q    = s + (size_t)NNODES * 4;               // E*4
  float* sums = q + (size_t)NEDGES * 4;               // 128
  int*   rowptr   = (int*)(sums + 128);               // N+1 (pad 8)
  int*   counts   = rowptr + NNODES + 8;              // N
  int*   fill     = counts + NNODES;                  // N
  int*   blockSum = fill + NNODES;                    // 256
  int*   blockOff = blockSum + 256;                   // 256
  int*   col      = blockOff + 256;                   // E

  hipMemsetAsync(counts, 0, NNODES * sizeof(int), stream);
  hipMemsetAsync(fill, 0, NNODES * sizeof(int), stream);
  hipMemsetAsync(sums, 0, 128 * sizeof(float), stream);

  // ---- CSR by dst ----
  hist_kernel<<<(NEDGES + 255) / 256, 256, 0, stream>>>(ei, counts);
  scanA_kernel<<<SCAN_BLOCKS, 256, 0, stream>>>(counts, rowptr, blockSum);
  scanB_kernel<<<1, 256, 0, stream>>>(blockSum, blockOff);
  scanC_kernel<<<SCAN_BLOCKS, 256, 0, stream>>>(rowptr, blockOff);
  scatter_kernel<<<NSLICE * 8, 256, 0, stream>>>(ei, rowptr, fill, col);

  // ---- layer 1: 64 -> 16 (t-gather) ----
  gemm_t_kernel<64, 16><<<1024, 256, 0, stream>>>(x, W1, t);
  s_kernel<64><<<(NNODES * 4 + 255) / 256, 256, 0, stream>>>(x, u1, s);
  q_kernel<<<(NNODES + 15) / 16, 256, 0, stream>>>(rowptr, col, s, c1, q);
  gather1_kernel<<<(NNODES + 15) / 16, 256, 0, stream>>>(rowptr, col, q, t, c1, b1, hA);

  // ---- layer 2: 16 -> 32 (g-gather) ----
  s_kernel<16><<<(NNODES * 4 + 255) / 256, 256, 0, stream>>>(hA, u2, s);
  q_kernel<<<(NNODES + 15) / 16, 256, 0, stream>>>(rowptr, col, s, c2, q);
  gatherG_kernel<16><<<(NNODES + 15) / 16, 256, 0, stream>>>(rowptr, col, q, hA, c2, g);
  transform_kernel<16, 32, 8, 2><<<(NNODES + 127) / 128, 256, 0, stream>>>(g, rowptr, W2, b2, hB);

  // ---- layer 3: 32 -> 64 (g-gather) ----
  s_kernel<32><<<(NNODES * 4 + 255) / 256, 256, 0, stream>>>(hB, u3, s);
  q_kernel<<<(NNODES + 15) / 16, 256, 0, stream>>>(rowptr, col, s, c3, q);
  gatherG_kernel<32><<<(NNODES + 7) / 8, 256, 0, stream>>>(rowptr, col, q, hB, c3, g);
  transform_kernel<32, 64, 8, 4><<<(NNODES + 127) / 128, 256, 0, stream>>>(g, rowptr, W3, b3, hA);

  // ---- BN stats + MLP head ----
  stats_kernel<<<256, 256, 0, stream>>>(hA, sums);
  mlp_kernel<<<(NNODES + 255) / 256, 256, 0, stream>>>(hA, sums, gamma, beta, lw1, lb1,
                                                       lw2, lb2, lw3, lb3, lw4, lb4,
                                                       ow, ob, out);
}

// Round 7
// 328.173 us; speedup vs baseline: 1.7472x; 1.1180x over previous
//
#include <hip/hip_runtime.h>

#define NNODES 50000
#define NEDGES 800000
#define SCAN_BLOCKS ((NNODES + 255) / 256)   // 196
#define NPART (NNODES / 8)                   // 6250 nodes per XCD partition
#define EPS 2048                             // edges per slice (small -> fill machine)
#define NSLICE ((NEDGES + EPS - 1) / EPS)    // 391

// ---------------- CSR build: histogram over dst ----------------
__global__ __launch_bounds__(256) void hist_kernel(const int* __restrict__ ei,
                                                   int* __restrict__ counts) {
  int e = blockIdx.x * 256 + threadIdx.x;
  if (e < NEDGES) atomicAdd(&counts[ei[NEDGES + e]], 1);
}

__global__ __launch_bounds__(256) void scanA_kernel(const int* __restrict__ counts,
                                                    int* __restrict__ rowptr,
                                                    int* __restrict__ blockSum) {
  __shared__ int sm[256];
  int i = blockIdx.x * 256 + threadIdx.x;
  int v = (i < NNODES) ? counts[i] : 0;
  sm[threadIdx.x] = v;
  __syncthreads();
  for (int off = 1; off < 256; off <<= 1) {
    int x = (threadIdx.x >= off) ? sm[threadIdx.x - off] : 0;
    __syncthreads();
    sm[threadIdx.x] += x;
    __syncthreads();
  }
  if (i < NNODES) rowptr[i] = sm[threadIdx.x] - v;
  if (threadIdx.x == 255) blockSum[blockIdx.x] = sm[255];
}

__global__ __launch_bounds__(256) void scanB_kernel(int* __restrict__ blockSum,
                                                    int* __restrict__ blockOff) {
  __shared__ int sm[256];
  int v = (threadIdx.x < SCAN_BLOCKS) ? blockSum[threadIdx.x] : 0;
  sm[threadIdx.x] = v;
  __syncthreads();
  for (int off = 1; off < 256; off <<= 1) {
    int x = (threadIdx.x >= off) ? sm[threadIdx.x - off] : 0;
    __syncthreads();
    sm[threadIdx.x] += x;
    __syncthreads();
  }
  if (threadIdx.x < SCAN_BLOCKS) blockOff[threadIdx.x] = sm[threadIdx.x] - v;
}

__global__ __launch_bounds__(256) void scanC_kernel(int* __restrict__ rowptr,
                                                    const int* __restrict__ blockOff) {
  int i = blockIdx.x * 256 + threadIdx.x;
  if (i < NNODES) rowptr[i] += blockOff[blockIdx.x];
  if (i == 0) rowptr[NNODES] = NEDGES;
}

// XCD-partitioned scatter: WG (slice, p) streams slice, writes only dst in
// partition p -> each contiguous col region written by one XCD's L2 only.
__global__ __launch_bounds__(256) void scatter_kernel(const int* __restrict__ ei,
                                                      const int* __restrict__ rowptr,
                                                      int* __restrict__ fill,
                                                      int* __restrict__ col) {
  const int p = blockIdx.x & 7;
  const int sl = blockIdx.x >> 3;
  const int P0 = p * NPART;
  const int e1 = min((sl + 1) * EPS, NEDGES);
  for (int e = sl * EPS + threadIdx.x; e < e1; e += 256) {
    int dst = ei[NEDGES + e];
    if ((unsigned)(dst - P0) < (unsigned)NPART) {
      int pos = rowptr[dst] + atomicAdd(&fill[dst], 1);
      col[pos] = ei[e];
    }
  }
}

// ---------------- t = x @ W1, stored [N][16][4] (layer 1 only) ----------------
template<int FIN, int OUT>
__global__ __launch_bounds__(256) void gemm_t_kernel(const float* __restrict__ x,
                                                     const float* __restrict__ W,
                                                     float* __restrict__ t) {
  constexpr int COLS = 4 * OUT;
  constexpr int GROUPS = 256 / COLS;
  const int cIdx = threadIdx.x & (COLS - 1);
  const int g = threadIdx.x / COLS;
  const int o = cIdx >> 2, h = cIdx & 3;
  float wreg[FIN];
#pragma unroll
  for (int f = 0; f < FIN; ++f) wreg[f] = W[f * COLS + h * OUT + o];
  for (int n = blockIdx.x * GROUPS + g; n < NNODES; n += gridDim.x * GROUPS) {
    const float4* xr = (const float4*)(x + (size_t)n * FIN);
    float acc = 0.f;
#pragma unroll
    for (int f4 = 0; f4 < FIN / 4; ++f4) {
      float4 xv = xr[f4];
      acc += wreg[4 * f4 + 0] * xv.x + wreg[4 * f4 + 1] * xv.y +
             wreg[4 * f4 + 2] * xv.z + wreg[4 * f4 + 3] * xv.w;
    }
    t[(size_t)n * COLS + cIdx] = acc;
  }
}

// ---------------- s = x @ u  ([N,4]) ----------------
template<int FIN>
__global__ __launch_bounds__(256) void s_kernel(const float* __restrict__ x,
                                                const float* __restrict__ u,
                                                float* __restrict__ s) {
  int tid = blockIdx.x * 256 + threadIdx.x;
  int n = tid >> 2, h = tid & 3;
  if (n >= NNODES) return;
  const float4* xr = (const float4*)(x + (size_t)n * FIN);
  float acc = 0.f;
#pragma unroll
  for (int f4 = 0; f4 < FIN / 4; ++f4) {
    float4 xv = xr[f4];
    acc += xv.x * u[(4 * f4 + 0) * 4 + h] + xv.y * u[(4 * f4 + 1) * 4 + h] +
           xv.z * u[(4 * f4 + 2) * 4 + h] + xv.w * u[(4 * f4 + 3) * 4 + h];
  }
  s[tid] = acc;  // tid == n*4+h
}

// ---------------- per-edge q = softmax(s[src]-s[dst]+c), 16 lanes per node ----------------
__global__ __launch_bounds__(256) void q_kernel(const int* __restrict__ rowptr,
                                                const int* __restrict__ col,
                                                const float* __restrict__ s,
                                                const float* __restrict__ cptr,
                                                float* __restrict__ q) {
  const int lane = threadIdx.x & 15;
  const int sub = threadIdx.x >> 4;
  const int n = blockIdx.x * 16 + sub;
  if (n >= NNODES) return;
  float4 c4 = *(const float4*)cptr;
  float4 sd = *(const float4*)(s + 4 * (size_t)n);
  const int beg = rowptr[n], end = rowptr[n + 1];
  for (int idx = beg + lane; idx < end; idx += 16) {
    int src = col[idx];
    float4 ss = *(const float4*)(s + 4 * (size_t)src);
    float l0 = ss.x - sd.x + c4.x;
    float l1 = ss.y - sd.y + c4.y;
    float l2 = ss.z - sd.z + c4.z;
    float l3 = ss.w - sd.w + c4.w;
    float mx = fmaxf(fmaxf(l0, l1), fmaxf(l2, l3));
    float e0 = __expf(l0 - mx), e1 = __expf(l1 - mx);
    float e2 = __expf(l2 - mx), e3 = __expf(l3 - mx);
    float inv = 1.f / (e0 + e1 + e2 + e3);
    *(float4*)(q + 4 * (size_t)idx) = make_float4(e0 * inv, e1 * inv, e2 * inv, e3 * inv);
  }
}

// ---------------- layer-1 gather over t (16 lanes per dst node), 4x unrolled ----------------
__global__ __launch_bounds__(256) void gather1_kernel(const int* __restrict__ rowptr,
                                                      const int* __restrict__ col,
                                                      const float* __restrict__ q,
                                                      const float* __restrict__ t,
                                                      const float* __restrict__ cptr,
                                                      const float* __restrict__ bptr,
                                                      float* __restrict__ h) {
  const int lane = threadIdx.x & 15;
  const int sub = threadIdx.x >> 4;
  const int n = blockIdx.x * 16 + sub;
  if (n >= NNODES) return;
  float4 c4 = *(const float4*)cptr;
  float mxc = fmaxf(fmaxf(c4.x, c4.y), fmaxf(c4.z, c4.w));
  float qs0 = __expf(c4.x - mxc), qs1 = __expf(c4.y - mxc);
  float qs2 = __expf(c4.z - mxc), qs3 = __expf(c4.w - mxc);
  float sinv = 1.f / (qs0 + qs1 + qs2 + qs3);
  float4 tv = *((const float4*)(t + (size_t)n * 64) + lane);
  float acc = (qs0 * tv.x + qs1 * tv.y + qs2 * tv.z + qs3 * tv.w) * sinv;
  const int beg = rowptr[n], end = rowptr[n + 1];
  int idx = beg;
  for (; idx + 3 < end; idx += 4) {
    int s0 = col[idx], s1 = col[idx + 1], s2 = col[idx + 2], s3 = col[idx + 3];
    float4 q0 = *(const float4*)(q + 4 * (size_t)(idx + 0));
    float4 q1 = *(const float4*)(q + 4 * (size_t)(idx + 1));
    float4 q2 = *(const float4*)(q + 4 * (size_t)(idx + 2));
    float4 q3 = *(const float4*)(q + 4 * (size_t)(idx + 3));
    float4 t0 = *((const float4*)(t + (size_t)s0 * 64) + lane);
    float4 t1 = *((const float4*)(t + (size_t)s1 * 64) + lane);
    float4 t2 = *((const float4*)(t + (size_t)s2 * 64) + lane);
    float4 t3 = *((const float4*)(t + (size_t)s3 * 64) + lane);
    acc += q0.x * t0.x + q0.y * t0.y + q0.z * t0.z + q0.w * t0.w;
    acc += q1.x * t1.x + q1.y * t1.y + q1.z * t1.z + q1.w * t1.w;
    acc += q2.x * t2.x + q2.y * t2.y + q2.z * t2.z + q2.w * t2.w;
    acc += q3.x * t3.x + q3.y * t3.y + q3.z * t3.z + q3.w * t3.w;
  }
  for (; idx < end; ++idx) {
    int src = col[idx];
    float4 qv = *(const float4*)(q + 4 * (size_t)idx);
    float4 tw = *((const float4*)(t + (size_t)src * 64) + lane);
    acc += qv.x * tw.x + qv.y * tw.y + qv.z * tw.z + qv.w * tw.w;
  }
  float d = (float)(end - beg + 1);
  h[(size_t)n * 16 + lane] = fmaxf(acc / d + bptr[lane], 0.f);
}

// ---------------- g-gather: g[n][h][f] = sum_j q_jh * x_j[f], 4x unrolled ----------------
template<int FIN>
__global__ __launch_bounds__(256) void gatherG_kernel(const int* __restrict__ rowptr,
                                                      const int* __restrict__ col,
                                                      const float* __restrict__ q,
                                                      const float* __restrict__ x,
                                                      const float* __restrict__ cptr,
                                                      float* __restrict__ g) {
  constexpr int NSUB = 256 / FIN;
  const int f = threadIdx.x & (FIN - 1);
  const int sub = threadIdx.x / FIN;
  const int n = blockIdx.x * NSUB + sub;
  if (n >= NNODES) return;
  float4 c4 = *(const float4*)cptr;
  float mxc = fmaxf(fmaxf(c4.x, c4.y), fmaxf(c4.z, c4.w));
  float qs0 = __expf(c4.x - mxc), qs1 = __expf(c4.y - mxc);
  float qs2 = __expf(c4.z - mxc), qs3 = __expf(c4.w - mxc);
  float sinv = 1.f / (qs0 + qs1 + qs2 + qs3);
  float xn = x[(size_t)n * FIN + f];
  float g0 = qs0 * sinv * xn, g1 = qs1 * sinv * xn;
  float g2 = qs2 * sinv * xn, g3 = qs3 * sinv * xn;
  const int beg = rowptr[n], end = rowptr[n + 1];
  int idx = beg;
  for (; idx + 3 < end; idx += 4) {
    int s0 = col[idx], s1 = col[idx + 1], s2 = col[idx + 2], s3 = col[idx + 3];
    float4 q0 = *(const float4*)(q + 4 * (size_t)(idx + 0));
    float4 q1 = *(const float4*)(q + 4 * (size_t)(idx + 1));
    float4 q2 = *(const float4*)(q + 4 * (size_t)(idx + 2));
    float4 q3 = *(const float4*)(q + 4 * (size_t)(idx + 3));
    float x0 = x[(size_t)s0 * FIN + f];
    float x1 = x[(size_t)s1 * FIN + f];
    float x2 = x[(size_t)s2 * FIN + f];
    float x3 = x[(size_t)s3 * FIN + f];
    g0 += q0.x * x0 + q1.x * x1 + q2.x * x2 + q3.x * x3;
    g1 += q0.y * x0 + q1.y * x1 + q2.y * x2 + q3.y * x3;
    g2 += q0.z * x0 + q1.z * x1 + q2.z * x2 + q3.z * x3;
    g3 += q0.w * x0 + q1.w * x1 + q2.w * x2 + q3.w * x3;
  }
  for (; idx < end; ++idx) {
    int src = col[idx];
    float4 qv = *(const float4*)(q + 4 * (size_t)idx);
    float xv = x[(size_t)src * FIN + f];
    g0 += qv.x * xv; g1 += qv.y * xv; g2 += qv.z * xv; g3 += qv.w * xv;
  }
  float* gr = g + (size_t)n * 4 * FIN;
  gr[0 * FIN + f] = g0;
  gr[1 * FIN + f] = g1;
  gr[2 * FIN + f] = g2;
  gr[3 * FIN + f] = g3;
}

// ---------------- per-node transform: h[n][o] = relu((sum_h W_h g_h)/deg + b) ----------------
template<int FIN, int OUT, int MO, int NP>
__global__ __launch_bounds__(256) void transform_kernel(const float* __restrict__ g,
                                                        const int* __restrict__ rowptr,
                                                        const float* __restrict__ W,
                                                        const float* __restrict__ bptr,
                                                        float* __restrict__ h) {
  constexpr int K = 4 * FIN;          // g row length
  constexpr int OG = OUT / MO;        // o-groups per node
  constexpr int NG = 256 / OG;        // node-groups per block
  constexpr int NPB = NG * NP;        // nodes per block
  __shared__ float wsT[OUT * K];
  for (int i = threadIdx.x; i < OUT * K; i += 256) {
    int o = i / K, k = i - o * K;
    int hh = k / FIN, f = k - hh * FIN;
    int kg = k >> 2;
    int pg = kg ^ (o / MO);           // granule swizzle
    wsT[o * K + (pg << 2) + (k & 3)] = W[f * (4 * OUT) + hh * OUT + o];
  }
  __syncthreads();
  const int og = threadIdx.x & (OG - 1);
  const int ng = threadIdx.x / OG;
  const int o0 = og * MO;
  const int nb = blockIdx.x * NPB + ng * NP;
  float acc[NP][MO];
#pragma unroll
  for (int p = 0; p < NP; ++p)
#pragma unroll
    for (int m = 0; m < MO; ++m) acc[p][m] = 0.f;
  const float* gptr[NP];
#pragma unroll
  for (int p = 0; p < NP; ++p) {
    int n = nb + p;
    gptr[p] = g + (size_t)(n < NNODES ? n : NNODES - 1) * K;
  }
#pragma unroll 2
  for (int kg = 0; kg < K / 4; ++kg) {
    float4 av[NP];
#pragma unroll
    for (int p = 0; p < NP; ++p) av[p] = *(const float4*)(gptr[p] + (kg << 2));
#pragma unroll
    for (int m = 0; m < MO; ++m) {
      const float4 wv = *(const float4*)(&wsT[(o0 + m) * K + ((kg ^ og) << 2)]);
#pragma unroll
      for (int p = 0; p < NP; ++p)
        acc[p][m] += av[p].x * wv.x + av[p].y * wv.y + av[p].z * wv.z + av[p].w * wv.w;
    }
  }
#pragma unroll
  for (int p = 0; p < NP; ++p) {
    int n = nb + p;
    if (n < NNODES) {
      float inv = 1.f / (float)(rowptr[n + 1] - rowptr[n] + 1);
#pragma unroll
      for (int m = 0; m < MO; ++m)
        h[(size_t)n * OUT + o0 + m] = fmaxf(acc[p][m] * inv + bptr[o0 + m], 0.f);
    }
  }
}

// ---------------- BN batch-stats over h3 [N,64] ----------------
__global__ __launch_bounds__(256) void stats_kernel(const float* __restrict__ h3,
                                                    float* __restrict__ sums) {
  const int o = threadIdx.x & 63;
  const int r = threadIdx.x >> 6;
  float accS = 0.f, accQ = 0.f;
  for (int base = blockIdx.x * 4; base < NNODES; base += gridDim.x * 4) {
    int n = base + r;
    if (n < NNODES) {
      float v = h3[(size_t)n * 64 + o];
      accS += v;
      accQ += v * v;
    }
  }
  __shared__ float ls[256], lq[256];
  ls[threadIdx.x] = accS;
  lq[threadIdx.x] = accQ;
  __syncthreads();
  if (threadIdx.x < 64) {
    float a = ls[threadIdx.x] + ls[threadIdx.x + 64] + ls[threadIdx.x + 128] + ls[threadIdx.x + 192];
    float qq = lq[threadIdx.x] + lq[threadIdx.x + 64] + lq[threadIdx.x + 128] + lq[threadIdx.x + 192];
    atomicAdd(&sums[threadIdx.x], a);
    atomicAdd(&sums[64 + threadIdx.x], qq);
  }
}

// ---------------- BN + MLP head + sigmoid, one thread per node ----------------
__global__ __launch_bounds__(256) void mlp_kernel(
    const float* __restrict__ h3, const float* __restrict__ sums,
    const float* __restrict__ gamma, const float* __restrict__ beta,
    const float* __restrict__ lw1, const float* __restrict__ lb1,
    const float* __restrict__ lw2, const float* __restrict__ lb2,
    const float* __restrict__ lw3, const float* __restrict__ lb3,
    const float* __restrict__ lw4, const float* __restrict__ lb4,
    const float* __restrict__ ow, const float* __restrict__ ob,
    float* __restrict__ out) {
  __shared__ float w1[64 * 32], w2[32 * 16], w3[16 * 8], w4[8 * 4];
  __shared__ float b1s[32], b2s[16], b3s[8], b4s[4], wos[4];
  __shared__ float scale[64], shift[64];
  int tid = threadIdx.x;
  for (int i = tid; i < 64 * 32; i += 256) w1[i] = lw1[i];
  for (int i = tid; i < 32 * 16; i += 256) w2[i] = lw2[i];
  if (tid < 128) w3[tid] = lw3[tid];
  if (tid < 32) { w4[tid] = lw4[tid]; b1s[tid] = lb1[tid]; }
  if (tid < 16) b2s[tid] = lb2[tid];
  if (tid < 8) b3s[tid] = lb3[tid];
  if (tid < 4) { b4s[tid] = lb4[tid]; wos[tid] = ow[tid]; }
  if (tid < 64) {
    float mu = sums[tid] * (1.f / NNODES);
    float var = sums[64 + tid] * (1.f / NNODES) - mu * mu;
    float sc = rsqrtf(var + 1e-5f) * gamma[tid];
    scale[tid] = sc;
    shift[tid] = beta[tid] - mu * sc;
  }
  __syncthreads();
  int n = blockIdx.x * 256 + tid;
  if (n >= NNODES) return;
  float obv = ob[0];
  const float4* hr = (const float4*)(h3 + (size_t)n * 64);
  float z1[32];
#pragma unroll
  for (int j = 0; j < 32; ++j) z1[j] = b1s[j];
  for (int i4 = 0; i4 < 16; ++i4) {
    float4 hv = hr[i4];
    float a0 = hv.x * scale[4 * i4 + 0] + shift[4 * i4 + 0];
    float a1 = hv.y * scale[4 * i4 + 1] + shift[4 * i4 + 1];
    float a2 = hv.z * scale[4 * i4 + 2] + shift[4 * i4 + 2];
    float a3 = hv.w * scale[4 * i4 + 3] + shift[4 * i4 + 3];
#pragma unroll
    for (int j = 0; j < 32; ++j) {
      z1[j] += a0 * w1[(4 * i4 + 0) * 32 + j] + a1 * w1[(4 * i4 + 1) * 32 + j] +
               a2 * w1[(4 * i4 + 2) * 32 + j] + a3 * w1[(4 * i4 + 3) * 32 + j];
    }
  }
  float z2[16];
#pragma unroll
  for (int j = 0; j < 16; ++j) z2[j] = b2s[j];
  for (int i = 0; i < 32; ++i) {
    float a = fmaxf(z1[i], 0.f);
#pragma unroll
    for (int j = 0; j < 16; ++j) z2[j] += a * w2[i * 16 + j];
  }
  float z3[8];
#pragma unroll
  for (int j = 0; j < 8; ++j) z3[j] = b3s[j];
  for (int i = 0; i < 16; ++i) {
    float a = fmaxf(z2[i], 0.f);
#pragma unroll
    for (int j = 0; j < 8; ++j) z3[j] += a * w3[i * 8 + j];
  }
  float z4[4];
#pragma unroll
  for (int j = 0; j < 4; ++j) z4[j] = b4s[j];
  for (int i = 0; i < 8; ++i) {
    float a = fmaxf(z3[i], 0.f);
#pragma unroll
    for (int j = 0; j < 4; ++j) z4[j] += a * w4[i * 4 + j];
  }
  float zo = obv;
#pragma unroll
  for (int i = 0; i < 4; ++i) zo += fmaxf(z4[i], 0.f) * wos[i];
  out[n] = 1.f / (1.f + __expf(-zo));
}

extern "C" void kernel_launch(void* const* d_in, const int* in_sizes, int n_in,
                              void* d_out, int out_size, void* d_ws, size_t ws_size,
                              hipStream_t stream) {
  const float* x  = (const float*)d_in[0];
  const int*   ei = (const int*)d_in[1];
  const float* W1 = (const float*)d_in[2];  const float* u1 = (const float*)d_in[3];
  const float* c1 = (const float*)d_in[4];  const float* b1 = (const float*)d_in[5];
  const float* W2 = (const float*)d_in[6];  const float* u2 = (const float*)d_in[7];
  const float* c2 = (const float*)d_in[8];  const float* b2 = (const float*)d_in[9];
  const float* W3 = (const float*)d_in[10]; const float* u3 = (const float*)d_in[11];
  const float* c3 = (const float*)d_in[12]; const float* b3 = (const float*)d_in[13];
  const float* gamma = (const float*)d_in[14]; const float* beta = (const float*)d_in[15];
  const float* lw1 = (const float*)d_in[16]; const float* lb1 = (const float*)d_in[17];
  const float* lw2 = (const float*)d_in[18]; const float* lb2 = (const float*)d_in[19];
  const float* lw3 = (const float*)d_in[20]; const float* lb3 = (const float*)d_in[21];
  const float* lw4 = (const float*)d_in[22]; const float* lb4 = (const float*)d_in[23];
  const float* ow  = (const float*)d_in[24]; const float* ob  = (const float*)d_in[25];
  float* out = (float*)d_out;

  float* t    = (float*)d_ws;                         // N*64   (layer-1 t)
  float* g    = t + (size_t)NNODES * 64;              // N*128  (g buffer, max 4*32)
  float* hA   = g + (size_t)NNODES * 128;             // N*64
  float* hB   = hA + (size_t)NNODES * 64;             // N*64
  float* s    = hB + (size_t)NNODES * 64;             // N*4
  float* q    = s + (size_t)NNODES * 4;               // E*4
  float* sums = q + (size_t)NEDGES * 4;               // 128
  int*   rowptr   = (int*)(sums + 128);               // N+1 (pad 8)
  int*   counts   = rowptr + NNODES + 8;              // N
  int*   fill     = counts + NNODES;                  // N
  int*   blockSum = fill + NNODES;                    // 256
  int*   blockOff = blockSum + 256;                   // 256
  int*   col      = blockOff + 256;                   // E

  hipMemsetAsync(counts, 0, NNODES * sizeof(int), stream);
  hipMemsetAsync(fill, 0, NNODES * sizeof(int), stream);
  hipMemsetAsync(sums, 0, 128 * sizeof(float), stream);

  // ---- CSR by dst ----
  hist_kernel<<<(NEDGES + 255) / 256, 256, 0, stream>>>(ei, counts);
  scanA_kernel<<<SCAN_BLOCKS, 256, 0, stream>>>(counts, rowptr, blockSum);
  scanB_kernel<<<1, 256, 0, stream>>>(blockSum, blockOff);
  scanC_kernel<<<SCAN_BLOCKS, 256, 0, stream>>>(rowptr, blockOff);
  scatter_kernel<<<NSLICE * 8, 256, 0, stream>>>(ei, rowptr, fill, col);

  // ---- layer 1: 64 -> 16 (t-gather) ----
  gemm_t_kernel<64, 16><<<1024, 256, 0, stream>>>(x, W1, t);
  s_kernel<64><<<(NNODES * 4 + 255) / 256, 256, 0, stream>>>(x, u1, s);
  q_kernel<<<(NNODES + 15) / 16, 256, 0, stream>>>(rowptr, col, s, c1, q);
  gather1_kernel<<<(NNODES + 15) / 16, 256, 0, stream>>>(rowptr, col, q, t, c1, b1, hA);

  // ---- layer 2: 16 -> 32 (g-gather) ----
  s_kernel<16><<<(NNODES * 4 + 255) / 256, 256, 0, stream>>>(hA, u2, s);
  q_kernel<<<(NNODES + 15) / 16, 256, 0, stream>>>(rowptr, col, s, c2, q);
  gatherG_kernel<16><<<(NNODES + 15) / 16, 256, 0, stream>>>(rowptr, col, q, hA, c2, g);
  transform_kernel<16, 32, 8, 2><<<(NNODES + 127) / 128, 256, 0, stream>>>(g, rowptr, W2, b2, hB);

  // ---- layer 3: 32 -> 64 (g-gather) ----
  s_kernel<32><<<(NNODES * 4 + 255) / 256, 256, 0, stream>>>(hB, u3, s);
  q_kernel<<<(NNODES + 15) / 16, 256, 0, stream>>>(rowptr, col, s, c3, q);
  gatherG_kernel<32><<<(NNODES + 7) / 8, 256, 0, stream>>>(rowptr, col, q, hB, c3, g);
  transform_kernel<32, 64, 8, 4><<<(NNODES + 127) / 128, 256, 0, stream>>>(g, rowptr, W3, b3, hA);

  // ---- BN stats + MLP head ----
  stats_kernel<<<256, 256, 0, stream>>>(hA, sums);
  mlp_kernel<<<(NNODES + 255) / 256, 256, 0, stream>>>(hA, sums, gamma, beta, lw1, lb1,
                                                       lw2, lb2, lw3, lb3, lw4, lb4,
                                                       ow, ob, out);
}

// Round 8
// 325.076 us; speedup vs baseline: 1.7639x; 1.0095x over previous
//
#include <hip/hip_runtime.h>

#define NNODES 50000
#define NEDGES 800000
#define SCAN_BLOCKS ((NNODES + 255) / 256)   // 196
#define NPART (NNODES / 8)                   // 6250 nodes per XCD partition
#define EPS 2048                             // edges per slice
#define NSLICE ((NEDGES + EPS - 1) / EPS)    // 391

// ---------------- CSR build: histogram over dst + per-edge rank ----------------
// rank[e] = this edge's slot among same-dst edges (atomic return value).
__global__ __launch_bounds__(256) void hist_kernel(const int* __restrict__ ei,
                                                   int* __restrict__ counts,
                                                   int* __restrict__ rank) {
  int e = blockIdx.x * 256 + threadIdx.x;
  if (e < NEDGES) rank[e] = atomicAdd(&counts[ei[NEDGES + e]], 1);
}

__global__ __launch_bounds__(256) void scanA_kernel(const int* __restrict__ counts,
                                                    int* __restrict__ rowptr,
                                                    int* __restrict__ blockSum) {
  __shared__ int sm[256];
  int i = blockIdx.x * 256 + threadIdx.x;
  int v = (i < NNODES) ? counts[i] : 0;
  sm[threadIdx.x] = v;
  __syncthreads();
  for (int off = 1; off < 256; off <<= 1) {
    int x = (threadIdx.x >= off) ? sm[threadIdx.x - off] : 0;
    __syncthreads();
    sm[threadIdx.x] += x;
    __syncthreads();
  }
  if (i < NNODES) rowptr[i] = sm[threadIdx.x] - v;
  if (threadIdx.x == 255) blockSum[blockIdx.x] = sm[255];
}

__global__ __launch_bounds__(256) void scanB_kernel(int* __restrict__ blockSum,
                                                    int* __restrict__ blockOff) {
  __shared__ int sm[256];
  int v = (threadIdx.x < SCAN_BLOCKS) ? blockSum[threadIdx.x] : 0;
  sm[threadIdx.x] = v;
  __syncthreads();
  for (int off = 1; off < 256; off <<= 1) {
    int x = (threadIdx.x >= off) ? sm[threadIdx.x - off] : 0;
    __syncthreads();
    sm[threadIdx.x] += x;
    __syncthreads();
  }
  if (threadIdx.x < SCAN_BLOCKS) blockOff[threadIdx.x] = sm[threadIdx.x] - v;
}

__global__ __launch_bounds__(256) void scanC_kernel(int* __restrict__ rowptr,
                                                    const int* __restrict__ blockOff) {
  int i = blockIdx.x * 256 + threadIdx.x;
  if (i < NNODES) rowptr[i] += blockOff[blockIdx.x];
  if (i == 0) rowptr[NNODES] = NEDGES;
}

// Atomic-free XCD-partitioned scatter: WG (slice, p) streams slice with
// nontemporal loads (protect col write-lines in L2), writes only dst in
// partition p. pos is fully determined by rowptr+rank -> no RMW chain.
__global__ __launch_bounds__(256) void scatter_kernel(const int* __restrict__ ei,
                                                      const int* __restrict__ rowptr,
                                                      const int* __restrict__ rank,
                                                      int* __restrict__ col) {
  const int p = blockIdx.x & 7;
  const int sl = blockIdx.x >> 3;
  const int P0 = p * NPART;
  const int e1 = min((sl + 1) * EPS, NEDGES);
  for (int e = sl * EPS + threadIdx.x; e < e1; e += 256) {
    int dst = __builtin_nontemporal_load(&ei[NEDGES + e]);
    if ((unsigned)(dst - P0) < (unsigned)NPART) {
      int pos = rowptr[dst] + __builtin_nontemporal_load(&rank[e]);
      col[pos] = __builtin_nontemporal_load(&ei[e]);
    }
  }
}

// ---------------- t = x @ W1, stored [N][16][4] (layer 1 only) ----------------
// One wave per 8 nodes, direct grid; W column in 64 VGPRs (wave lane = column).
template<int FIN, int OUT, int NPW>
__global__ __launch_bounds__(256) void gemm_t_kernel(const float* __restrict__ x,
                                                     const float* __restrict__ W,
                                                     float* __restrict__ t) {
  constexpr int COLS = 4 * OUT;   // 64
  const int lane = threadIdx.x & 63;
  const int wv = threadIdx.x >> 6;
  const int o = lane >> 2, h = lane & 3;
  float wreg[FIN];
#pragma unroll
  for (int f = 0; f < FIN; ++f) wreg[f] = W[f * COLS + h * OUT + o];
  const int n0 = (blockIdx.x * 4 + wv) * NPW;
#pragma unroll 2
  for (int p = 0; p < NPW; ++p) {
    int n = n0 + p;
    if (n < NNODES) {
      const float4* xr = (const float4*)(x + (size_t)n * FIN);
      float acc = 0.f;
#pragma unroll
      for (int f4 = 0; f4 < FIN / 4; ++f4) {
        float4 xv = xr[f4];
        acc += wreg[4 * f4 + 0] * xv.x + wreg[4 * f4 + 1] * xv.y +
               wreg[4 * f4 + 2] * xv.z + wreg[4 * f4 + 3] * xv.w;
      }
      t[(size_t)n * COLS + lane] = acc;
    }
  }
}

// ---------------- s = x @ u  ([N,4]) ----------------
template<int FIN>
__global__ __launch_bounds__(256) void s_kernel(const float* __restrict__ x,
                                                const float* __restrict__ u,
                                                float* __restrict__ s) {
  int tid = blockIdx.x * 256 + threadIdx.x;
  int n = tid >> 2, h = tid & 3;
  if (n >= NNODES) return;
  const float4* xr = (const float4*)(x + (size_t)n * FIN);
  float acc = 0.f;
#pragma unroll
  for (int f4 = 0; f4 < FIN / 4; ++f4) {
    float4 xv = xr[f4];
    acc += xv.x * u[(4 * f4 + 0) * 4 + h] + xv.y * u[(4 * f4 + 1) * 4 + h] +
           xv.z * u[(4 * f4 + 2) * 4 + h] + xv.w * u[(4 * f4 + 3) * 4 + h];
  }
  s[tid] = acc;  // tid == n*4+h
}

// ---------------- per-edge q = softmax(s[src]-s[dst]+c), 16 lanes per node ----------------
__global__ __launch_bounds__(256) void q_kernel(const int* __restrict__ rowptr,
                                                const int* __restrict__ col,
                                                const float* __restrict__ s,
                                                const float* __restrict__ cptr,
                                                float* __restrict__ q) {
  const int lane = threadIdx.x & 15;
  const int sub = threadIdx.x >> 4;
  const int n = blockIdx.x * 16 + sub;
  if (n >= NNODES) return;
  float4 c4 = *(const float4*)cptr;
  float4 sd = *(const float4*)(s + 4 * (size_t)n);
  const int beg = rowptr[n], end = rowptr[n + 1];
  for (int idx = beg + lane; idx < end; idx += 16) {
    int src = col[idx];
    float4 ss = *(const float4*)(s + 4 * (size_t)src);
    float l0 = ss.x - sd.x + c4.x;
    float l1 = ss.y - sd.y + c4.y;
    float l2 = ss.z - sd.z + c4.z;
    float l3 = ss.w - sd.w + c4.w;
    float mx = fmaxf(fmaxf(l0, l1), fmaxf(l2, l3));
    float e0 = __expf(l0 - mx), e1 = __expf(l1 - mx);
    float e2 = __expf(l2 - mx), e3 = __expf(l3 - mx);
    float inv = 1.f / (e0 + e1 + e2 + e3);
    *(float4*)(q + 4 * (size_t)idx) = make_float4(e0 * inv, e1 * inv, e2 * inv, e3 * inv);
  }
}

// ---------------- layer-1 gather over t (16 lanes per dst node), 4x unrolled ----------------
__global__ __launch_bounds__(256) void gather1_kernel(const int* __restrict__ rowptr,
                                                      const int* __restrict__ col,
                                                      const float* __restrict__ q,
                                                      const float* __restrict__ t,
                                                      const float* __restrict__ cptr,
                                                      const float* __restrict__ bptr,
                                                      float* __restrict__ h) {
  const int lane = threadIdx.x & 15;
  const int sub = threadIdx.x >> 4;
  const int n = blockIdx.x * 16 + sub;
  if (n >= NNODES) return;
  float4 c4 = *(const float4*)cptr;
  float mxc = fmaxf(fmaxf(c4.x, c4.y), fmaxf(c4.z, c4.w));
  float qs0 = __expf(c4.x - mxc), qs1 = __expf(c4.y - mxc);
  float qs2 = __expf(c4.z - mxc), qs3 = __expf(c4.w - mxc);
  float sinv = 1.f / (qs0 + qs1 + qs2 + qs3);
  float4 tv = *((const float4*)(t + (size_t)n * 64) + lane);
  float acc = (qs0 * tv.x + qs1 * tv.y + qs2 * tv.z + qs3 * tv.w) * sinv;
  const int beg = rowptr[n], end = rowptr[n + 1];
  int idx = beg;
  for (; idx + 3 < end; idx += 4) {
    int s0 = col[idx], s1 = col[idx + 1], s2 = col[idx + 2], s3 = col[idx + 3];
    float4 q0 = *(const float4*)(q + 4 * (size_t)(idx + 0));
    float4 q1 = *(const float4*)(q + 4 * (size_t)(idx + 1));
    float4 q2 = *(const float4*)(q + 4 * (size_t)(idx + 2));
    float4 q3 = *(const float4*)(q + 4 * (size_t)(idx + 3));
    float4 t0 = *((const float4*)(t + (size_t)s0 * 64) + lane);
    float4 t1 = *((const float4*)(t + (size_t)s1 * 64) + lane);
    float4 t2 = *((const float4*)(t + (size_t)s2 * 64) + lane);
    float4 t3 = *((const float4*)(t + (size_t)s3 * 64) + lane);
    acc += q0.x * t0.x + q0.y * t0.y + q0.z * t0.z + q0.w * t0.w;
    acc += q1.x * t1.x + q1.y * t1.y + q1.z * t1.z + q1.w * t1.w;
    acc += q2.x * t2.x + q2.y * t2.y + q2.z * t2.z + q2.w * t2.w;
    acc += q3.x * t3.x + q3.y * t3.y + q3.z * t3.z + q3.w * t3.w;
  }
  for (; idx < end; ++idx) {
    int src = col[idx];
    float4 qv = *(const float4*)(q + 4 * (size_t)idx);
    float4 tw = *((const float4*)(t + (size_t)src * 64) + lane);
    acc += qv.x * tw.x + qv.y * tw.y + qv.z * tw.z + qv.w * tw.w;
  }
  float d = (float)(end - beg + 1);
  h[(size_t)n * 16 + lane] = fmaxf(acc / d + bptr[lane], 0.f);
}

// ---------------- g-gather: g[n][h][f] = sum_j q_jh * x_j[f], 4x unrolled ----------------
template<int FIN>
__global__ __launch_bounds__(256) void gatherG_kernel(const int* __restrict__ rowptr,
                                                      const int* __restrict__ col,
                                                      const float* __restrict__ q,
                                                      const float* __restrict__ x,
                                                      const float* __restrict__ cptr,
                                                      float* __restrict__ g) {
  constexpr int NSUB = 256 / FIN;
  const int f = threadIdx.x & (FIN - 1);
  const int sub = threadIdx.x / FIN;
  const int n = blockIdx.x * NSUB + sub;
  if (n >= NNODES) return;
  float4 c4 = *(const float4*)cptr;
  float mxc = fmaxf(fmaxf(c4.x, c4.y), fmaxf(c4.z, c4.w));
  float qs0 = __expf(c4.x - mxc), qs1 = __expf(c4.y - mxc);
  float qs2 = __expf(c4.z - mxc), qs3 = __expf(c4.w - mxc);
  float sinv = 1.f / (qs0 + qs1 + qs2 + qs3);
  float xn = x[(size_t)n * FIN + f];
  float g0 = qs0 * sinv * xn, g1 = qs1 * sinv * xn;
  float g2 = qs2 * sinv * xn, g3 = qs3 * sinv * xn;
  const int beg = rowptr[n], end = rowptr[n + 1];
  int idx = beg;
  for (; idx + 3 < end; idx += 4) {
    int s0 = col[idx], s1 = col[idx + 1], s2 = col[idx + 2], s3 = col[idx + 3];
    float4 q0 = *(const float4*)(q + 4 * (size_t)(idx + 0));
    float4 q1 = *(const float4*)(q + 4 * (size_t)(idx + 1));
    float4 q2 = *(const float4*)(q + 4 * (size_t)(idx + 2));
    float4 q3 = *(const float4*)(q + 4 * (size_t)(idx + 3));
    float x0 = x[(size_t)s0 * FIN + f];
    float x1 = x[(size_t)s1 * FIN + f];
    float x2 = x[(size_t)s2 * FIN + f];
    float x3 = x[(size_t)s3 * FIN + f];
    g0 += q0.x * x0 + q1.x * x1 + q2.x * x2 + q3.x * x3;
    g1 += q0.y * x0 + q1.y * x1 + q2.y * x2 + q3.y * x3;
    g2 += q0.z * x0 + q1.z * x1 + q2.z * x2 + q3.z * x3;
    g3 += q0.w * x0 + q1.w * x1 + q2.w * x2 + q3.w * x3;
  }
  for (; idx < end; ++idx) {
    int src = col[idx];
    float4 qv = *(const float4*)(q + 4 * (size_t)idx);
    float xv = x[(size_t)src * FIN + f];
    g0 += qv.x * xv; g1 += qv.y * xv; g2 += qv.z * xv; g3 += qv.w * xv;
  }
  float* gr = g + (size_t)n * 4 * FIN;
  gr[0 * FIN + f] = g0;
  gr[1 * FIN + f] = g1;
  gr[2 * FIN + f] = g2;
  gr[3 * FIN + f] = g3;
}

// ---------------- per-node transform: h[n][o] = relu((sum_h W_h g_h)/deg + b) ----------------
template<int FIN, int OUT, int MO, int NP>
__global__ __launch_bounds__(256) void transform_kernel(const float* __restrict__ g,
                                                        const int* __restrict__ rowptr,
                                                        const float* __restrict__ W,
                                                        const float* __restrict__ bptr,
                                                        float* __restrict__ h) {
  constexpr int K = 4 * FIN;          // g row length
  constexpr int OG = OUT / MO;        // o-groups per node
  constexpr int NG = 256 / OG;        // node-groups per block
  constexpr int NPB = NG * NP;        // nodes per block
  __shared__ float wsT[OUT * K];
  for (int i = threadIdx.x; i < OUT * K; i += 256) {
    int o = i / K, k = i - o * K;
    int hh = k / FIN, f = k - hh * FIN;
    int kg = k >> 2;
    int pg = kg ^ (o / MO);           // granule swizzle
    wsT[o * K + (pg << 2) + (k & 3)] = W[f * (4 * OUT) + hh * OUT + o];
  }
  __syncthreads();
  const int og = threadIdx.x & (OG - 1);
  const int ng = threadIdx.x / OG;
  const int o0 = og * MO;
  const int nb = blockIdx.x * NPB + ng * NP;
  float acc[NP][MO];
#pragma unroll
  for (int p = 0; p < NP; ++p)
#pragma unroll
    for (int m = 0; m < MO; ++m) acc[p][m] = 0.f;
  const float* gptr[NP];
#pragma unroll
  for (int p = 0; p < NP; ++p) {
    int n = nb + p;
    gptr[p] = g + (size_t)(n < NNODES ? n : NNODES - 1) * K;
  }
#pragma unroll 2
  for (int kg = 0; kg < K / 4; ++kg) {
    float4 av[NP];
#pragma unroll
    for (int p = 0; p < NP; ++p) av[p] = *(const float4*)(gptr[p] + (kg << 2));
#pragma unroll
    for (int m = 0; m < MO; ++m) {
      const float4 wv = *(const float4*)(&wsT[(o0 + m) * K + ((kg ^ og) << 2)]);
#pragma unroll
      for (int p = 0; p < NP; ++p)
        acc[p][m] += av[p].x * wv.x + av[p].y * wv.y + av[p].z * wv.z + av[p].w * wv.w;
    }
  }
#pragma unroll
  for (int p = 0; p < NP; ++p) {
    int n = nb + p;
    if (n < NNODES) {
      float inv = 1.f / (float)(rowptr[n + 1] - rowptr[n] + 1);
#pragma unroll
      for (int m = 0; m < MO; ++m)
        h[(size_t)n * OUT + o0 + m] = fmaxf(acc[p][m] * inv + bptr[o0 + m], 0.f);
    }
  }
}

// ---------------- BN batch-stats over h3 [N,64] ----------------
__global__ __launch_bounds__(256) void stats_kernel(const float* __restrict__ h3,
                                                    float* __restrict__ sums) {
  const int o = threadIdx.x & 63;
  const int r = threadIdx.x >> 6;
  float accS = 0.f, accQ = 0.f;
  for (int base = blockIdx.x * 4; base < NNODES; base += gridDim.x * 4) {
    int n = base + r;
    if (n < NNODES) {
      float v = h3[(size_t)n * 64 + o];
      accS += v;
      accQ += v * v;
    }
  }
  __shared__ float ls[256], lq[256];
  ls[threadIdx.x] = accS;
  lq[threadIdx.x] = accQ;
  __syncthreads();
  if (threadIdx.x < 64) {
    float a = ls[threadIdx.x] + ls[threadIdx.x + 64] + ls[threadIdx.x + 128] + ls[threadIdx.x + 192];
    float qq = lq[threadIdx.x] + lq[threadIdx.x + 64] + lq[threadIdx.x + 128] + lq[threadIdx.x + 192];
    atomicAdd(&sums[threadIdx.x], a);
    atomicAdd(&sums[64 + threadIdx.x], qq);
  }
}

// ---------------- BN + MLP head + sigmoid, one thread per node ----------------
__global__ __launch_bounds__(256) void mlp_kernel(
    const float* __restrict__ h3, const float* __restrict__ sums,
    const float* __restrict__ gamma, const float* __restrict__ beta,
    const float* __restrict__ lw1, const float* __restrict__ lb1,
    const float* __restrict__ lw2, const float* __restrict__ lb2,
    const float* __restrict__ lw3, const float* __restrict__ lb3,
    const float* __restrict__ lw4, const float* __restrict__ lb4,
    const float* __restrict__ ow, const float* __restrict__ ob,
    float* __restrict__ out) {
  __shared__ float w1[64 * 32], w2[32 * 16], w3[16 * 8], w4[8 * 4];
  __shared__ float b1s[32], b2s[16], b3s[8], b4s[4], wos[4];
  __shared__ float scale[64], shift[64];
  int tid = threadIdx.x;
  for (int i = tid; i < 64 * 32; i += 256) w1[i] = lw1[i];
  for (int i = tid; i < 32 * 16; i += 256) w2[i] = lw2[i];
  if (tid < 128) w3[tid] = lw3[tid];
  if (tid < 32) { w4[tid] = lw4[tid]; b1s[tid] = lb1[tid]; }
  if (tid < 16) b2s[tid] = lb2[tid];
  if (tid < 8) b3s[tid] = lb3[tid];
  if (tid < 4) { b4s[tid] = lb4[tid]; wos[tid] = ow[tid]; }
  if (tid < 64) {
    float mu = sums[tid] * (1.f / NNODES);
    float var = sums[64 + tid] * (1.f / NNODES) - mu * mu;
    float sc = rsqrtf(var + 1e-5f) * gamma[tid];
    scale[tid] = sc;
    shift[tid] = beta[tid] - mu * sc;
  }
  __syncthreads();
  int n = blockIdx.x * 256 + tid;
  if (n >= NNODES) return;
  float obv = ob[0];
  const float4* hr = (const float4*)(h3 + (size_t)n * 64);
  float z1[32];
#pragma unroll
  for (int j = 0; j < 32; ++j) z1[j] = b1s[j];
  for (int i4 = 0; i4 < 16; ++i4) {
    float4 hv = hr[i4];
    float a0 = hv.x * scale[4 * i4 + 0] + shift[4 * i4 + 0];
    float a1 = hv.y * scale[4 * i4 + 1] + shift[4 * i4 + 1];
    float a2 = hv.z * scale[4 * i4 + 2] + shift[4 * i4 + 2];
    float a3 = hv.w * scale[4 * i4 + 3] + shift[4 * i4 + 3];
#pragma unroll
    for (int j = 0; j < 32; ++j) {
      z1[j] += a0 * w1[(4 * i4 + 0) * 32 + j] + a1 * w1[(4 * i4 + 1) * 32 + j] +
               a2 * w1[(4 * i4 + 2) * 32 + j] + a3 * w1[(4 * i4 + 3) * 32 + j];
    }
  }
  float z2[16];
#pragma unroll
  for (int j = 0; j < 16; ++j) z2[j] = b2s[j];
  for (int i = 0; i < 32; ++i) {
    float a = fmaxf(z1[i], 0.f);
#pragma unroll
    for (int j = 0; j < 16; ++j) z2[j] += a * w2[i * 16 + j];
  }
  float z3[8];
#pragma unroll
  for (int j = 0; j < 8; ++j) z3[j] = b3s[j];
  for (int i = 0; i < 16; ++i) {
    float a = fmaxf(z2[i], 0.f);
#pragma unroll
    for (int j = 0; j < 8; ++j) z3[j] += a * w3[i * 8 + j];
  }
  float z4[4];
#pragma unroll
  for (int j = 0; j < 4; ++j) z4[j] = b4s[j];
  for (int i = 0; i < 8; ++i) {
    float a = fmaxf(z3[i], 0.f);
#pragma unroll
    for (int j = 0; j < 4; ++j) z4[j] += a * w4[i * 4 + j];
  }
  float zo = obv;
#pragma unroll
  for (int i = 0; i < 4; ++i) zo += fmaxf(z4[i], 0.f) * wos[i];
  out[n] = 1.f / (1.f + __expf(-zo));
}

extern "C" void kernel_launch(void* const* d_in, const int* in_sizes, int n_in,
                              void* d_out, int out_size, void* d_ws, size_t ws_size,
                              hipStream_t stream) {
  const float* x  = (const float*)d_in[0];
  const int*   ei = (const int*)d_in[1];
  const float* W1 = (const float*)d_in[2];  const float* u1 = (const float*)d_in[3];
  const float* c1 = (const float*)d_in[4];  const float* b1 = (const float*)d_in[5];
  const float* W2 = (const float*)d_in[6];  const float* u2 = (const float*)d_in[7];
  const float* c2 = (const float*)d_in[8];  const float* b2 = (const float*)d_in[9];
  const float* W3 = (const float*)d_in[10]; const float* u3 = (const float*)d_in[11];
  const float* c3 = (const float*)d_in[12]; const float* b3 = (const float*)d_in[13];
  const float* gamma = (const float*)d_in[14]; const float* beta = (const float*)d_in[15];
  const float* lw1 = (const float*)d_in[16]; const float* lb1 = (const float*)d_in[17];
  const float* lw2 = (const float*)d_in[18]; const float* lb2 = (const float*)d_in[19];
  const float* lw3 = (const float*)d_in[20]; const float* lb3 = (const float*)d_in[21];
  const float* lw4 = (const float*)d_in[22]; const float* lb4 = (const float*)d_in[23];
  const float* ow  = (const float*)d_in[24]; const float* ob  = (const float*)d_in[25];
  float* out = (float*)d_out;

  float* t    = (float*)d_ws;                         // N*64   (layer-1 t)
  float* g    = t + (size_t)NNODES * 64;              // N*128  (g buffer, max 4*32)
  float* hA   = g + (size_t)NNODES * 128;             // N*64
  float* hB   = hA + (size_t)NNODES * 64;             // N*64
  float* s    = hB + (size_t)NNODES * 64;             // N*4
  float* q    = s + (size_t)NNODES * 4;               // E*4
  float* sums = q + (size_t)NEDGES * 4;               // 128
  int*   rowptr   = (int*)(sums + 128);               // N+1 (pad 8)
  int*   counts   = rowptr + NNODES + 8;              // N
  int*   blockSum = counts + NNODES;                  // 256
  int*   blockOff = blockSum + 256;                   // 256
  int*   col      = blockOff + 256;                   // E
  int*   rank     = col + NEDGES;                     // E

  hipMemsetAsync(counts, 0, NNODES * sizeof(int), stream);
  hipMemsetAsync(sums, 0, 128 * sizeof(float), stream);

  // ---- CSR by dst (atomic-free scatter via hist-assigned ranks) ----
  hist_kernel<<<(NEDGES + 255) / 256, 256, 0, stream>>>(ei, counts, rank);
  scanA_kernel<<<SCAN_BLOCKS, 256, 0, stream>>>(counts, rowptr, blockSum);
  scanB_kernel<<<1, 256, 0, stream>>>(blockSum, blockOff);
  scanC_kernel<<<SCAN_BLOCKS, 256, 0, stream>>>(rowptr, blockOff);
  scatter_kernel<<<NSLICE * 8, 256, 0, stream>>>(ei, rowptr, rank, col);

  // ---- layer 1: 64 -> 16 (t-gather) ----
  gemm_t_kernel<64, 16, 8><<<(NNODES + 31) / 32, 256, 0, stream>>>(x, W1, t);
  s_kernel<64><<<(NNODES * 4 + 255) / 256, 256, 0, stream>>>(x, u1, s);
  q_kernel<<<(NNODES + 15) / 16, 256, 0, stream>>>(rowptr, col, s, c1, q);
  gather1_kernel<<<(NNODES + 15) / 16, 256, 0, stream>>>(rowptr, col, q, t, c1, b1, hA);

  // ---- layer 2: 16 -> 32 (g-gather) ----
  s_kernel<16><<<(NNODES * 4 + 255) / 256, 256, 0, stream>>>(hA, u2, s);
  q_kernel<<<(NNODES + 15) / 16, 256, 0, stream>>>(rowptr, col, s, c2, q);
  gatherG_kernel<16><<<(NNODES + 15) / 16, 256, 0, stream>>>(rowptr, col, q, hA, c2, g);
  transform_kernel<16, 32, 8, 2><<<(NNODES + 127) / 128, 256, 0, stream>>>(g, rowptr, W2, b2, hB);

  // ---- layer 3: 32 -> 64 (g-gather) ----
  s_kernel<32><<<(NNODES * 4 + 255) / 256, 256, 0, stream>>>(hB, u3, s);
  q_kernel<<<(NNODES + 15) / 16, 256, 0, stream>>>(rowptr, col, s, c3, q);
  gatherG_kernel<32><<<(NNODES + 7) / 8, 256, 0, stream>>>(rowptr, col, q, hB, c3, g);
  transform_kernel<32, 64, 8, 4><<<(NNODES + 127) / 128, 256, 0, stream>>>(g, rowptr, W3, b3, hA);

  // ---- BN stats + MLP head ----
  stats_kernel<<<256, 256, 0, stream>>>(hA, sums);
  mlp_kernel<<<(NNODES + 255) / 256, 256, 0, stream>>>(hA, sums, gamma, beta, lw1, lb1,
                                                       lw2, lb2, lw3, lb3, lw4, lb4,
                                                       ow, ob, out);
}

// Round 9
// 307.257 us; speedup vs baseline: 1.8662x; 1.0580x over previous
//
#include <hip/hip_runtime.h>

#define NNODES 50000
#define NEDGES 800000
#define SCAN_BLOCKS ((NNODES + 255) / 256)   // 196
#define NPART (NNODES / 8)                   // 6250 nodes per XCD partition
#define EPS 2048                             // edges per slice
#define NSLICE ((NEDGES + EPS - 1) / EPS)    // 391

// ---------------- CSR build: histogram over dst + per-edge rank ----------------
__global__ __launch_bounds__(256) void hist_kernel(const int* __restrict__ ei,
                                                   int* __restrict__ counts,
                                                   int* __restrict__ rank) {
  int e = blockIdx.x * 256 + threadIdx.x;
  if (e < NEDGES) rank[e] = atomicAdd(&counts[ei[NEDGES + e]], 1);
}

__global__ __launch_bounds__(256) void scanA_kernel(const int* __restrict__ counts,
                                                    int* __restrict__ rowptr,
                                                    int* __restrict__ blockSum) {
  __shared__ int sm[256];
  int i = blockIdx.x * 256 + threadIdx.x;
  int v = (i < NNODES) ? counts[i] : 0;
  sm[threadIdx.x] = v;
  __syncthreads();
  for (int off = 1; off < 256; off <<= 1) {
    int x = (threadIdx.x >= off) ? sm[threadIdx.x - off] : 0;
    __syncthreads();
    sm[threadIdx.x] += x;
    __syncthreads();
  }
  if (i < NNODES) rowptr[i] = sm[threadIdx.x] - v;
  if (threadIdx.x == 255) blockSum[blockIdx.x] = sm[255];
}

__global__ __launch_bounds__(256) void scanB_kernel(int* __restrict__ blockSum,
                                                    int* __restrict__ blockOff) {
  __shared__ int sm[256];
  int v = (threadIdx.x < SCAN_BLOCKS) ? blockSum[threadIdx.x] : 0;
  sm[threadIdx.x] = v;
  __syncthreads();
  for (int off = 1; off < 256; off <<= 1) {
    int x = (threadIdx.x >= off) ? sm[threadIdx.x - off] : 0;
    __syncthreads();
    sm[threadIdx.x] += x;
    __syncthreads();
  }
  if (threadIdx.x < SCAN_BLOCKS) blockOff[threadIdx.x] = sm[threadIdx.x] - v;
}

__global__ __launch_bounds__(256) void scanC_kernel(int* __restrict__ rowptr,
                                                    const int* __restrict__ blockOff) {
  int i = blockIdx.x * 256 + threadIdx.x;
  if (i < NNODES) rowptr[i] += blockOff[blockIdx.x];
  if (i == 0) rowptr[NNODES] = NEDGES;
}

// Atomic-free XCD-partitioned scatter.
__global__ __launch_bounds__(256) void scatter_kernel(const int* __restrict__ ei,
                                                      const int* __restrict__ rowptr,
                                                      const int* __restrict__ rank,
                                                      int* __restrict__ col) {
  const int p = blockIdx.x & 7;
  const int sl = blockIdx.x >> 3;
  const int P0 = p * NPART;
  const int e1 = min((sl + 1) * EPS, NEDGES);
  for (int e = sl * EPS + threadIdx.x; e < e1; e += 256) {
    int dst = __builtin_nontemporal_load(&ei[NEDGES + e]);
    if ((unsigned)(dst - P0) < (unsigned)NPART) {
      int pos = rowptr[dst] + __builtin_nontemporal_load(&rank[e]);
      col[pos] = __builtin_nontemporal_load(&ei[e]);
    }
  }
}

// ---------------- layer-1 t = x @ W1, stored t[n][j] with j=o*4+h (col c(j)=h*16+o) ----
// Tiled like transform_kernel: W^T in LDS (swizzled), MO outputs x NP nodes per
// thread, float4 k-vec. No per-thread W array -> no scratch spill (round-8 bug).
template<int MO, int NP>
__global__ __launch_bounds__(256) void gemm1_kernel(const float* __restrict__ x,
                                                    const float* __restrict__ W,
                                                    float* __restrict__ t) {
  constexpr int K = 64, OUT = 64;
  constexpr int OG = OUT / MO;        // 8
  constexpr int NG = 256 / OG;        // 32
  constexpr int NPB = NG * NP;        // 64
  __shared__ float wsT[OUT * K];
  for (int i = threadIdx.x; i < OUT * K; i += 256) {
    int k = i >> 6, j = i & 63;
    int c = ((j & 3) << 4) + (j >> 2);   // t-slot j <- W column c
    int sg = (k >> 2) ^ (j / MO);        // granule swizzle
    wsT[j * K + (sg << 2) + (k & 3)] = W[k * OUT + c];   // coalesced read (c is a perm)
  }
  __syncthreads();
  const int og = threadIdx.x & (OG - 1);
  const int ng = threadIdx.x / OG;
  const int o0 = og * MO;
  const int nb = blockIdx.x * NPB + ng * NP;
  float acc[NP][MO];
#pragma unroll
  for (int p = 0; p < NP; ++p)
#pragma unroll
    for (int m = 0; m < MO; ++m) acc[p][m] = 0.f;
  const float* xp[NP];
#pragma unroll
  for (int p = 0; p < NP; ++p) {
    int n = nb + p;
    xp[p] = x + (size_t)(n < NNODES ? n : NNODES - 1) * K;
  }
#pragma unroll 2
  for (int kg = 0; kg < K / 4; ++kg) {
    float4 av[NP];
#pragma unroll
    for (int p = 0; p < NP; ++p) av[p] = *(const float4*)(xp[p] + (kg << 2));
#pragma unroll
    for (int m = 0; m < MO; ++m) {
      const float4 wv = *(const float4*)(&wsT[(o0 + m) * K + ((kg ^ og) << 2)]);
#pragma unroll
      for (int p = 0; p < NP; ++p)
        acc[p][m] += av[p].x * wv.x + av[p].y * wv.y + av[p].z * wv.z + av[p].w * wv.w;
    }
  }
#pragma unroll
  for (int p = 0; p < NP; ++p) {
    int n = nb + p;
    if (n < NNODES) {
#pragma unroll
      for (int m = 0; m < MO; ++m) t[(size_t)n * OUT + o0 + m] = acc[p][m];
    }
  }
}

// ---------------- s = x @ u  ([N,4]) ----------------
template<int FIN>
__global__ __launch_bounds__(256) void s_kernel(const float* __restrict__ x,
                                                const float* __restrict__ u,
                                                float* __restrict__ s) {
  int tid = blockIdx.x * 256 + threadIdx.x;
  int n = tid >> 2, h = tid & 3;
  if (n >= NNODES) return;
  const float4* xr = (const float4*)(x + (size_t)n * FIN);
  float acc = 0.f;
#pragma unroll
  for (int f4 = 0; f4 < FIN / 4; ++f4) {
    float4 xv = xr[f4];
    acc += xv.x * u[(4 * f4 + 0) * 4 + h] + xv.y * u[(4 * f4 + 1) * 4 + h] +
           xv.z * u[(4 * f4 + 2) * 4 + h] + xv.w * u[(4 * f4 + 3) * 4 + h];
  }
  s[tid] = acc;  // tid == n*4+h
}

// ---------------- per-edge q = softmax(s[src]-s[dst]+c), 16 lanes per node ----------------
__global__ __launch_bounds__(256) void q_kernel(const int* __restrict__ rowptr,
                                                const int* __restrict__ col,
                                                const float* __restrict__ s,
                                                const float* __restrict__ cptr,
                                                float* __restrict__ q) {
  const int lane = threadIdx.x & 15;
  const int sub = threadIdx.x >> 4;
  const int n = blockIdx.x * 16 + sub;
  if (n >= NNODES) return;
  float4 c4 = *(const float4*)cptr;
  float4 sd = *(const float4*)(s + 4 * (size_t)n);
  const int beg = rowptr[n], end = rowptr[n + 1];
  for (int idx = beg + lane; idx < end; idx += 16) {
    int src = col[idx];
    float4 ss = *(const float4*)(s + 4 * (size_t)src);
    float l0 = ss.x - sd.x + c4.x;
    float l1 = ss.y - sd.y + c4.y;
    float l2 = ss.z - sd.z + c4.z;
    float l3 = ss.w - sd.w + c4.w;
    float mx = fmaxf(fmaxf(l0, l1), fmaxf(l2, l3));
    float e0 = __expf(l0 - mx), e1 = __expf(l1 - mx);
    float e2 = __expf(l2 - mx), e3 = __expf(l3 - mx);
    float inv = 1.f / (e0 + e1 + e2 + e3);
    *(float4*)(q + 4 * (size_t)idx) = make_float4(e0 * inv, e1 * inv, e2 * inv, e3 * inv);
  }
}

// ---------------- layer-1 gather over t (16 lanes per dst node), 4x unrolled ----------------
__global__ __launch_bounds__(256) void gather1_kernel(const int* __restrict__ rowptr,
                                                      const int* __restrict__ col,
                                                      const float* __restrict__ q,
                                                      const float* __restrict__ t,
                                                      const float* __restrict__ cptr,
                                                      const float* __restrict__ bptr,
                                                      float* __restrict__ h) {
  const int lane = threadIdx.x & 15;
  const int sub = threadIdx.x >> 4;
  const int n = blockIdx.x * 16 + sub;
  if (n >= NNODES) return;
  float4 c4 = *(const float4*)cptr;
  float mxc = fmaxf(fmaxf(c4.x, c4.y), fmaxf(c4.z, c4.w));
  float qs0 = __expf(c4.x - mxc), qs1 = __expf(c4.y - mxc);
  float qs2 = __expf(c4.z - mxc), qs3 = __expf(c4.w - mxc);
  float sinv = 1.f / (qs0 + qs1 + qs2 + qs3);
  float4 tv = *((const float4*)(t + (size_t)n * 64) + lane);
  float acc = (qs0 * tv.x + qs1 * tv.y + qs2 * tv.z + qs3 * tv.w) * sinv;
  const int beg = rowptr[n], end = rowptr[n + 1];
  int idx = beg;
  for (; idx + 3 < end; idx += 4) {
    int s0 = col[idx], s1 = col[idx + 1], s2 = col[idx + 2], s3 = col[idx + 3];
    float4 q0 = *(const float4*)(q + 4 * (size_t)(idx + 0));
    float4 q1 = *(const float4*)(q + 4 * (size_t)(idx + 1));
    float4 q2 = *(const float4*)(q + 4 * (size_t)(idx + 2));
    float4 q3 = *(const float4*)(q + 4 * (size_t)(idx + 3));
    float4 t0 = *((const float4*)(t + (size_t)s0 * 64) + lane);
    float4 t1 = *((const float4*)(t + (size_t)s1 * 64) + lane);
    float4 t2 = *((const float4*)(t + (size_t)s2 * 64) + lane);
    float4 t3 = *((const float4*)(t + (size_t)s3 * 64) + lane);
    acc += q0.x * t0.x + q0.y * t0.y + q0.z * t0.z + q0.w * t0.w;
    acc += q1.x * t1.x + q1.y * t1.y + q1.z * t1.z + q1.w * t1.w;
    acc += q2.x * t2.x + q2.y * t2.y + q2.z * t2.z + q2.w * t2.w;
    acc += q3.x * t3.x + q3.y * t3.y + q3.z * t3.z + q3.w * t3.w;
  }
  for (; idx < end; ++idx) {
    int src = col[idx];
    float4 qv = *(const float4*)(q + 4 * (size_t)idx);
    float4 tw = *((const float4*)(t + (size_t)src * 64) + lane);
    acc += qv.x * tw.x + qv.y * tw.y + qv.z * tw.z + qv.w * tw.w;
  }
  float d = (float)(end - beg + 1);
  h[(size_t)n * 16 + lane] = fmaxf(acc / d + bptr[lane], 0.f);
}

// ---------------- g-gather: g[n][h][f] = sum_j q_jh * x_j[f], 4x unrolled ----------------
template<int FIN>
__global__ __launch_bounds__(256) void gatherG_kernel(const int* __restrict__ rowptr,
                                                      const int* __restrict__ col,
                                                      const float* __restrict__ q,
                                                      const float* __restrict__ x,
                                                      const float* __restrict__ cptr,
                                                      float* __restrict__ g) {
  constexpr int NSUB = 256 / FIN;
  const int f = threadIdx.x & (FIN - 1);
  const int sub = threadIdx.x / FIN;
  const int n = blockIdx.x * NSUB + sub;
  if (n >= NNODES) return;
  float4 c4 = *(const float4*)cptr;
  float mxc = fmaxf(fmaxf(c4.x, c4.y), fmaxf(c4.z, c4.w));
  float qs0 = __expf(c4.x - mxc), qs1 = __expf(c4.y - mxc);
  float qs2 = __expf(c4.z - mxc), qs3 = __expf(c4.w - mxc);
  float sinv = 1.f / (qs0 + qs1 + qs2 + qs3);
  float xn = x[(size_t)n * FIN + f];
  float g0 = qs0 * sinv * xn, g1 = qs1 * sinv * xn;
  float g2 = qs2 * sinv * xn, g3 = qs3 * sinv * xn;
  const int beg = rowptr[n], end = rowptr[n + 1];
  int idx = beg;
  for (; idx + 3 < end; idx += 4) {
    int s0 = col[idx], s1 = col[idx + 1], s2 = col[idx + 2], s3 = col[idx + 3];
    float4 q0 = *(const float4*)(q + 4 * (size_t)(idx + 0));
    float4 q1 = *(const float4*)(q + 4 * (size_t)(idx + 1));
    float4 q2 = *(const float4*)(q + 4 * (size_t)(idx + 2));
    float4 q3 = *(const float4*)(q + 4 * (size_t)(idx + 3));
    float x0 = x[(size_t)s0 * FIN + f];
    float x1 = x[(size_t)s1 * FIN + f];
    float x2 = x[(size_t)s2 * FIN + f];
    float x3 = x[(size_t)s3 * FIN + f];
    g0 += q0.x * x0 + q1.x * x1 + q2.x * x2 + q3.x * x3;
    g1 += q0.y * x0 + q1.y * x1 + q2.y * x2 + q3.y * x3;
    g2 += q0.z * x0 + q1.z * x1 + q2.z * x2 + q3.z * x3;
    g3 += q0.w * x0 + q1.w * x1 + q2.w * x2 + q3.w * x3;
  }
  for (; idx < end; ++idx) {
    int src = col[idx];
    float4 qv = *(const float4*)(q + 4 * (size_t)idx);
    float xv = x[(size_t)src * FIN + f];
    g0 += qv.x * xv; g1 += qv.y * xv; g2 += qv.z * xv; g3 += qv.w * xv;
  }
  float* gr = g + (size_t)n * 4 * FIN;
  gr[0 * FIN + f] = g0;
  gr[1 * FIN + f] = g1;
  gr[2 * FIN + f] = g2;
  gr[3 * FIN + f] = g3;
}

// ---------------- per-node transform: h[n][o] = relu((sum_h W_h g_h)/deg + b) ----------------
template<int FIN, int OUT, int MO, int NP>
__global__ __launch_bounds__(256) void transform_kernel(const float* __restrict__ g,
                                                        const int* __restrict__ rowptr,
                                                        const float* __restrict__ W,
                                                        const float* __restrict__ bptr,
                                                        float* __restrict__ h) {
  constexpr int K = 4 * FIN;          // g row length
  constexpr int OG = OUT / MO;        // o-groups per node
  constexpr int NG = 256 / OG;        // node-groups per block
  constexpr int NPB = NG * NP;        // nodes per block
  __shared__ float wsT[OUT * K];
  for (int i = threadIdx.x; i < OUT * K; i += 256) {
    int o = i / K, k = i - o * K;
    int hh = k / FIN, f = k - hh * FIN;
    int kg = k >> 2;
    int pg = kg ^ (o / MO);           // granule swizzle
    wsT[o * K + (pg << 2) + (k & 3)] = W[f * (4 * OUT) + hh * OUT + o];
  }
  __syncthreads();
  const int og = threadIdx.x & (OG - 1);
  const int ng = threadIdx.x / OG;
  const int o0 = og * MO;
  const int nb = blockIdx.x * NPB + ng * NP;
  float acc[NP][MO];
#pragma unroll
  for (int p = 0; p < NP; ++p)
#pragma unroll
    for (int m = 0; m < MO; ++m) acc[p][m] = 0.f;
  const float* gptr[NP];
#pragma unroll
  for (int p = 0; p < NP; ++p) {
    int n = nb + p;
    gptr[p] = g + (size_t)(n < NNODES ? n : NNODES - 1) * K;
  }
#pragma unroll 2
  for (int kg = 0; kg < K / 4; ++kg) {
    float4 av[NP];
#pragma unroll
    for (int p = 0; p < NP; ++p) av[p] = *(const float4*)(gptr[p] + (kg << 2));
#pragma unroll
    for (int m = 0; m < MO; ++m) {
      const float4 wv = *(const float4*)(&wsT[(o0 + m) * K + ((kg ^ og) << 2)]);
#pragma unroll
      for (int p = 0; p < NP; ++p)
        acc[p][m] += av[p].x * wv.x + av[p].y * wv.y + av[p].z * wv.z + av[p].w * wv.w;
    }
  }
#pragma unroll
  for (int p = 0; p < NP; ++p) {
    int n = nb + p;
    if (n < NNODES) {
      float inv = 1.f / (float)(rowptr[n + 1] - rowptr[n] + 1);
#pragma unroll
      for (int m = 0; m < MO; ++m)
        h[(size_t)n * OUT + o0 + m] = fmaxf(acc[p][m] * inv + bptr[o0 + m], 0.f);
    }
  }
}

// ---------------- BN batch-stats over h3 [N,64] ----------------
__global__ __launch_bounds__(256) void stats_kernel(const float* __restrict__ h3,
                                                    float* __restrict__ sums) {
  const int o = threadIdx.x & 63;
  const int r = threadIdx.x >> 6;
  float accS = 0.f, accQ = 0.f;
  for (int base = blockIdx.x * 4; base < NNODES; base += gridDim.x * 4) {
    int n = base + r;
    if (n < NNODES) {
      float v = h3[(size_t)n * 64 + o];
      accS += v;
      accQ += v * v;
    }
  }
  __shared__ float ls[256], lq[256];
  ls[threadIdx.x] = accS;
  lq[threadIdx.x] = accQ;
  __syncthreads();
  if (threadIdx.x < 64) {
    float a = ls[threadIdx.x] + ls[threadIdx.x + 64] + ls[threadIdx.x + 128] + ls[threadIdx.x + 192];
    float qq = lq[threadIdx.x] + lq[threadIdx.x + 64] + lq[threadIdx.x + 128] + lq[threadIdx.x + 192];
    atomicAdd(&sums[threadIdx.x], a);
    atomicAdd(&sums[64 + threadIdx.x], qq);
  }
}

// ---------------- BN + MLP head + sigmoid, one thread per node ----------------
__global__ __launch_bounds__(256) void mlp_kernel(
    const float* __restrict__ h3, const float* __restrict__ sums,
    const float* __restrict__ gamma, const float* __restrict__ beta,
    const float* __restrict__ lw1, const float* __restrict__ lb1,
    const float* __restrict__ lw2, const float* __restrict__ lb2,
    const float* __restrict__ lw3, const float* __restrict__ lb3,
    const float* __restrict__ lw4, const float* __restrict__ lb4,
    const float* __restrict__ ow, const float* __restrict__ ob,
    float* __restrict__ out) {
  __shared__ float w1[64 * 32], w2[32 * 16], w3[16 * 8], w4[8 * 4];
  __shared__ float b1s[32], b2s[16], b3s[8], b4s[4], wos[4];
  __shared__ float scale[64], shift[64];
  int tid = threadIdx.x;
  for (int i = tid; i < 64 * 32; i += 256) w1[i] = lw1[i];
  for (int i = tid; i < 32 * 16; i += 256) w2[i] = lw2[i];
  if (tid < 128) w3[tid] = lw3[tid];
  if (tid < 32) { w4[tid] = lw4[tid]; b1s[tid] = lb1[tid]; }
  if (tid < 16) b2s[tid] = lb2[tid];
  if (tid < 8) b3s[tid] = lb3[tid];
  if (tid < 4) { b4s[tid] = lb4[tid]; wos[tid] = ow[tid]; }
  if (tid < 64) {
    float mu = sums[tid] * (1.f / NNODES);
    float var = sums[64 + tid] * (1.f / NNODES) - mu * mu;
    float sc = rsqrtf(var + 1e-5f) * gamma[tid];
    scale[tid] = sc;
    shift[tid] = beta[tid] - mu * sc;
  }
  __syncthreads();
  int n = blockIdx.x * 256 + tid;
  if (n >= NNODES) return;
  float obv = ob[0];
  const float4* hr = (const float4*)(h3 + (size_t)n * 64);
  float z1[32];
#pragma unroll
  for (int j = 0; j < 32; ++j) z1[j] = b1s[j];
  for (int i4 = 0; i4 < 16; ++i4) {
    float4 hv = hr[i4];
    float a0 = hv.x * scale[4 * i4 + 0] + shift[4 * i4 + 0];
    float a1 = hv.y * scale[4 * i4 + 1] + shift[4 * i4 + 1];
    float a2 = hv.z * scale[4 * i4 + 2] + shift[4 * i4 + 2];
    float a3 = hv.w * scale[4 * i4 + 3] + shift[4 * i4 + 3];
#pragma unroll
    for (int j = 0; j < 32; ++j) {
      z1[j] += a0 * w1[(4 * i4 + 0) * 32 + j] + a1 * w1[(4 * i4 + 1) * 32 + j] +
               a2 * w1[(4 * i4 + 2) * 32 + j] + a3 * w1[(4 * i4 + 3) * 32 + j];
    }
  }
  float z2[16];
#pragma unroll
  for (int j = 0; j < 16; ++j) z2[j] = b2s[j];
  for (int i = 0; i < 32; ++i) {
    float a = fmaxf(z1[i], 0.f);
#pragma unroll
    for (int j = 0; j < 16; ++j) z2[j] += a * w2[i * 16 + j];
  }
  float z3[8];
#pragma unroll
  for (int j = 0; j < 8; ++j) z3[j] = b3s[j];
  for (int i = 0; i < 16; ++i) {
    float a = fmaxf(z2[i], 0.f);
#pragma unroll
    for (int j = 0; j < 8; ++j) z3[j] += a * w3[i * 8 + j];
  }
  float z4[4];
#pragma unroll
  for (int j = 0; j < 4; ++j) z4[j] = b4s[j];
  for (int i = 0; i < 8; ++i) {
    float a = fmaxf(z3[i], 0.f);
#pragma unroll
    for (int j = 0; j < 4; ++j) z4[j] += a * w4[i * 4 + j];
  }
  float zo = obv;
#pragma unroll
  for (int i = 0; i < 4; ++i) zo += fmaxf(z4[i], 0.f) * wos[i];
  out[n] = 1.f / (1.f + __expf(-zo));
}

extern "C" void kernel_launch(void* const* d_in, const int* in_sizes, int n_in,
                              void* d_out, int out_size, void* d_ws, size_t ws_size,
                              hipStream_t stream) {
  const float* x  = (const float*)d_in[0];
  const int*   ei = (const int*)d_in[1];
  const float* W1 = (const float*)d_in[2];  const float* u1 = (const float*)d_in[3];
  const float* c1 = (const float*)d_in[4];  const float* b1 = (const float*)d_in[5];
  const float* W2 = (const float*)d_in[6];  const float* u2 = (const float*)d_in[7];
  const float* c2 = (const float*)d_in[8];  const float* b2 = (const float*)d_in[9];
  const float* W3 = (const float*)d_in[10]; const float* u3 = (const float*)d_in[11];
  const float* c3 = (const float*)d_in[12]; const float* b3 = (const float*)d_in[13];
  const float* gamma = (const float*)d_in[14]; const float* beta = (const float*)d_in[15];
  const float* lw1 = (const float*)d_in[16]; const float* lb1 = (const float*)d_in[17];
  const float* lw2 = (const float*)d_in[18]; const float* lb2 = (const float*)d_in[19];
  const float* lw3 = (const float*)d_in[20]; const float* lb3 = (const float*)d_in[21];
  const float* lw4 = (const float*)d_in[22]; const float* lb4 = (const float*)d_in[23];
  const float* ow  = (const float*)d_in[24]; const float* ob  = (const float*)d_in[25];
  float* out = (float*)d_out;

  float* t    = (float*)d_ws;                         // N*64   (layer-1 t)
  float* g    = t + (size_t)NNODES * 64;              // N*128  (g buffer, max 4*32)
  float* hA   = g + (size_t)NNODES * 128;             // N*64
  float* hB   = hA + (size_t)NNODES * 64;             // N*64
  float* s    = hB + (size_t)NNODES * 64;             // N*4
  float* q    = s + (size_t)NNODES * 4;               // E*4
  float* sums = q + (size_t)NEDGES * 4;               // 128
  int*   rowptr   = (int*)(sums + 128);               // N+1 (pad 8)
  int*   counts   = rowptr + NNODES + 8;              // N
  int*   blockSum = counts + NNODES;                  // 256
  int*   blockOff = blockSum + 256;                   // 256
  int*   col      = blockOff + 256;                   // E
  int*   rank     = col + NEDGES;                     // E

  hipMemsetAsync(counts, 0, NNODES * sizeof(int), stream);
  hipMemsetAsync(sums, 0, 128 * sizeof(float), stream);

  // ---- CSR by dst (atomic-free scatter via hist-assigned ranks) ----
  hist_kernel<<<(NEDGES + 255) / 256, 256, 0, stream>>>(ei, counts, rank);
  scanA_kernel<<<SCAN_BLOCKS, 256, 0, stream>>>(counts, rowptr, blockSum);
  scanB_kernel<<<1, 256, 0, stream>>>(blockSum, blockOff);
  scanC_kernel<<<SCAN_BLOCKS, 256, 0, stream>>>(rowptr, blockOff);
  scatter_kernel<<<NSLICE * 8, 256, 0, stream>>>(ei, rowptr, rank, col);

  // ---- layer 1: 64 -> 16 (t-gather) ----
  gemm1_kernel<8, 2><<<(NNODES + 63) / 64, 256, 0, stream>>>(x, W1, t);
  s_kernel<64><<<(NNODES * 4 + 255) / 256, 256, 0, stream>>>(x, u1, s);
  q_kernel<<<(NNODES + 15) / 16, 256, 0, stream>>>(rowptr, col, s, c1, q);
  gather1_kernel<<<(NNODES + 15) / 16, 256, 0, stream>>>(rowptr, col, q, t, c1, b1, hA);

  // ---- layer 2: 16 -> 32 (g-gather) ----
  s_kernel<16><<<(NNODES * 4 + 255) / 256, 256, 0, stream>>>(hA, u2, s);
  q_kernel<<<(NNODES + 15) / 16, 256, 0, stream>>>(rowptr, col, s, c2, q);
  gatherG_kernel<16><<<(NNODES + 15) / 16, 256, 0, stream>>>(rowptr, col, q, hA, c2, g);
  transform_kernel<16, 32, 4, 2><<<(NNODES + 63) / 64, 256, 0, stream>>>(g, rowptr, W2, b2, hB);

  // ---- layer 3: 32 -> 64 (g-gather) ----
  s_kernel<32><<<(NNODES * 4 + 255) / 256, 256, 0, stream>>>(hB, u3, s);
  q_kernel<<<(NNODES + 15) / 16, 256, 0, stream>>>(rowptr, col, s, c3, q);
  gatherG_kernel<32><<<(NNODES + 7) / 8, 256, 0, stream>>>(rowptr, col, q, hB, c3, g);
  transform_kernel<32, 64, 8, 2><<<(NNODES + 63) / 64, 256, 0, stream>>>(g, rowptr, W3, b3, hA);

  // ---- BN stats + MLP head ----
  stats_kernel<<<256, 256, 0, stream>>>(hA, sums);
  mlp_kernel<<<(NNODES + 255) / 256, 256, 0, stream>>>(hA, sums, gamma, beta, lw1, lb1,
                                                       lw2, lb2, lw3, lb3, lw4, lb4,
                                                       ow, ob, out);
}